// Round 1
// baseline (2076.622 us; speedup 1.0000x reference)
//
#include <hip/hip_runtime.h>
#include <math.h>

#define NB   16
#define NOPn 512
#define NMAn 64
#define DOPn 16
#define DMAn 8
#define DEGn 8
#define HIDn 256
#define OUTn 128

struct MlpW {
    const float *w1, *b1, *w2, *b2, *w3, *b3;
};

__device__ __forceinline__ float eluf(float x) { return x > 0.f ? x : expm1f(x); }

// 32-row chunk through a 3-layer MLP (16->256->256->128), f32.
// Xs: [32][16] staged inputs. H: [32][256] scratch (holds h1, then h2 in place).
// Output mapping: y[rr][q] = row 8*(t>>6)+rr (rr=0..7), col 2*(t&63)+q (q=0..1).
__device__ __forceinline__ void mlp16_chunk(const float (*Xs)[DOPn], float (*H)[HIDn],
                                            const MlpW& W, float y[8][2])
{
    const int t = threadIdx.x;
    // ---- layer 1: 16 -> 256. one hidden column per thread, loop 32 rows.
    {
        float w1c[DOPn];
        #pragma unroll
        for (int k = 0; k < DOPn; ++k) w1c[k] = W.w1[k * HIDn + t];
        const float bb = W.b1[t];
        #pragma unroll 4
        for (int r = 0; r < 32; ++r) {
            const float4* xr = (const float4*)Xs[r];
            const float4 x0 = xr[0], x1 = xr[1], x2 = xr[2], x3 = xr[3];
            float acc = bb;
            acc += x0.x * w1c[0];  acc += x0.y * w1c[1];  acc += x0.z * w1c[2];  acc += x0.w * w1c[3];
            acc += x1.x * w1c[4];  acc += x1.y * w1c[5];  acc += x1.z * w1c[6];  acc += x1.w * w1c[7];
            acc += x2.x * w1c[8];  acc += x2.y * w1c[9];  acc += x2.z * w1c[10]; acc += x2.w * w1c[11];
            acc += x3.x * w1c[12]; acc += x3.y * w1c[13]; acc += x3.z * w1c[14]; acc += x3.w * w1c[15];
            H[r][t] = eluf(acc);
        }
    }
    __syncthreads();
    // ---- layer 2: 256 -> 256 (in place). threads [0,128) -> rows 0..15, [128,256) -> rows 16..31.
    // col pair 2*(t&127). LDS H reads are wave-uniform (broadcast, conflict-free);
    // W2 reads are fully coalesced float2 across lanes.
    {
        const int half = t >> 7;
        const int c0 = 2 * (t & 127);
        const int r0 = 16 * half;
        float acc[16][2];
        {
            const float b0 = W.b2[c0], b1v = W.b2[c0 + 1];
            #pragma unroll
            for (int rr = 0; rr < 16; ++rr) { acc[rr][0] = b0; acc[rr][1] = b1v; }
        }
        #pragma unroll 1
        for (int k = 0; k < HIDn; k += 4) {
            float2 wv[4];
            #pragma unroll
            for (int kk = 0; kk < 4; ++kk) wv[kk] = *(const float2*)&W.w2[(size_t)(k + kk) * HIDn + c0];
            #pragma unroll
            for (int rr = 0; rr < 16; ++rr) {
                const float4 h4 = *(const float4*)&H[r0 + rr][k];
                const float ha[4] = {h4.x, h4.y, h4.z, h4.w};
                #pragma unroll
                for (int kk = 0; kk < 4; ++kk) {
                    acc[rr][0] += ha[kk] * wv[kk].x;
                    acc[rr][1] += ha[kk] * wv[kk].y;
                }
            }
        }
        __syncthreads();   // all H reads complete before in-place overwrite
        #pragma unroll
        for (int rr = 0; rr < 16; ++rr) {
            float2 v; v.x = eluf(acc[rr][0]); v.y = eluf(acc[rr][1]);
            *(float2*)&H[r0 + rr][c0] = v;
        }
    }
    __syncthreads();
    // ---- layer 3: 256 -> 128. wave w -> rows 8w..8w+7, col pair 2*(t&63). Linear output.
    {
        const int w = t >> 6;
        const int c0 = 2 * (t & 63);
        const int r0 = 8 * w;
        const float b0 = W.b3[c0], b1v = W.b3[c0 + 1];
        #pragma unroll
        for (int rr = 0; rr < 8; ++rr) { y[rr][0] = b0; y[rr][1] = b1v; }
        #pragma unroll 1
        for (int k = 0; k < HIDn; k += 4) {
            float2 wv[4];
            #pragma unroll
            for (int kk = 0; kk < 4; ++kk) wv[kk] = *(const float2*)&W.w3[(size_t)(k + kk) * OUTn + c0];
            #pragma unroll
            for (int rr = 0; rr < 8; ++rr) {
                const float4 h4 = *(const float4*)&H[r0 + rr][k];
                const float ha[4] = {h4.x, h4.y, h4.z, h4.w};
                #pragma unroll
                for (int kk = 0; kk < 4; ++kk) {
                    y[rr][0] += ha[kk] * wv[kk].x;
                    y[rr][1] += ha[kk] * wv[kk].y;
                }
            }
        }
    }
}

// pre_agg / sub_agg: adjacency-gated row sums of op. One block per (i, b).
__global__ __launch_bounds__(256) void agg_kernel(const float* __restrict__ op,
                                                  const int* __restrict__ pre_adj,
                                                  const int* __restrict__ sub_adj,
                                                  const int* __restrict__ bidx,
                                                  float* __restrict__ pre_agg,
                                                  float* __restrict__ sub_agg)
{
    const int i = blockIdx.x, b = blockIdx.y;
    const int bi = bidx[b];
    const int t = threadIdx.x, d = t & 15, g = t >> 4;
    const int* pr = pre_adj + ((size_t)bi * NOPn + i) * NOPn;
    const int* sr = sub_adj + ((size_t)bi * NOPn + i) * NOPn;
    const float* opb = op + (size_t)b * NOPn * DOPn;
    float ap = 0.f, as = 0.f;
    for (int j = g; j < NOPn; j += 16) {
        const float v = opb[j * DOPn + d];
        if (pr[j]) ap += v;
        if (sr[j]) as += v;
    }
    __shared__ float red[2][16][16];
    red[0][g][d] = ap;
    red[1][g][d] = as;
    __syncthreads();
    if (t < 32) {
        const int which = t >> 4, dd = t & 15;
        float s = 0.f;
        #pragma unroll
        for (int gg = 0; gg < 16; ++gg) s += red[which][gg][dd];
        float* dst = which ? sub_agg : pre_agg;
        dst[((size_t)b * NOPn + i) * DOPn + dd] = s;
    }
}

// pre/sub/self MLP over 32 rows per block. Writes f1 and its attention dot (ut).
__global__ __launch_bounds__(256) void mlp_rows_kernel(const float* __restrict__ X, MlpW W,
                                                       const float* __restrict__ attn,
                                                       float* __restrict__ f1_out,
                                                       float* __restrict__ ut_out)
{
    const int chunk = blockIdx.x, b = blockIdx.y;
    const int i0 = chunk * 32;
    const int t = threadIdx.x;
    __shared__ float Xs[32][DOPn];
    __shared__ float H[32][HIDn];
    __shared__ float UT[32];
    for (int idx = t; idx < 32 * DOPn; idx += 256) {
        const int r = idx >> 4, d = idx & 15;
        Xs[r][d] = X[((size_t)b * NOPn + i0 + r) * DOPn + d];
    }
    __syncthreads();
    float y[8][2];
    mlp16_chunk(Xs, H, W, y);
    const int w = t >> 6, c0 = 2 * (t & 63);
    #pragma unroll
    for (int rr = 0; rr < 8; ++rr) {
        const int r = 8 * w + rr;
        float2 v; v.x = y[rr][0]; v.y = y[rr][1];
        *(float2*)&f1_out[((size_t)b * NOPn + i0 + r) * OUTn + c0] = v;
        float part = y[rr][0] * attn[c0] + y[rr][1] * attn[c0 + 1];
        #pragma unroll
        for (int off = 32; off > 0; off >>= 1) part += __shfl_down(part, off);
        if ((t & 63) == 0) UT[r] = part;   // row owned by exactly one wave
    }
    __syncthreads();
    if (t < 32) ut_out[b * NOPn + i0 + t] = UT[t];
}

// MLP0 over all 64 ma-edges of one (b,i) (dense: inactive rows give exactly
// MLP0(0), matching reference cnt semantics bit-for-bit), then mean-pool + MLP4.
__global__ __launch_bounds__(256) void ma_kernel(const float* __restrict__ ma,
                                                 const float* __restrict__ eg,
                                                 const int* __restrict__ ma_adj,
                                                 const int* __restrict__ bidx,
                                                 const float* __restrict__ attn,
                                                 MlpW W0, MlpW W4,
                                                 float* __restrict__ ma_f2_out,
                                                 float* __restrict__ ut_out)
{
    const int i = blockIdx.x, b = blockIdx.y;
    const int bi = bidx[b];
    const int t = threadIdx.x;
    __shared__ float Xs[32][DOPn];
    __shared__ float H[32][HIDn];
    __shared__ float SUM[OUTn];
    __shared__ float CNT[OUTn];
    __shared__ float R1[HIDn];
    __shared__ float R2[HIDn];
    if (t < OUTn) { SUM[t] = 0.f; CNT[t] = 0.f; }
    const float* mab = ma + (size_t)b * NMAn * DMAn;
    const float* egr = eg + ((size_t)b * NOPn + i) * NMAn * DEGn;
    const int* adjr = ma_adj + ((size_t)bi * NOPn + i) * NMAn;
    for (int ch = 0; ch < 2; ++ch) {
        __syncthreads();   // SUM init (ch 0) / previous chunk fully done (ch 1)
        const int j0 = ch * 32;
        for (int idx = t; idx < 32 * DOPn; idx += 256) {
            const int r = idx >> 4, d = idx & 15;
            const int j = j0 + r;
            const float a = (float)adjr[j];
            const float v = (d < DMAn) ? mab[j * DMAn + d] : egr[j * DEGn + (d - DMAn)];
            Xs[r][d] = a * v;
        }
        __syncthreads();
        float y[8][2];
        mlp16_chunk(Xs, H, W0, y);
        float s0 = 0.f, s1 = 0.f, n0 = 0.f, n1 = 0.f;
        #pragma unroll
        for (int rr = 0; rr < 8; ++rr) {
            s0 += y[rr][0]; s1 += y[rr][1];
            n0 += (y[rr][0] != 0.f) ? 1.f : 0.f;
            n1 += (y[rr][1] != 0.f) ? 1.f : 0.f;
        }
        const int cc = 2 * (t & 63);
        atomicAdd(&SUM[cc], s0);     atomicAdd(&SUM[cc + 1], s1);
        atomicAdd(&CNT[cc], n0);     atomicAdd(&CNT[cc + 1], n1);
    }
    __syncthreads();
    // x2 = SUM / CNT  (reference: sum(ma_f1)/count(ma_f1 != 0))
    float* x2 = &Xs[0][0];
    if (t < OUTn) x2[t] = SUM[t] / CNT[t];
    __syncthreads();
    // MLP4 layer 1: 128 -> 256
    {
        float acc = W4.b1[t];
        #pragma unroll 1
        for (int k = 0; k < OUTn; k += 4) {
            const float4 xv = *(const float4*)&x2[k];
            acc += xv.x * W4.w1[(size_t)(k + 0) * HIDn + t];
            acc += xv.y * W4.w1[(size_t)(k + 1) * HIDn + t];
            acc += xv.z * W4.w1[(size_t)(k + 2) * HIDn + t];
            acc += xv.w * W4.w1[(size_t)(k + 3) * HIDn + t];
        }
        R1[t] = eluf(acc);
    }
    __syncthreads();
    // MLP4 layer 2: 256 -> 256
    {
        float acc = W4.b2[t];
        #pragma unroll 1
        for (int k = 0; k < HIDn; k += 4) {
            const float4 hv = *(const float4*)&R1[k];
            acc += hv.x * W4.w2[(size_t)(k + 0) * HIDn + t];
            acc += hv.y * W4.w2[(size_t)(k + 1) * HIDn + t];
            acc += hv.z * W4.w2[(size_t)(k + 2) * HIDn + t];
            acc += hv.w * W4.w2[(size_t)(k + 3) * HIDn + t];
        }
        R2[t] = eluf(acc);
    }
    __syncthreads();
    // MLP4 layer 3: 256 -> 128 (linear), plus attention dot partials
    if (t < OUTn) {
        float acc = W4.b3[t];
        #pragma unroll 1
        for (int k = 0; k < HIDn; k += 4) {
            const float4 hv = *(const float4*)&R2[k];
            acc += hv.x * W4.w3[(size_t)(k + 0) * OUTn + t];
            acc += hv.y * W4.w3[(size_t)(k + 1) * OUTn + t];
            acc += hv.z * W4.w3[(size_t)(k + 2) * OUTn + t];
            acc += hv.w * W4.w3[(size_t)(k + 3) * OUTn + t];
        }
        ma_f2_out[((size_t)b * NOPn + i) * OUTn + t] = acc;
        x2[t] = acc * attn[t];
    }
    __syncthreads();
    if (t < 64) {
        float v = x2[t] + x2[t + 64];
        #pragma unroll
        for (int off = 32; off > 0; off >>= 1) v += __shfl_down(v, off);
        if (t == 0) ut_out[b * NOPn + i] = v;
    }
}

// Per-batch joint softmax over the 4*NOP scores + sigmoid combine.
__global__ __launch_bounds__(256) void final_kernel(const float* __restrict__ pre_f1,
                                                    const float* __restrict__ sub_f1,
                                                    const float* __restrict__ self_f1,
                                                    const float* __restrict__ ma_f2,
                                                    const float* __restrict__ uts,
                                                    float* __restrict__ out)
{
    const int b = blockIdx.x, t = threadIdx.x;
    __shared__ float sc[4 * NOPn];
    __shared__ float red[256];
    const float* put = uts + 0 * NB * NOPn + (size_t)b * NOPn;
    const float* sut = uts + 1 * NB * NOPn + (size_t)b * NOPn;
    const float* eut = uts + 2 * NB * NOPn + (size_t)b * NOPn;
    const float* mut = uts + 3 * NB * NOPn + (size_t)b * NOPn;
    for (int i = t; i < NOPn; i += 256) {
        const float se = eut[i];
        const float s0 = put[i] + se, s1 = sut[i] + se, s2 = se + se, s3 = mut[i] + se;
        sc[0 * NOPn + i] = s0 > 0.f ? s0 : 0.2f * s0;
        sc[1 * NOPn + i] = s1 > 0.f ? s1 : 0.2f * s1;
        sc[2 * NOPn + i] = s2 > 0.f ? s2 : 0.2f * s2;
        sc[3 * NOPn + i] = s3 > 0.f ? s3 : 0.2f * s3;
    }
    __syncthreads();
    float mx = -INFINITY;
    for (int idx = t; idx < 4 * NOPn; idx += 256) mx = fmaxf(mx, sc[idx]);
    red[t] = mx;
    __syncthreads();
    for (int s = 128; s > 0; s >>= 1) { if (t < s) red[t] = fmaxf(red[t], red[t + s]); __syncthreads(); }
    mx = red[0];
    __syncthreads();
    float ps = 0.f;
    for (int idx = t; idx < 4 * NOPn; idx += 256) {
        const float e = expf(sc[idx] - mx);
        sc[idx] = e;
        ps += e;
    }
    red[t] = ps;
    __syncthreads();
    for (int s = 128; s > 0; s >>= 1) { if (t < s) red[t] += red[t + s]; __syncthreads(); }
    const float invZ = 1.f / red[0];
    const size_t base = (size_t)b * NOPn * OUTn;
    for (int idx = t; idx < NOPn * OUTn; idx += 256) {
        const int i = idx >> 7;
        const float v = (sc[i] * pre_f1[base + idx] + sc[NOPn + i] * sub_f1[base + idx]
                       + sc[2 * NOPn + i] * self_f1[base + idx] + sc[3 * NOPn + i] * ma_f2[base + idx]) * invZ;
        out[base + idx] = 1.f / (1.f + expf(-v));
    }
}

extern "C" void kernel_launch(void* const* d_in, const int* in_sizes, int n_in,
                              void* d_out, int out_size, void* d_ws, size_t ws_size,
                              hipStream_t stream) {
    const float* op      = (const float*)d_in[0];
    const float* ma      = (const float*)d_in[1];
    const float* eg      = (const float*)d_in[2];
    const int*   ma_adj  = (const int*)d_in[3];
    const int*   pre_adj = (const int*)d_in[4];
    const int*   sub_adj = (const int*)d_in[5];
    const int*   bidx    = (const int*)d_in[6];
    const float* attn    = (const float*)d_in[7];
    MlpW W[5];
    for (int m = 0; m < 5; ++m) {
        W[m].w1 = (const float*)d_in[8 + 6 * m + 0];
        W[m].b1 = (const float*)d_in[8 + 6 * m + 1];
        W[m].w2 = (const float*)d_in[8 + 6 * m + 2];
        W[m].b2 = (const float*)d_in[8 + 6 * m + 3];
        W[m].w3 = (const float*)d_in[8 + 6 * m + 4];
        W[m].b3 = (const float*)d_in[8 + 6 * m + 5];
    }

    // workspace layout (floats): ~18 MB total
    float* ws = (float*)d_ws;
    float* pre_agg = ws;  ws += (size_t)NB * NOPn * DOPn;
    float* sub_agg = ws;  ws += (size_t)NB * NOPn * DOPn;
    float* pre_f1  = ws;  ws += (size_t)NB * NOPn * OUTn;
    float* sub_f1  = ws;  ws += (size_t)NB * NOPn * OUTn;
    float* self_f1 = ws;  ws += (size_t)NB * NOPn * OUTn;
    float* ma_f2   = ws;  ws += (size_t)NB * NOPn * OUTn;
    float* uts     = ws;  ws += (size_t)4 * NB * NOPn;
    float* out     = (float*)d_out;

    agg_kernel<<<dim3(NOPn, NB), 256, 0, stream>>>(op, pre_adj, sub_adj, bidx, pre_agg, sub_agg);
    mlp_rows_kernel<<<dim3(NOPn / 32, NB), 256, 0, stream>>>(pre_agg, W[1], attn, pre_f1, uts + 0 * NB * NOPn);
    mlp_rows_kernel<<<dim3(NOPn / 32, NB), 256, 0, stream>>>(sub_agg, W[2], attn, sub_f1, uts + 1 * NB * NOPn);
    mlp_rows_kernel<<<dim3(NOPn / 32, NB), 256, 0, stream>>>(op,      W[3], attn, self_f1, uts + 2 * NB * NOPn);
    ma_kernel<<<dim3(NOPn, NB), 256, 0, stream>>>(ma, eg, ma_adj, bidx, attn, W[0], W[4], ma_f2, uts + 3 * NB * NOPn);
    final_kernel<<<NB, 256, 0, stream>>>(pre_f1, sub_f1, self_f1, ma_f2, uts, out);
}

// Round 3
// 682.918 us; speedup vs baseline: 3.0408x; 3.0408x over previous
//
#include <hip/hip_runtime.h>
#include <math.h>

#define NBb  16
#define NOPc 512
#define NMAc 64
#define HIDc 256
#define OUTc 128

typedef unsigned int uint32;
typedef unsigned short ush;
typedef __attribute__((ext_vector_type(8))) short bf16x8;
typedef __attribute__((ext_vector_type(4))) float f32x4;
typedef __attribute__((ext_vector_type(4))) ush ushx4;

__device__ __forceinline__ ush f2bf(float v) {
    uint32 u = __float_as_uint(v);
    u += 0x7FFFu + ((u >> 16) & 1u);
    return (ush)(u >> 16);
}
__device__ __forceinline__ float bf2f(ush b) { return __uint_as_float(((uint32)b) << 16); }
__device__ __forceinline__ float eluf(float x) { return x > 0.f ? x : expm1f(x); }

#define MFMA(A, B, C) __builtin_amdgcn_mfma_f32_16x16x32_bf16((A), (B), (C), 0, 0, 0)

// All weights pre-split into hi/lo bf16 fragment-ordered packs:
// pack[((kb*nbn + nb)*64 + lane)*8 + e] = W[kb*32 + 8*(lane>>4) + e][nb*16 + (lane&15)]
struct MlpPack {
    const ush *w1h, *w1l, *w2h, *w2l, *w3h, *w3l;
    const float *b1, *b2, *b3;
};

// ---------------------------------------------------------------------------
// Fused 3-layer MLP core over a 64-row tile. KX = KB1*32 (input staged hi/lo
// in Xh/Xl, linear [64][KX]). Hh/Hl: [64][256] bf16 planes, XOR-swizzled
// (k ^ 8*(row&7)) to kill the 512B-stride bank conflict. Swapped-operand
// MFMA: D rows = out-cols n (4g+q contiguous), D cols = tile rows m (=r).
// Leaves layer-3 accs (pre-bias) in acc3[a][m]: cols n0=(wv*2+a)*16+4g+q,
// rows m = 16*mb + r.
// ---------------------------------------------------------------------------
template<int KB1>
__device__ __forceinline__ void mlp3_core(
    const MlpPack& P,
    const ush* Xh, const ush* Xl, ush* Hh, ush* Hl, f32x4 acc3[2][4])
{
    const int tid = threadIdx.x;
    const int wv = tid >> 6, lane = tid & 63, r = lane & 15, g = lane >> 4;
    constexpr int KX = KB1 * 32;

    // ---------- layer 1: KX -> 256 ----------
    {
        f32x4 acc[4][4];
        #pragma unroll
        for (int a = 0; a < 4; ++a)
            #pragma unroll
            for (int m = 0; m < 4; ++m) acc[a][m] = f32x4{0.f, 0.f, 0.f, 0.f};
        #pragma unroll 1
        for (int kb = 0; kb < KB1; ++kb) {
            bf16x8 wh[4], wl[4];
            #pragma unroll
            for (int a = 0; a < 4; ++a) {
                const size_t o = ((size_t)(kb * 16 + (wv * 4 + a)) * 64 + lane) * 8;
                wh[a] = *(const bf16x8*)(P.w1h + o);
                wl[a] = *(const bf16x8*)(P.w1l + o);
            }
            #pragma unroll
            for (int m = 0; m < 4; ++m) {
                const int row = 16 * m + r;
                const int ki = kb * 32 + 8 * g;
                bf16x8 xh = *(const bf16x8*)(Xh + row * KX + ki);
                bf16x8 xl = *(const bf16x8*)(Xl + row * KX + ki);
                #pragma unroll
                for (int a = 0; a < 4; ++a) {
                    acc[a][m] = MFMA(wh[a], xh, acc[a][m]);
                    acc[a][m] = MFMA(wh[a], xl, acc[a][m]);
                    acc[a][m] = MFMA(wl[a], xh, acc[a][m]);
                }
            }
        }
        // epilogue: bias + ELU + hi/lo split -> H planes
        #pragma unroll
        for (int a = 0; a < 4; ++a) {
            const int n0 = (wv * 4 + a) * 16 + 4 * g;
            const float4 bv = *(const float4*)(P.b1 + n0);
            const float bb[4] = {bv.x, bv.y, bv.z, bv.w};
            #pragma unroll
            for (int m = 0; m < 4; ++m) {
                const int row = 16 * m + r;
                ushx4 vh, vl;
                #pragma unroll
                for (int q = 0; q < 4; ++q) {
                    float y = eluf(acc[a][m][q] + bb[q]);
                    const ush hi = f2bf(y);
                    vh[q] = hi;
                    vl[q] = f2bf(y - bf2f(hi));
                }
                const int idx = row * 256 + (n0 ^ (8 * (row & 7)));
                *(ushx4*)(Hh + idx) = vh;
                *(ushx4*)(Hl + idx) = vl;
            }
        }
    }
    __syncthreads();

    // ---------- layer 2: 256 -> 256 (in place after full-read barrier) ----------
    {
        f32x4 acc[4][4];
        #pragma unroll
        for (int a = 0; a < 4; ++a)
            #pragma unroll
            for (int m = 0; m < 4; ++m) acc[a][m] = f32x4{0.f, 0.f, 0.f, 0.f};
        #pragma unroll 1
        for (int kb = 0; kb < 8; ++kb) {
            bf16x8 wh[4], wl[4];
            #pragma unroll
            for (int a = 0; a < 4; ++a) {
                const size_t o = ((size_t)(kb * 16 + (wv * 4 + a)) * 64 + lane) * 8;
                wh[a] = *(const bf16x8*)(P.w2h + o);
                wl[a] = *(const bf16x8*)(P.w2l + o);
            }
            #pragma unroll
            for (int m = 0; m < 4; ++m) {
                const int row = 16 * m + r;
                const int k0 = kb * 32 + 8 * g;
                const int idx = row * 256 + (k0 ^ (8 * (row & 7)));
                bf16x8 hh = *(const bf16x8*)(Hh + idx);
                bf16x8 hl = *(const bf16x8*)(Hl + idx);
                #pragma unroll
                for (int a = 0; a < 4; ++a) {
                    acc[a][m] = MFMA(wh[a], hh, acc[a][m]);
                    acc[a][m] = MFMA(wh[a], hl, acc[a][m]);
                    acc[a][m] = MFMA(wl[a], hh, acc[a][m]);
                }
            }
        }
        __syncthreads();   // all H1 reads complete before in-place overwrite
        #pragma unroll
        for (int a = 0; a < 4; ++a) {
            const int n0 = (wv * 4 + a) * 16 + 4 * g;
            const float4 bv = *(const float4*)(P.b2 + n0);
            const float bb[4] = {bv.x, bv.y, bv.z, bv.w};
            #pragma unroll
            for (int m = 0; m < 4; ++m) {
                const int row = 16 * m + r;
                ushx4 vh, vl;
                #pragma unroll
                for (int q = 0; q < 4; ++q) {
                    float y = eluf(acc[a][m][q] + bb[q]);
                    const ush hi = f2bf(y);
                    vh[q] = hi;
                    vl[q] = f2bf(y - bf2f(hi));
                }
                const int idx = row * 256 + (n0 ^ (8 * (row & 7)));
                *(ushx4*)(Hh + idx) = vh;
                *(ushx4*)(Hl + idx) = vl;
            }
        }
    }
    __syncthreads();

    // ---------- layer 3: 256 -> 128 (linear, accs returned) ----------
    {
        #pragma unroll
        for (int a = 0; a < 2; ++a)
            #pragma unroll
            for (int m = 0; m < 4; ++m) acc3[a][m] = f32x4{0.f, 0.f, 0.f, 0.f};
        #pragma unroll 1
        for (int kb = 0; kb < 8; ++kb) {
            bf16x8 wh[2], wl[2];
            #pragma unroll
            for (int a = 0; a < 2; ++a) {
                const size_t o = ((size_t)(kb * 8 + (wv * 2 + a)) * 64 + lane) * 8;
                wh[a] = *(const bf16x8*)(P.w3h + o);
                wl[a] = *(const bf16x8*)(P.w3l + o);
            }
            #pragma unroll
            for (int m = 0; m < 4; ++m) {
                const int row = 16 * m + r;
                const int k0 = kb * 32 + 8 * g;
                const int idx = row * 256 + (k0 ^ (8 * (row & 7)));
                bf16x8 hh = *(const bf16x8*)(Hh + idx);
                bf16x8 hl = *(const bf16x8*)(Hl + idx);
                #pragma unroll
                for (int a = 0; a < 2; ++a) {
                    acc3[a][m] = MFMA(wh[a], hh, acc3[a][m]);
                    acc3[a][m] = MFMA(wh[a], hl, acc3[a][m]);
                    acc3[a][m] = MFMA(wl[a], hh, acc3[a][m]);
                }
            }
        }
    }
}

// ---------------------------------------------------------------------------
// Weight pre-pack: f32 -> (hi, lo) bf16 fragment order.
// ---------------------------------------------------------------------------
struct PackDesc { const float* src; ush* dh; ush* dl; int kreal; int kbn; int nbn; };
struct PackArgs { PackDesc d[15]; };

__global__ __launch_bounds__(256) void pack_kernel(PackArgs pa)
{
    const PackDesc d = pa.d[blockIdx.y];
    const int total = d.kbn * d.nbn * 512;
    const int N = d.nbn * 16;
    for (int idx = blockIdx.x * 256 + threadIdx.x; idx < total; idx += gridDim.x * 256) {
        const int e = idx & 7;
        const int l = (idx >> 3) & 63;
        const int t2 = idx >> 9;
        const int nb = t2 % d.nbn;
        const int kb = t2 / d.nbn;
        const int k = kb * 32 + ((l >> 4) << 3) + e;
        const int n = nb * 16 + (l & 15);
        const float v = (k < d.kreal) ? d.src[(size_t)k * N + n] : 0.f;
        const ush hi = f2bf(v);
        d.dh[idx] = hi;
        d.dl[idx] = f2bf(v - bf2f(hi));
    }
}

// ---------------------------------------------------------------------------
// pre/sub/self/MLP4 path: 64 rows/block through the MLP; writes f1 and ut.
// ---------------------------------------------------------------------------
template<int KB1, int KINR>
__global__ __launch_bounds__(256) void mlp_f1_kernel(
    const float* __restrict__ Xg, MlpPack P, const float* __restrict__ attn,
    float* __restrict__ f1_out, float* __restrict__ ut_out)
{
    constexpr int KX = KB1 * 32;
    __shared__ ush Xh[64 * KX], Xl[64 * KX];
    __shared__ ush Hh[64 * 256], Hl[64 * 256];
    __shared__ float UT[64];
    const int tid = threadIdx.x;
    const int row0 = blockIdx.x * 64;
    if (tid < 64) UT[tid] = 0.f;
    for (int idx = tid; idx < 64 * KX; idx += 256) {
        const int row = idx / KX, k = idx % KX;
        float v = 0.f;
        if (k < KINR) v = Xg[(size_t)(row0 + row) * KINR + k];
        const ush hi = f2bf(v);
        Xh[idx] = hi;
        Xl[idx] = f2bf(v - bf2f(hi));
    }
    __syncthreads();
    f32x4 acc3[2][4];
    mlp3_core<KB1>(P, Xh, Xl, Hh, Hl, acc3);

    const int wv = tid >> 6, lane = tid & 63, r = lane & 15, g = lane >> 4;
    float utp[4] = {0.f, 0.f, 0.f, 0.f};
    #pragma unroll
    for (int a = 0; a < 2; ++a) {
        const int n0 = (wv * 2 + a) * 16 + 4 * g;
        const float4 bv = *(const float4*)(P.b3 + n0);
        const float4 av = *(const float4*)(attn + n0);
        #pragma unroll
        for (int m = 0; m < 4; ++m) {
            float4 y;
            y.x = acc3[a][m][0] + bv.x;
            y.y = acc3[a][m][1] + bv.y;
            y.z = acc3[a][m][2] + bv.z;
            y.w = acc3[a][m][3] + bv.w;
            *(float4*)&f1_out[(size_t)(row0 + 16 * m + r) * OUTc + n0] = y;
            utp[m] += y.x * av.x + y.y * av.y + y.z * av.z + y.w * av.w;
        }
    }
    #pragma unroll
    for (int m = 0; m < 4; ++m) {
        float v = utp[m];
        v += __shfl_xor(v, 16);
        v += __shfl_xor(v, 32);
        if (lane < 16) atomicAdd(&UT[16 * m + r], v);
    }
    __syncthreads();
    if (tid < 64) ut_out[row0 + tid] = UT[tid];
}

// ---------------------------------------------------------------------------
// MLP0 over all 64 ma-edges of one (b,i) (dense: zero rows -> exactly MLP0(0),
// matching reference cnt semantics), mean-pool -> x2.
// ---------------------------------------------------------------------------
__global__ __launch_bounds__(256) void ma_mlp0_kernel(
    const float* __restrict__ ma, const float* __restrict__ eg,
    const int* __restrict__ ma_adj, const int* __restrict__ bidx,
    MlpPack P, float* __restrict__ x2_out)
{
    __shared__ ush Xh[64 * 32], Xl[64 * 32];
    __shared__ ush Hh[64 * 256], Hl[64 * 256];
    __shared__ float SUM[128], CNT[128];
    const int i = blockIdx.x, b = blockIdx.y;
    const int tid = threadIdx.x;
    const int bi = bidx[b];
    if (tid < 128) { SUM[tid] = 0.f; CNT[tid] = 0.f; }
    const float* mab = ma + (size_t)b * NMAc * 8;
    const float* egr = eg + ((size_t)b * NOPc + i) * NMAc * 8;
    const int* adjr = ma_adj + ((size_t)bi * NOPc + i) * NMAc;
    for (int idx = tid; idx < 64 * 32; idx += 256) {
        const int j = idx >> 5, k = idx & 31;
        float v = 0.f;
        if (k < 16) {
            const float a = (float)adjr[j];
            v = a * ((k < 8) ? mab[j * 8 + k] : egr[j * 8 + (k - 8)]);
        }
        const ush hi = f2bf(v);
        Xh[idx] = hi;
        Xl[idx] = f2bf(v - bf2f(hi));
    }
    __syncthreads();
    f32x4 acc3[2][4];
    mlp3_core<1>(P, Xh, Xl, Hh, Hl, acc3);

    const int wv = tid >> 6, lane = tid & 63, r = lane & 15, g = lane >> 4;
    #pragma unroll
    for (int a = 0; a < 2; ++a) {
        const int n0 = (wv * 2 + a) * 16 + 4 * g;
        const float4 bv = *(const float4*)(P.b3 + n0);
        const float bb[4] = {bv.x, bv.y, bv.z, bv.w};
        float s[4] = {0.f, 0.f, 0.f, 0.f}, c[4] = {0.f, 0.f, 0.f, 0.f};
        #pragma unroll
        for (int m = 0; m < 4; ++m) {
            #pragma unroll
            for (int q = 0; q < 4; ++q) {
                const float y = acc3[a][m][q] + bb[q];
                s[q] += y;
                c[q] += (y != 0.f) ? 1.f : 0.f;
            }
        }
        #pragma unroll
        for (int q = 0; q < 4; ++q) {
            float sv = s[q], cv = c[q];
            #pragma unroll
            for (int o = 1; o < 16; o <<= 1) { sv += __shfl_xor(sv, o); cv += __shfl_xor(cv, o); }
            if (r == 0) { atomicAdd(&SUM[n0 + q], sv); atomicAdd(&CNT[n0 + q], cv); }
        }
    }
    __syncthreads();
    if (tid < 128) {
        const size_t rowI = (size_t)b * NOPc + i;
        x2_out[rowI * 128 + tid] = SUM[tid] / CNT[tid];
    }
}

// ---------------------------------------------------------------------------
// pre_agg / sub_agg: adjacency-gated row sums of op. One block per (i, b).
// ---------------------------------------------------------------------------
__global__ __launch_bounds__(256) void agg_kernel(const float* __restrict__ op,
                                                  const int* __restrict__ pre_adj,
                                                  const int* __restrict__ sub_adj,
                                                  const int* __restrict__ bidx,
                                                  float* __restrict__ pre_agg,
                                                  float* __restrict__ sub_agg)
{
    const int i = blockIdx.x, b = blockIdx.y;
    const int bi = bidx[b];
    const int t = threadIdx.x, d = t & 15, g = t >> 4;
    const int* pr = pre_adj + ((size_t)bi * NOPc + i) * NOPc;
    const int* sr = sub_adj + ((size_t)bi * NOPc + i) * NOPc;
    const float* opb = op + (size_t)b * NOPc * 16;
    float ap = 0.f, as = 0.f;
    for (int j = g; j < NOPc; j += 16) {
        const float v = opb[j * 16 + d];
        if (pr[j]) ap += v;
        if (sr[j]) as += v;
    }
    __shared__ float red[2][16][16];
    red[0][g][d] = ap;
    red[1][g][d] = as;
    __syncthreads();
    if (t < 32) {
        const int which = t >> 4, dd = t & 15;
        float s = 0.f;
        #pragma unroll
        for (int gg = 0; gg < 16; ++gg) s += red[which][gg][dd];
        float* dst = which ? sub_agg : pre_agg;
        dst[((size_t)b * NOPc + i) * 16 + dd] = s;
    }
}

// ---------------------------------------------------------------------------
// Per-batch joint softmax over the 4*NOP scores + sigmoid combine.
// ---------------------------------------------------------------------------
__global__ __launch_bounds__(256) void final_kernel(const float* __restrict__ pre_f1,
                                                    const float* __restrict__ sub_f1,
                                                    const float* __restrict__ self_f1,
                                                    const float* __restrict__ ma_f2,
                                                    const float* __restrict__ uts,
                                                    float* __restrict__ out)
{
    const int b = blockIdx.x, t = threadIdx.x;
    __shared__ float sc[4 * NOPc];
    __shared__ float red[256];
    const float* put = uts + 0 * NBb * NOPc + (size_t)b * NOPc;
    const float* sut = uts + 1 * NBb * NOPc + (size_t)b * NOPc;
    const float* eut = uts + 2 * NBb * NOPc + (size_t)b * NOPc;
    const float* mut = uts + 3 * NBb * NOPc + (size_t)b * NOPc;
    for (int i = t; i < NOPc; i += 256) {
        const float se = eut[i];
        const float s0 = put[i] + se, s1 = sut[i] + se, s2 = se + se, s3 = mut[i] + se;
        sc[0 * NOPc + i] = s0 > 0.f ? s0 : 0.2f * s0;
        sc[1 * NOPc + i] = s1 > 0.f ? s1 : 0.2f * s1;
        sc[2 * NOPc + i] = s2 > 0.f ? s2 : 0.2f * s2;
        sc[3 * NOPc + i] = s3 > 0.f ? s3 : 0.2f * s3;
    }
    __syncthreads();
    float mx = -INFINITY;
    for (int idx = t; idx < 4 * NOPc; idx += 256) mx = fmaxf(mx, sc[idx]);
    red[t] = mx;
    __syncthreads();
    for (int s = 128; s > 0; s >>= 1) { if (t < s) red[t] = fmaxf(red[t], red[t + s]); __syncthreads(); }
    mx = red[0];
    __syncthreads();
    float ps = 0.f;
    for (int idx = t; idx < 4 * NOPc; idx += 256) {
        const float e = expf(sc[idx] - mx);
        sc[idx] = e;
        ps += e;
    }
    red[t] = ps;
    __syncthreads();
    for (int s = 128; s > 0; s >>= 1) { if (t < s) red[t] += red[t + s]; __syncthreads(); }
    const float invZ = 1.f / red[0];
    const size_t base = (size_t)b * NOPc * OUTc;
    for (int idx = t; idx < NOPc * OUTc; idx += 256) {
        const int i = idx >> 7;
        const float v = (sc[i] * pre_f1[base + idx] + sc[NOPc + i] * sub_f1[base + idx]
                       + sc[2 * NOPc + i] * self_f1[base + idx] + sc[3 * NOPc + i] * ma_f2[base + idx]) * invZ;
        out[base + idx] = 1.f / (1.f + expf(-v));
    }
}

extern "C" void kernel_launch(void* const* d_in, const int* in_sizes, int n_in,
                              void* d_out, int out_size, void* d_ws, size_t ws_size,
                              hipStream_t stream) {
    const float* op      = (const float*)d_in[0];
    const float* ma      = (const float*)d_in[1];
    const float* eg      = (const float*)d_in[2];
    const int*   ma_adj  = (const int*)d_in[3];
    const int*   pre_adj = (const int*)d_in[4];
    const int*   sub_adj = (const int*)d_in[5];
    const int*   bidx    = (const int*)d_in[6];
    const float* attn    = (const float*)d_in[7];
    float* out = (float*)d_out;
    const float* Wraw[5][6];
    for (int m = 0; m < 5; ++m)
        for (int j = 0; j < 6; ++j)
            Wraw[m][j] = (const float*)d_in[8 + 6 * m + j];

    // ---- workspace layout ----
    float* wsf = (float*)d_ws;
    float* pre_agg = wsf;  wsf += (size_t)NBb * NOPc * 16;
    float* sub_agg = wsf;  wsf += (size_t)NBb * NOPc * 16;
    float* pre_f1  = wsf;  wsf += (size_t)NBb * NOPc * OUTc;
    float* sub_f1  = wsf;  wsf += (size_t)NBb * NOPc * OUTc;
    float* self_f1 = wsf;  wsf += (size_t)NBb * NOPc * OUTc;
    float* ma_f2   = wsf;  wsf += (size_t)NBb * NOPc * OUTc;
    float* x2      = wsf;  wsf += (size_t)NBb * NOPc * OUTc;
    float* uts     = wsf;  wsf += (size_t)4 * NBb * NOPc;
    ush* packp = (ush*)wsf;

    PackArgs pa;
    MlpPack pk[5];
    for (int m = 0; m < 5; ++m) {
        const int kre[3] = { (m == 4 ? 128 : 16), 256, 256 };
        const int kbn[3] = { (m == 4 ? 4 : 1), 8, 8 };
        const int nbn[3] = { 16, 16, 8 };
        const ush* dh[3]; const ush* dl[3];
        for (int j = 0; j < 3; ++j) {
            const int id = m * 3 + j;
            pa.d[id].src = Wraw[m][2 * j];     // w1, w2, w3
            pa.d[id].kreal = kre[j];
            pa.d[id].kbn = kbn[j];
            pa.d[id].nbn = nbn[j];
            const int cnt = kbn[j] * nbn[j] * 512;
            pa.d[id].dh = packp; dh[j] = packp; packp += cnt;
            pa.d[id].dl = packp; dl[j] = packp; packp += cnt;
        }
        pk[m].w1h = dh[0]; pk[m].w1l = dl[0];
        pk[m].w2h = dh[1]; pk[m].w2l = dl[1];
        pk[m].w3h = dh[2]; pk[m].w3l = dl[2];
        pk[m].b1 = Wraw[m][1]; pk[m].b2 = Wraw[m][3]; pk[m].b3 = Wraw[m][5];
    }

    pack_kernel<<<dim3(64, 15), 256, 0, stream>>>(pa);
    agg_kernel<<<dim3(NOPc, NBb), 256, 0, stream>>>(op, pre_adj, sub_adj, bidx, pre_agg, sub_agg);
    mlp_f1_kernel<1, 16><<<dim3(128), 256, 0, stream>>>(pre_agg, pk[1], attn, pre_f1, uts + 0 * NBb * NOPc);
    mlp_f1_kernel<1, 16><<<dim3(128), 256, 0, stream>>>(sub_agg, pk[2], attn, sub_f1, uts + 1 * NBb * NOPc);
    mlp_f1_kernel<1, 16><<<dim3(128), 256, 0, stream>>>(op,      pk[3], attn, self_f1, uts + 2 * NBb * NOPc);
    ma_mlp0_kernel<<<dim3(NOPc, NBb), 256, 0, stream>>>(ma, eg, ma_adj, bidx, pk[0], x2);
    mlp_f1_kernel<4, 128><<<dim3(128), 256, 0, stream>>>(x2, pk[4], attn, ma_f2, uts + 3 * NBb * NOPc);
    final_kernel<<<NBb, 256, 0, stream>>>(pre_f1, sub_f1, self_f1, ma_f2, uts, out);
}

// Round 4
// 395.611 us; speedup vs baseline: 5.2491x; 1.7262x over previous
//
#include <hip/hip_runtime.h>
#include <math.h>

#define NBb  16
#define NOPc 512
#define NMAc 64
#define HIDc 256
#define OUTc 128

typedef unsigned int uint32;
typedef unsigned short ush;
typedef __attribute__((ext_vector_type(8))) short bf16x8;
typedef __attribute__((ext_vector_type(4))) float f32x4;
typedef __attribute__((ext_vector_type(4))) ush ushx4;
typedef __attribute__((ext_vector_type(8))) ush ushx8;

__device__ __forceinline__ ush f2bf(float v) {
    uint32 u = __float_as_uint(v);
    u += 0x7FFFu + ((u >> 16) & 1u);
    return (ush)(u >> 16);
}
__device__ __forceinline__ float bf2f(ush b) { return __uint_as_float(((uint32)b) << 16); }
__device__ __forceinline__ float eluf(float x) { return x > 0.f ? x : expm1f(x); }
// fast ELU: exp(x)-1; cancellation only near 0 where rel err ~1e-5 (fine for bf16 target)
__device__ __forceinline__ float eluf_fast(float x) { return x > 0.f ? x : __expf(x) - 1.f; }

#define MFMA(A, B, C) __builtin_amdgcn_mfma_f32_16x16x32_bf16((A), (B), (C), 0, 0, 0)

// All weights pre-split into hi/lo bf16 fragment-ordered packs:
// pack[((kb*nbn + nb)*64 + lane)*8 + e] = W[kb*32 + 8*(lane>>4) + e][nb*16 + (lane&15)]
struct MlpPack {
    const ush *w1h, *w1l, *w2h, *w2l, *w3h, *w3l;
    const float *b1, *b2, *b3;
};

// ---------------------------------------------------------------------------
// Hi/lo (bf16x3) 3-layer core — unchanged from R3 (used by pre/sub/self/MLP4,
// whose operands are large-magnitude).
// ---------------------------------------------------------------------------
template<int KB1>
__device__ __forceinline__ void mlp3_core(
    const MlpPack& P,
    const ush* Xh, const ush* Xl, ush* Hh, ush* Hl, f32x4 acc3[2][4])
{
    const int tid = threadIdx.x;
    const int wv = tid >> 6, lane = tid & 63, r = lane & 15, g = lane >> 4;
    constexpr int KX = KB1 * 32;

    // ---------- layer 1: KX -> 256 ----------
    {
        f32x4 acc[4][4];
        #pragma unroll
        for (int a = 0; a < 4; ++a)
            #pragma unroll
            for (int m = 0; m < 4; ++m) acc[a][m] = f32x4{0.f, 0.f, 0.f, 0.f};
        #pragma unroll 1
        for (int kb = 0; kb < KB1; ++kb) {
            bf16x8 wh[4], wl[4];
            #pragma unroll
            for (int a = 0; a < 4; ++a) {
                const size_t o = ((size_t)(kb * 16 + (wv * 4 + a)) * 64 + lane) * 8;
                wh[a] = *(const bf16x8*)(P.w1h + o);
                wl[a] = *(const bf16x8*)(P.w1l + o);
            }
            #pragma unroll
            for (int m = 0; m < 4; ++m) {
                const int row = 16 * m + r;
                const int ki = kb * 32 + 8 * g;
                bf16x8 xh = *(const bf16x8*)(Xh + row * KX + ki);
                bf16x8 xl = *(const bf16x8*)(Xl + row * KX + ki);
                #pragma unroll
                for (int a = 0; a < 4; ++a) {
                    acc[a][m] = MFMA(wh[a], xh, acc[a][m]);
                    acc[a][m] = MFMA(wh[a], xl, acc[a][m]);
                    acc[a][m] = MFMA(wl[a], xh, acc[a][m]);
                }
            }
        }
        #pragma unroll
        for (int a = 0; a < 4; ++a) {
            const int n0 = (wv * 4 + a) * 16 + 4 * g;
            const float4 bv = *(const float4*)(P.b1 + n0);
            const float bb[4] = {bv.x, bv.y, bv.z, bv.w};
            #pragma unroll
            for (int m = 0; m < 4; ++m) {
                const int row = 16 * m + r;
                ushx4 vh, vl;
                #pragma unroll
                for (int q = 0; q < 4; ++q) {
                    float y = eluf(acc[a][m][q] + bb[q]);
                    const ush hi = f2bf(y);
                    vh[q] = hi;
                    vl[q] = f2bf(y - bf2f(hi));
                }
                const int idx = row * 256 + (n0 ^ (8 * (row & 7)));
                *(ushx4*)(Hh + idx) = vh;
                *(ushx4*)(Hl + idx) = vl;
            }
        }
    }
    __syncthreads();

    // ---------- layer 2: 256 -> 256 ----------
    {
        f32x4 acc[4][4];
        #pragma unroll
        for (int a = 0; a < 4; ++a)
            #pragma unroll
            for (int m = 0; m < 4; ++m) acc[a][m] = f32x4{0.f, 0.f, 0.f, 0.f};
        #pragma unroll 1
        for (int kb = 0; kb < 8; ++kb) {
            bf16x8 wh[4], wl[4];
            #pragma unroll
            for (int a = 0; a < 4; ++a) {
                const size_t o = ((size_t)(kb * 16 + (wv * 4 + a)) * 64 + lane) * 8;
                wh[a] = *(const bf16x8*)(P.w2h + o);
                wl[a] = *(const bf16x8*)(P.w2l + o);
            }
            #pragma unroll
            for (int m = 0; m < 4; ++m) {
                const int row = 16 * m + r;
                const int k0 = kb * 32 + 8 * g;
                const int idx = row * 256 + (k0 ^ (8 * (row & 7)));
                bf16x8 hh = *(const bf16x8*)(Hh + idx);
                bf16x8 hl = *(const bf16x8*)(Hl + idx);
                #pragma unroll
                for (int a = 0; a < 4; ++a) {
                    acc[a][m] = MFMA(wh[a], hh, acc[a][m]);
                    acc[a][m] = MFMA(wh[a], hl, acc[a][m]);
                    acc[a][m] = MFMA(wl[a], hh, acc[a][m]);
                }
            }
        }
        __syncthreads();
        #pragma unroll
        for (int a = 0; a < 4; ++a) {
            const int n0 = (wv * 4 + a) * 16 + 4 * g;
            const float4 bv = *(const float4*)(P.b2 + n0);
            const float bb[4] = {bv.x, bv.y, bv.z, bv.w};
            #pragma unroll
            for (int m = 0; m < 4; ++m) {
                const int row = 16 * m + r;
                ushx4 vh, vl;
                #pragma unroll
                for (int q = 0; q < 4; ++q) {
                    float y = eluf(acc[a][m][q] + bb[q]);
                    const ush hi = f2bf(y);
                    vh[q] = hi;
                    vl[q] = f2bf(y - bf2f(hi));
                }
                const int idx = row * 256 + (n0 ^ (8 * (row & 7)));
                *(ushx4*)(Hh + idx) = vh;
                *(ushx4*)(Hl + idx) = vl;
            }
        }
    }
    __syncthreads();

    // ---------- layer 3: 256 -> 128 ----------
    {
        #pragma unroll
        for (int a = 0; a < 2; ++a)
            #pragma unroll
            for (int m = 0; m < 4; ++m) acc3[a][m] = f32x4{0.f, 0.f, 0.f, 0.f};
        #pragma unroll 1
        for (int kb = 0; kb < 8; ++kb) {
            bf16x8 wh[2], wl[2];
            #pragma unroll
            for (int a = 0; a < 2; ++a) {
                const size_t o = ((size_t)(kb * 8 + (wv * 2 + a)) * 64 + lane) * 8;
                wh[a] = *(const bf16x8*)(P.w3h + o);
                wl[a] = *(const bf16x8*)(P.w3l + o);
            }
            #pragma unroll
            for (int m = 0; m < 4; ++m) {
                const int row = 16 * m + r;
                const int k0 = kb * 32 + 8 * g;
                const int idx = row * 256 + (k0 ^ (8 * (row & 7)));
                bf16x8 hh = *(const bf16x8*)(Hh + idx);
                bf16x8 hl = *(const bf16x8*)(Hl + idx);
                #pragma unroll
                for (int a = 0; a < 2; ++a) {
                    acc3[a][m] = MFMA(wh[a], hh, acc3[a][m]);
                    acc3[a][m] = MFMA(wh[a], hl, acc3[a][m]);
                    acc3[a][m] = MFMA(wl[a], hh, acc3[a][m]);
                }
            }
        }
    }
}

// ---------------------------------------------------------------------------
// Single-plane bf16 core, KX=32, with m-block skip (MB = ceil(rows/16),
// wave-uniform). Used by the ma path (small-magnitude operands).
// ---------------------------------------------------------------------------
__device__ __forceinline__ void mlp3_core_1p(
    const MlpPack& P, const int MB,
    const ush* Xh, ush* Hh, f32x4 acc3[2][4])
{
    const int tid = threadIdx.x;
    const int wv = tid >> 6, lane = tid & 63, r = lane & 15, g = lane >> 4;

    // ---------- layer 1: 32 -> 256 ----------
    {
        f32x4 acc[4][4];
        #pragma unroll
        for (int a = 0; a < 4; ++a)
            #pragma unroll
            for (int m = 0; m < 4; ++m) acc[a][m] = f32x4{0.f, 0.f, 0.f, 0.f};
        bf16x8 wh[4];
        #pragma unroll
        for (int a = 0; a < 4; ++a)
            wh[a] = *(const bf16x8*)(P.w1h + ((size_t)(wv * 4 + a) * 64 + lane) * 8);
        #pragma unroll
        for (int m = 0; m < 4; ++m) {
            if (m < MB) {
                const int row = 16 * m + r;
                bf16x8 xh = *(const bf16x8*)(Xh + row * 32 + 8 * g);
                #pragma unroll
                for (int a = 0; a < 4; ++a) acc[a][m] = MFMA(wh[a], xh, acc[a][m]);
            }
        }
        #pragma unroll
        for (int a = 0; a < 4; ++a) {
            const int n0 = (wv * 4 + a) * 16 + 4 * g;
            const float4 bv = *(const float4*)(P.b1 + n0);
            const float bb[4] = {bv.x, bv.y, bv.z, bv.w};
            #pragma unroll
            for (int m = 0; m < 4; ++m) {
                if (m < MB) {
                    const int row = 16 * m + r;
                    ushx4 vh;
                    #pragma unroll
                    for (int q = 0; q < 4; ++q) vh[q] = f2bf(eluf_fast(acc[a][m][q] + bb[q]));
                    *(ushx4*)(Hh + row * 256 + (n0 ^ (8 * (row & 7)))) = vh;
                }
            }
        }
    }
    __syncthreads();

    // ---------- layer 2: 256 -> 256 ----------
    {
        f32x4 acc[4][4];
        #pragma unroll
        for (int a = 0; a < 4; ++a)
            #pragma unroll
            for (int m = 0; m < 4; ++m) acc[a][m] = f32x4{0.f, 0.f, 0.f, 0.f};
        #pragma unroll 1
        for (int kb = 0; kb < 8; ++kb) {
            bf16x8 wh[4];
            #pragma unroll
            for (int a = 0; a < 4; ++a)
                wh[a] = *(const bf16x8*)(P.w2h + ((size_t)(kb * 16 + (wv * 4 + a)) * 64 + lane) * 8);
            #pragma unroll
            for (int m = 0; m < 4; ++m) {
                if (m < MB) {
                    const int row = 16 * m + r;
                    const int k0 = kb * 32 + 8 * g;
                    bf16x8 hh = *(const bf16x8*)(Hh + row * 256 + (k0 ^ (8 * (row & 7))));
                    #pragma unroll
                    for (int a = 0; a < 4; ++a) acc[a][m] = MFMA(wh[a], hh, acc[a][m]);
                }
            }
        }
        __syncthreads();
        #pragma unroll
        for (int a = 0; a < 4; ++a) {
            const int n0 = (wv * 4 + a) * 16 + 4 * g;
            const float4 bv = *(const float4*)(P.b2 + n0);
            const float bb[4] = {bv.x, bv.y, bv.z, bv.w};
            #pragma unroll
            for (int m = 0; m < 4; ++m) {
                if (m < MB) {
                    const int row = 16 * m + r;
                    ushx4 vh;
                    #pragma unroll
                    for (int q = 0; q < 4; ++q) vh[q] = f2bf(eluf_fast(acc[a][m][q] + bb[q]));
                    *(ushx4*)(Hh + row * 256 + (n0 ^ (8 * (row & 7)))) = vh;
                }
            }
        }
    }
    __syncthreads();

    // ---------- layer 3: 256 -> 128 ----------
    {
        #pragma unroll
        for (int a = 0; a < 2; ++a)
            #pragma unroll
            for (int m = 0; m < 4; ++m) acc3[a][m] = f32x4{0.f, 0.f, 0.f, 0.f};
        #pragma unroll 1
        for (int kb = 0; kb < 8; ++kb) {
            bf16x8 wh[2];
            #pragma unroll
            for (int a = 0; a < 2; ++a)
                wh[a] = *(const bf16x8*)(P.w3h + ((size_t)(kb * 8 + (wv * 2 + a)) * 64 + lane) * 8);
            #pragma unroll
            for (int m = 0; m < 4; ++m) {
                if (m < MB) {
                    const int row = 16 * m + r;
                    const int k0 = kb * 32 + 8 * g;
                    bf16x8 hh = *(const bf16x8*)(Hh + row * 256 + (k0 ^ (8 * (row & 7))));
                    #pragma unroll
                    for (int a = 0; a < 2; ++a) acc3[a][m] = MFMA(wh[a], hh, acc3[a][m]);
                }
            }
        }
    }
}

// ---------------------------------------------------------------------------
// Weight pre-pack: f32 -> (hi, lo) bf16 fragment order.
// ---------------------------------------------------------------------------
struct PackDesc { const float* src; ush* dh; ush* dl; int kreal; int kbn; int nbn; };
struct PackArgs { PackDesc d[15]; };

__global__ __launch_bounds__(256) void pack_kernel(PackArgs pa)
{
    const PackDesc d = pa.d[blockIdx.y];
    const int total = d.kbn * d.nbn * 512;
    const int N = d.nbn * 16;
    for (int idx = blockIdx.x * 256 + threadIdx.x; idx < total; idx += gridDim.x * 256) {
        const int e = idx & 7;
        const int l = (idx >> 3) & 63;
        const int t2 = idx >> 9;
        const int nb = t2 % d.nbn;
        const int kb = t2 / d.nbn;
        const int k = kb * 32 + ((l >> 4) << 3) + e;
        const int n = nb * 16 + (l & 15);
        const float v = (k < d.kreal) ? d.src[(size_t)k * N + n] : 0.f;
        const ush hi = f2bf(v);
        d.dh[idx] = hi;
        d.dl[idx] = f2bf(v - bf2f(hi));
    }
}

// ---------------------------------------------------------------------------
// f1z = MLP0(0) through the EXACT single-plane code path (one block).
// ---------------------------------------------------------------------------
__global__ __launch_bounds__(256) void zero_f1_kernel(MlpPack P, float* __restrict__ f1z)
{
    __shared__ ush Xh[64 * 32];
    __shared__ ush Hh[64 * 256];
    const int tid = threadIdx.x;
    for (int idx = tid; idx < 64 * 32; idx += 256) Xh[idx] = 0;
    __syncthreads();
    f32x4 acc3[2][4];
    mlp3_core_1p(P, 1, Xh, Hh, acc3);
    const int wv = tid >> 6, lane = tid & 63, r = lane & 15, g = lane >> 4;
    if (r == 0) {
        #pragma unroll
        for (int a = 0; a < 2; ++a) {
            const int n0 = (wv * 2 + a) * 16 + 4 * g;
            const float4 bv = *(const float4*)(P.b3 + n0);
            f1z[n0 + 0] = acc3[a][0][0] + bv.x;
            f1z[n0 + 1] = acc3[a][0][1] + bv.y;
            f1z[n0 + 2] = acc3[a][0][2] + bv.z;
            f1z[n0 + 3] = acc3[a][0][3] + bv.w;
        }
    }
}

// ---------------------------------------------------------------------------
// pre/sub/self/MLP4 path (hi/lo core, unchanged).
// ---------------------------------------------------------------------------
template<int KB1, int KINR>
__global__ __launch_bounds__(256) void mlp_f1_kernel(
    const float* __restrict__ Xg, MlpPack P, const float* __restrict__ attn,
    float* __restrict__ f1_out, float* __restrict__ ut_out)
{
    constexpr int KX = KB1 * 32;
    __shared__ ush Xh[64 * KX], Xl[64 * KX];
    __shared__ ush Hh[64 * 256], Hl[64 * 256];
    __shared__ float UT[64];
    const int tid = threadIdx.x;
    const int row0 = blockIdx.x * 64;
    if (tid < 64) UT[tid] = 0.f;
    for (int idx = tid; idx < 64 * KX; idx += 256) {
        const int row = idx / KX, k = idx % KX;
        float v = 0.f;
        if (k < KINR) v = Xg[(size_t)(row0 + row) * KINR + k];
        const ush hi = f2bf(v);
        Xh[idx] = hi;
        Xl[idx] = f2bf(v - bf2f(hi));
    }
    __syncthreads();
    f32x4 acc3[2][4];
    mlp3_core<KB1>(P, Xh, Xl, Hh, Hl, acc3);

    const int wv = tid >> 6, lane = tid & 63, r = lane & 15, g = lane >> 4;
    float utp[4] = {0.f, 0.f, 0.f, 0.f};
    #pragma unroll
    for (int a = 0; a < 2; ++a) {
        const int n0 = (wv * 2 + a) * 16 + 4 * g;
        const float4 bv = *(const float4*)(P.b3 + n0);
        const float4 av = *(const float4*)(attn + n0);
        #pragma unroll
        for (int m = 0; m < 4; ++m) {
            float4 y;
            y.x = acc3[a][m][0] + bv.x;
            y.y = acc3[a][m][1] + bv.y;
            y.z = acc3[a][m][2] + bv.z;
            y.w = acc3[a][m][3] + bv.w;
            *(float4*)&f1_out[(size_t)(row0 + 16 * m + r) * OUTc + n0] = y;
            utp[m] += y.x * av.x + y.y * av.y + y.z * av.z + y.w * av.w;
        }
    }
    #pragma unroll
    for (int m = 0; m < 4; ++m) {
        float v = utp[m];
        v += __shfl_xor(v, 16);
        v += __shfl_xor(v, 32);
        if (lane < 16) atomicAdd(&UT[16 * m + r], v);
    }
    __syncthreads();
    if (tid < 64) ut_out[row0 + tid] = UT[tid];
}

// ---------------------------------------------------------------------------
// ma path: compact active edges (ballot), single-plane MLP0 on MB m-blocks,
// masked mean-pool + (64-na)*f1z correction -> x2.
// ---------------------------------------------------------------------------
__global__ __launch_bounds__(256) void ma_mlp0_kernel(
    const float* __restrict__ ma, const float* __restrict__ eg,
    const int* __restrict__ ma_adj, const int* __restrict__ bidx,
    MlpPack P, const float* __restrict__ f1z, float* __restrict__ x2_out)
{
    __shared__ ush Xh[64 * 32];
    __shared__ ush Hh[64 * 256];
    __shared__ float SUM[128], CNT[128];
    __shared__ int idxs[64];
    __shared__ int naSh;
    const int i = blockIdx.x, b = blockIdx.y;
    const int tid = threadIdx.x;
    const int bi = bidx[b];
    if (tid < 128) { SUM[tid] = 0.f; CNT[tid] = 0.f; }
    const int* adjr = ma_adj + ((size_t)bi * NOPc + i) * NMAc;
    if (tid < 64) {
        const int active = (adjr[tid] != 0) ? 1 : 0;
        const unsigned long long mk = __ballot(active);
        if (active) {
            const int pos = __popcll(mk & ((1ull << tid) - 1ull));
            idxs[pos] = tid;
        }
        if (tid == 0) naSh = (int)__popcll(mk);
    }
    __syncthreads();
    const int na = naSh;
    const int MB = (na + 15) >> 4;

    // stage: row r (compacted) = edge idxs[r]; cols 0..7 = ma, 8..15 = eg, 16..31 = 0
    {
        const int r = tid >> 2, qt = tid & 3;
        ushx8 v = {0, 0, 0, 0, 0, 0, 0, 0};
        if (r < na && qt < 2) {
            const int j = idxs[r];
            const float4* src = (qt == 0)
                ? (const float4*)(ma + ((size_t)b * NMAc + j) * 8)
                : (const float4*)(eg + (((size_t)b * NOPc + i) * NMAc + j) * 8);
            const float4 s0 = src[0], s1 = src[1];
            v[0] = f2bf(s0.x); v[1] = f2bf(s0.y); v[2] = f2bf(s0.z); v[3] = f2bf(s0.w);
            v[4] = f2bf(s1.x); v[5] = f2bf(s1.y); v[6] = f2bf(s1.z); v[7] = f2bf(s1.w);
        }
        *(ushx8*)(Xh + r * 32 + 8 * qt) = v;
    }
    __syncthreads();

    f32x4 acc3[2][4];
    mlp3_core_1p(P, MB, Xh, Hh, acc3);

    const int wv = tid >> 6, lane = tid & 63, r = lane & 15, g = lane >> 4;
    #pragma unroll
    for (int a = 0; a < 2; ++a) {
        const int n0 = (wv * 2 + a) * 16 + 4 * g;
        const float4 bv = *(const float4*)(P.b3 + n0);
        const float bb[4] = {bv.x, bv.y, bv.z, bv.w};
        float s[4] = {0.f, 0.f, 0.f, 0.f}, c[4] = {0.f, 0.f, 0.f, 0.f};
        #pragma unroll
        for (int m = 0; m < 4; ++m) {
            if (m < MB) {
                const int row = 16 * m + r;
                const float ok = (row < na) ? 1.f : 0.f;
                #pragma unroll
                for (int q = 0; q < 4; ++q) {
                    const float y = acc3[a][m][q] + bb[q];
                    s[q] += ok * y;
                    c[q] += ok * ((y != 0.f) ? 1.f : 0.f);
                }
            }
        }
        #pragma unroll
        for (int q = 0; q < 4; ++q) {
            float sv = s[q], cv = c[q];
            #pragma unroll
            for (int o = 1; o < 16; o <<= 1) { sv += __shfl_xor(sv, o); cv += __shfl_xor(cv, o); }
            if (r == 0) { atomicAdd(&SUM[n0 + q], sv); atomicAdd(&CNT[n0 + q], cv); }
        }
    }
    __syncthreads();
    if (tid < 128) {
        const float fz = f1z[tid];
        const float nz = (float)(64 - na);
        const float s = SUM[tid] + nz * fz;
        const float c = CNT[tid] + nz * ((fz != 0.f) ? 1.f : 0.f);
        x2_out[((size_t)b * NOPc + i) * 128 + tid] = s / c;
    }
}

// ---------------------------------------------------------------------------
// pre_agg / sub_agg: adjacency-gated row sums of op. One block per (i, b).
// ---------------------------------------------------------------------------
__global__ __launch_bounds__(256) void agg_kernel(const float* __restrict__ op,
                                                  const int* __restrict__ pre_adj,
                                                  const int* __restrict__ sub_adj,
                                                  const int* __restrict__ bidx,
                                                  float* __restrict__ pre_agg,
                                                  float* __restrict__ sub_agg)
{
    const int i = blockIdx.x, b = blockIdx.y;
    const int bi = bidx[b];
    const int t = threadIdx.x, d = t & 15, g = t >> 4;
    const int* pr = pre_adj + ((size_t)bi * NOPc + i) * NOPc;
    const int* sr = sub_adj + ((size_t)bi * NOPc + i) * NOPc;
    const float* opb = op + (size_t)b * NOPc * 16;
    float ap = 0.f, as = 0.f;
    for (int j = g; j < NOPc; j += 16) {
        const float v = opb[j * 16 + d];
        if (pr[j]) ap += v;
        if (sr[j]) as += v;
    }
    __shared__ float red[2][16][16];
    red[0][g][d] = ap;
    red[1][g][d] = as;
    __syncthreads();
    if (t < 32) {
        const int which = t >> 4, dd = t & 15;
        float s = 0.f;
        #pragma unroll
        for (int gg = 0; gg < 16; ++gg) s += red[which][gg][dd];
        float* dst = which ? sub_agg : pre_agg;
        dst[((size_t)b * NOPc + i) * 16 + dd] = s;
    }
}

// ---------------------------------------------------------------------------
// Per-batch joint softmax over the 4*NOP scores + sigmoid combine.
// ---------------------------------------------------------------------------
__global__ __launch_bounds__(256) void final_kernel(const float* __restrict__ pre_f1,
                                                    const float* __restrict__ sub_f1,
                                                    const float* __restrict__ self_f1,
                                                    const float* __restrict__ ma_f2,
                                                    const float* __restrict__ uts,
                                                    float* __restrict__ out)
{
    const int b = blockIdx.x, t = threadIdx.x;
    __shared__ float sc[4 * NOPc];
    __shared__ float red[256];
    const float* put = uts + 0 * NBb * NOPc + (size_t)b * NOPc;
    const float* sut = uts + 1 * NBb * NOPc + (size_t)b * NOPc;
    const float* eut = uts + 2 * NBb * NOPc + (size_t)b * NOPc;
    const float* mut = uts + 3 * NBb * NOPc + (size_t)b * NOPc;
    for (int i = t; i < NOPc; i += 256) {
        const float se = eut[i];
        const float s0 = put[i] + se, s1 = sut[i] + se, s2 = se + se, s3 = mut[i] + se;
        sc[0 * NOPc + i] = s0 > 0.f ? s0 : 0.2f * s0;
        sc[1 * NOPc + i] = s1 > 0.f ? s1 : 0.2f * s1;
        sc[2 * NOPc + i] = s2 > 0.f ? s2 : 0.2f * s2;
        sc[3 * NOPc + i] = s3 > 0.f ? s3 : 0.2f * s3;
    }
    __syncthreads();
    float mx = -INFINITY;
    for (int idx = t; idx < 4 * NOPc; idx += 256) mx = fmaxf(mx, sc[idx]);
    red[t] = mx;
    __syncthreads();
    for (int s = 128; s > 0; s >>= 1) { if (t < s) red[t] = fmaxf(red[t], red[t + s]); __syncthreads(); }
    mx = red[0];
    __syncthreads();
    float ps = 0.f;
    for (int idx = t; idx < 4 * NOPc; idx += 256) {
        const float e = expf(sc[idx] - mx);
        sc[idx] = e;
        ps += e;
    }
    red[t] = ps;
    __syncthreads();
    for (int s = 128; s > 0; s >>= 1) { if (t < s) red[t] += red[t + s]; __syncthreads(); }
    const float invZ = 1.f / red[0];
    const size_t base = (size_t)b * NOPc * OUTc;
    for (int idx = t; idx < NOPc * OUTc; idx += 256) {
        const int i = idx >> 7;
        const float v = (sc[i] * pre_f1[base + idx] + sc[NOPc + i] * sub_f1[base + idx]
                       + sc[2 * NOPc + i] * self_f1[base + idx] + sc[3 * NOPc + i] * ma_f2[base + idx]) * invZ;
        out[base + idx] = 1.f / (1.f + expf(-v));
    }
}

extern "C" void kernel_launch(void* const* d_in, const int* in_sizes, int n_in,
                              void* d_out, int out_size, void* d_ws, size_t ws_size,
                              hipStream_t stream) {
    const float* op      = (const float*)d_in[0];
    const float* ma      = (const float*)d_in[1];
    const float* eg      = (const float*)d_in[2];
    const int*   ma_adj  = (const int*)d_in[3];
    const int*   pre_adj = (const int*)d_in[4];
    const int*   sub_adj = (const int*)d_in[5];
    const int*   bidx    = (const int*)d_in[6];
    const float* attn    = (const float*)d_in[7];
    float* out = (float*)d_out;
    const float* Wraw[5][6];
    for (int m = 0; m < 5; ++m)
        for (int j = 0; j < 6; ++j)
            Wraw[m][j] = (const float*)d_in[8 + 6 * m + j];

    // ---- workspace layout ----
    float* wsf = (float*)d_ws;
    float* pre_agg = wsf;  wsf += (size_t)NBb * NOPc * 16;
    float* sub_agg = wsf;  wsf += (size_t)NBb * NOPc * 16;
    float* pre_f1  = wsf;  wsf += (size_t)NBb * NOPc * OUTc;
    float* sub_f1  = wsf;  wsf += (size_t)NBb * NOPc * OUTc;
    float* self_f1 = wsf;  wsf += (size_t)NBb * NOPc * OUTc;
    float* ma_f2   = wsf;  wsf += (size_t)NBb * NOPc * OUTc;
    float* x2      = wsf;  wsf += (size_t)NBb * NOPc * OUTc;
    float* uts     = wsf;  wsf += (size_t)4 * NBb * NOPc;
    float* f1z     = wsf;  wsf += 128;
    ush* packp = (ush*)wsf;

    PackArgs pa;
    MlpPack pk[5];
    for (int m = 0; m < 5; ++m) {
        const int kre[3] = { (m == 4 ? 128 : 16), 256, 256 };
        const int kbn[3] = { (m == 4 ? 4 : 1), 8, 8 };
        const int nbn[3] = { 16, 16, 8 };
        const ush* dh[3]; const ush* dl[3];
        for (int j = 0; j < 3; ++j) {
            const int id = m * 3 + j;
            pa.d[id].src = Wraw[m][2 * j];     // w1, w2, w3
            pa.d[id].kreal = kre[j];
            pa.d[id].kbn = kbn[j];
            pa.d[id].nbn = nbn[j];
            const int cnt = kbn[j] * nbn[j] * 512;
            pa.d[id].dh = packp; dh[j] = packp; packp += cnt;
            pa.d[id].dl = packp; dl[j] = packp; packp += cnt;
        }
        pk[m].w1h = dh[0]; pk[m].w1l = dl[0];
        pk[m].w2h = dh[1]; pk[m].w2l = dl[1];
        pk[m].w3h = dh[2]; pk[m].w3l = dl[2];
        pk[m].b1 = Wraw[m][1]; pk[m].b2 = Wraw[m][3]; pk[m].b3 = Wraw[m][5];
    }

    pack_kernel<<<dim3(64, 15), 256, 0, stream>>>(pa);
    zero_f1_kernel<<<1, 256, 0, stream>>>(pk[0], f1z);
    agg_kernel<<<dim3(NOPc, NBb), 256, 0, stream>>>(op, pre_adj, sub_adj, bidx, pre_agg, sub_agg);
    mlp_f1_kernel<1, 16><<<dim3(128), 256, 0, stream>>>(pre_agg, pk[1], attn, pre_f1, uts + 0 * NBb * NOPc);
    mlp_f1_kernel<1, 16><<<dim3(128), 256, 0, stream>>>(sub_agg, pk[2], attn, sub_f1, uts + 1 * NBb * NOPc);
    mlp_f1_kernel<1, 16><<<dim3(128), 256, 0, stream>>>(op,      pk[3], attn, self_f1, uts + 2 * NBb * NOPc);
    ma_mlp0_kernel<<<dim3(NOPc, NBb), 256, 0, stream>>>(ma, eg, ma_adj, bidx, pk[0], f1z, x2);
    mlp_f1_kernel<4, 128><<<dim3(128), 256, 0, stream>>>(x2, pk[4], attn, ma_f2, uts + 3 * NBb * NOPc);
    final_kernel<<<NBb, 256, 0, stream>>>(pre_f1, sub_f1, self_f1, ma_f2, uts, out);
}

// Round 5
// 301.596 us; speedup vs baseline: 6.8854x; 1.3117x over previous
//
#include <hip/hip_runtime.h>
#include <math.h>

#define NBb  16
#define NOPc 512
#define NMAc 64
#define HIDc 256
#define OUTc 128

typedef unsigned int uint32;
typedef unsigned short ush;
typedef __attribute__((ext_vector_type(8))) short bf16x8;
typedef __attribute__((ext_vector_type(4))) float f32x4;
typedef __attribute__((ext_vector_type(4))) ush ushx4;
typedef __attribute__((ext_vector_type(8))) ush ushx8;

__device__ __forceinline__ ush f2bf(float v) {
    uint32 u = __float_as_uint(v);
    u += 0x7FFFu + ((u >> 16) & 1u);
    return (ush)(u >> 16);
}
__device__ __forceinline__ float bf2f(ush b) { return __uint_as_float(((uint32)b) << 16); }
__device__ __forceinline__ float eluf(float x) { return x > 0.f ? x : expm1f(x); }
__device__ __forceinline__ float eluf_fast(float x) { return x > 0.f ? x : __expf(x) - 1.f; }

#define MFMA(A, B, C) __builtin_amdgcn_mfma_f32_16x16x32_bf16((A), (B), (C), 0, 0, 0)

// pack[((kb*nbn + nb)*64 + lane)*8 + e] = W[kb*32 + 8*(lane>>4) + e][nb*16 + (lane&15)]
struct MlpPack {
    const ush *w1h, *w1l, *w2h, *w2l, *w3h, *w3l;
    const float *b1, *b2, *b3;
};

// ---------------------------------------------------------------------------
// Hi/lo (bf16x3) 3-layer core (pre/sub/self/MLP4 — large-magnitude operands).
// ---------------------------------------------------------------------------
template<int KB1>
__device__ __forceinline__ void mlp3_core(
    const MlpPack& P,
    const ush* Xh, const ush* Xl, ush* Hh, ush* Hl, f32x4 acc3[2][4])
{
    const int tid = threadIdx.x;
    const int wv = tid >> 6, lane = tid & 63, r = lane & 15, g = lane >> 4;
    constexpr int KX = KB1 * 32;

    // layer 1
    {
        f32x4 acc[4][4];
        #pragma unroll
        for (int a = 0; a < 4; ++a)
            #pragma unroll
            for (int m = 0; m < 4; ++m) acc[a][m] = f32x4{0.f, 0.f, 0.f, 0.f};
        #pragma unroll 1
        for (int kb = 0; kb < KB1; ++kb) {
            bf16x8 wh[4], wl[4];
            #pragma unroll
            for (int a = 0; a < 4; ++a) {
                const size_t o = ((size_t)(kb * 16 + (wv * 4 + a)) * 64 + lane) * 8;
                wh[a] = *(const bf16x8*)(P.w1h + o);
                wl[a] = *(const bf16x8*)(P.w1l + o);
            }
            #pragma unroll
            for (int m = 0; m < 4; ++m) {
                const int row = 16 * m + r;
                const int ki = kb * 32 + 8 * g;
                bf16x8 xh = *(const bf16x8*)(Xh + row * KX + ki);
                bf16x8 xl = *(const bf16x8*)(Xl + row * KX + ki);
                #pragma unroll
                for (int a = 0; a < 4; ++a) {
                    acc[a][m] = MFMA(wh[a], xh, acc[a][m]);
                    acc[a][m] = MFMA(wh[a], xl, acc[a][m]);
                    acc[a][m] = MFMA(wl[a], xh, acc[a][m]);
                }
            }
        }
        #pragma unroll
        for (int a = 0; a < 4; ++a) {
            const int n0 = (wv * 4 + a) * 16 + 4 * g;
            const float4 bv = *(const float4*)(P.b1 + n0);
            const float bb[4] = {bv.x, bv.y, bv.z, bv.w};
            #pragma unroll
            for (int m = 0; m < 4; ++m) {
                const int row = 16 * m + r;
                ushx4 vh, vl;
                #pragma unroll
                for (int q = 0; q < 4; ++q) {
                    float y = eluf(acc[a][m][q] + bb[q]);
                    const ush hi = f2bf(y);
                    vh[q] = hi;
                    vl[q] = f2bf(y - bf2f(hi));
                }
                const int idx = row * 256 + (n0 ^ (8 * (row & 7)));
                *(ushx4*)(Hh + idx) = vh;
                *(ushx4*)(Hl + idx) = vl;
            }
        }
    }
    __syncthreads();

    // layer 2
    {
        f32x4 acc[4][4];
        #pragma unroll
        for (int a = 0; a < 4; ++a)
            #pragma unroll
            for (int m = 0; m < 4; ++m) acc[a][m] = f32x4{0.f, 0.f, 0.f, 0.f};
        #pragma unroll 1
        for (int kb = 0; kb < 8; ++kb) {
            bf16x8 wh[4], wl[4];
            #pragma unroll
            for (int a = 0; a < 4; ++a) {
                const size_t o = ((size_t)(kb * 16 + (wv * 4 + a)) * 64 + lane) * 8;
                wh[a] = *(const bf16x8*)(P.w2h + o);
                wl[a] = *(const bf16x8*)(P.w2l + o);
            }
            #pragma unroll
            for (int m = 0; m < 4; ++m) {
                const int row = 16 * m + r;
                const int k0 = kb * 32 + 8 * g;
                const int idx = row * 256 + (k0 ^ (8 * (row & 7)));
                bf16x8 hh = *(const bf16x8*)(Hh + idx);
                bf16x8 hl = *(const bf16x8*)(Hl + idx);
                #pragma unroll
                for (int a = 0; a < 4; ++a) {
                    acc[a][m] = MFMA(wh[a], hh, acc[a][m]);
                    acc[a][m] = MFMA(wh[a], hl, acc[a][m]);
                    acc[a][m] = MFMA(wl[a], hh, acc[a][m]);
                }
            }
        }
        __syncthreads();
        #pragma unroll
        for (int a = 0; a < 4; ++a) {
            const int n0 = (wv * 4 + a) * 16 + 4 * g;
            const float4 bv = *(const float4*)(P.b2 + n0);
            const float bb[4] = {bv.x, bv.y, bv.z, bv.w};
            #pragma unroll
            for (int m = 0; m < 4; ++m) {
                const int row = 16 * m + r;
                ushx4 vh, vl;
                #pragma unroll
                for (int q = 0; q < 4; ++q) {
                    float y = eluf(acc[a][m][q] + bb[q]);
                    const ush hi = f2bf(y);
                    vh[q] = hi;
                    vl[q] = f2bf(y - bf2f(hi));
                }
                const int idx = row * 256 + (n0 ^ (8 * (row & 7)));
                *(ushx4*)(Hh + idx) = vh;
                *(ushx4*)(Hl + idx) = vl;
            }
        }
    }
    __syncthreads();

    // layer 3
    {
        #pragma unroll
        for (int a = 0; a < 2; ++a)
            #pragma unroll
            for (int m = 0; m < 4; ++m) acc3[a][m] = f32x4{0.f, 0.f, 0.f, 0.f};
        #pragma unroll 1
        for (int kb = 0; kb < 8; ++kb) {
            bf16x8 wh[2], wl[2];
            #pragma unroll
            for (int a = 0; a < 2; ++a) {
                const size_t o = ((size_t)(kb * 8 + (wv * 2 + a)) * 64 + lane) * 8;
                wh[a] = *(const bf16x8*)(P.w3h + o);
                wl[a] = *(const bf16x8*)(P.w3l + o);
            }
            #pragma unroll
            for (int m = 0; m < 4; ++m) {
                const int row = 16 * m + r;
                const int k0 = kb * 32 + 8 * g;
                const int idx = row * 256 + (k0 ^ (8 * (row & 7)));
                bf16x8 hh = *(const bf16x8*)(Hh + idx);
                bf16x8 hl = *(const bf16x8*)(Hl + idx);
                #pragma unroll
                for (int a = 0; a < 2; ++a) {
                    acc3[a][m] = MFMA(wh[a], hh, acc3[a][m]);
                    acc3[a][m] = MFMA(wh[a], hl, acc3[a][m]);
                    acc3[a][m] = MFMA(wl[a], hh, acc3[a][m]);
                }
            }
        }
    }
}

// ---------------------------------------------------------------------------
// Single-plane bf16 core, KX=32, m-block skip (wave-uniform MB).
// ---------------------------------------------------------------------------
__device__ __forceinline__ void mlp3_core_1p(
    const MlpPack& P, const int MB,
    const ush* Xh, ush* Hh, f32x4 acc3[2][4])
{
    const int tid = threadIdx.x;
    const int wv = tid >> 6, lane = tid & 63, r = lane & 15, g = lane >> 4;

    // layer 1: 32 -> 256
    {
        f32x4 acc[4][4];
        #pragma unroll
        for (int a = 0; a < 4; ++a)
            #pragma unroll
            for (int m = 0; m < 4; ++m) acc[a][m] = f32x4{0.f, 0.f, 0.f, 0.f};
        bf16x8 wh[4];
        #pragma unroll
        for (int a = 0; a < 4; ++a)
            wh[a] = *(const bf16x8*)(P.w1h + ((size_t)(wv * 4 + a) * 64 + lane) * 8);
        #pragma unroll
        for (int m = 0; m < 4; ++m) {
            if (m < MB) {
                const int row = 16 * m + r;
                bf16x8 xh = *(const bf16x8*)(Xh + row * 32 + 8 * g);
                #pragma unroll
                for (int a = 0; a < 4; ++a) acc[a][m] = MFMA(wh[a], xh, acc[a][m]);
            }
        }
        #pragma unroll
        for (int a = 0; a < 4; ++a) {
            const int n0 = (wv * 4 + a) * 16 + 4 * g;
            const float4 bv = *(const float4*)(P.b1 + n0);
            const float bb[4] = {bv.x, bv.y, bv.z, bv.w};
            #pragma unroll
            for (int m = 0; m < 4; ++m) {
                if (m < MB) {
                    const int row = 16 * m + r;
                    ushx4 vh;
                    #pragma unroll
                    for (int q = 0; q < 4; ++q) vh[q] = f2bf(eluf_fast(acc[a][m][q] + bb[q]));
                    *(ushx4*)(Hh + row * 256 + (n0 ^ (8 * (row & 7)))) = vh;
                }
            }
        }
    }
    __syncthreads();

    // layer 2: 256 -> 256
    {
        f32x4 acc[4][4];
        #pragma unroll
        for (int a = 0; a < 4; ++a)
            #pragma unroll
            for (int m = 0; m < 4; ++m) acc[a][m] = f32x4{0.f, 0.f, 0.f, 0.f};
        #pragma unroll 1
        for (int kb = 0; kb < 8; ++kb) {
            bf16x8 wh[4];
            #pragma unroll
            for (int a = 0; a < 4; ++a)
                wh[a] = *(const bf16x8*)(P.w2h + ((size_t)(kb * 16 + (wv * 4 + a)) * 64 + lane) * 8);
            #pragma unroll
            for (int m = 0; m < 4; ++m) {
                if (m < MB) {
                    const int row = 16 * m + r;
                    const int k0 = kb * 32 + 8 * g;
                    bf16x8 hh = *(const bf16x8*)(Hh + row * 256 + (k0 ^ (8 * (row & 7))));
                    #pragma unroll
                    for (int a = 0; a < 4; ++a) acc[a][m] = MFMA(wh[a], hh, acc[a][m]);
                }
            }
        }
        __syncthreads();
        #pragma unroll
        for (int a = 0; a < 4; ++a) {
            const int n0 = (wv * 4 + a) * 16 + 4 * g;
            const float4 bv = *(const float4*)(P.b2 + n0);
            const float bb[4] = {bv.x, bv.y, bv.z, bv.w};
            #pragma unroll
            for (int m = 0; m < 4; ++m) {
                if (m < MB) {
                    const int row = 16 * m + r;
                    ushx4 vh;
                    #pragma unroll
                    for (int q = 0; q < 4; ++q) vh[q] = f2bf(eluf_fast(acc[a][m][q] + bb[q]));
                    *(ushx4*)(Hh + row * 256 + (n0 ^ (8 * (row & 7)))) = vh;
                }
            }
        }
    }
    __syncthreads();

    // layer 3: 256 -> 128
    {
        #pragma unroll
        for (int a = 0; a < 2; ++a)
            #pragma unroll
            for (int m = 0; m < 4; ++m) acc3[a][m] = f32x4{0.f, 0.f, 0.f, 0.f};
        #pragma unroll 1
        for (int kb = 0; kb < 8; ++kb) {
            bf16x8 wh[2];
            #pragma unroll
            for (int a = 0; a < 2; ++a)
                wh[a] = *(const bf16x8*)(P.w3h + ((size_t)(kb * 8 + (wv * 2 + a)) * 64 + lane) * 8);
            #pragma unroll
            for (int m = 0; m < 4; ++m) {
                if (m < MB) {
                    const int row = 16 * m + r;
                    const int k0 = kb * 32 + 8 * g;
                    bf16x8 hh = *(const bf16x8*)(Hh + row * 256 + (k0 ^ (8 * (row & 7))));
                    #pragma unroll
                    for (int a = 0; a < 2; ++a) acc3[a][m] = MFMA(wh[a], hh, acc3[a][m]);
                }
            }
        }
    }
}

// ---------------------------------------------------------------------------
// Weight pre-pack.
// ---------------------------------------------------------------------------
struct PackDesc { const float* src; ush* dh; ush* dl; int kreal; int kbn; int nbn; };
struct PackArgs { PackDesc d[15]; };

__global__ __launch_bounds__(256) void pack_kernel(PackArgs pa)
{
    const PackDesc d = pa.d[blockIdx.y];
    const int total = d.kbn * d.nbn * 512;
    const int N = d.nbn * 16;
    for (int idx = blockIdx.x * 256 + threadIdx.x; idx < total; idx += gridDim.x * 256) {
        const int e = idx & 7;
        const int l = (idx >> 3) & 63;
        const int t2 = idx >> 9;
        const int nb = t2 % d.nbn;
        const int kb = t2 / d.nbn;
        const int k = kb * 32 + ((l >> 4) << 3) + e;
        const int n = nb * 16 + (l & 15);
        const float v = (k < d.kreal) ? d.src[(size_t)k * N + n] : 0.f;
        const ush hi = f2bf(v);
        d.dh[idx] = hi;
        d.dl[idx] = f2bf(v - bf2f(hi));
    }
}

// ---------------------------------------------------------------------------
// f1z = MLP0(0) via the exact single-plane path (one block).
// ---------------------------------------------------------------------------
__global__ __launch_bounds__(256) void zero_f1_kernel(MlpPack P, float* __restrict__ f1z)
{
    __shared__ ush Xh[64 * 32];
    __shared__ ush Hh[64 * 256];
    const int tid = threadIdx.x;
    for (int idx = tid; idx < 64 * 32; idx += 256) Xh[idx] = 0;
    __syncthreads();
    f32x4 acc3[2][4];
    mlp3_core_1p(P, 1, Xh, Hh, acc3);
    const int wv = tid >> 6, lane = tid & 63, r = lane & 15, g = lane >> 4;
    if (r == 0) {
        #pragma unroll
        for (int a = 0; a < 2; ++a) {
            const int n0 = (wv * 2 + a) * 16 + 4 * g;
            const float4 bv = *(const float4*)(P.b3 + n0);
            f1z[n0 + 0] = acc3[a][0][0] + bv.x;
            f1z[n0 + 1] = acc3[a][0][1] + bv.y;
            f1z[n0 + 2] = acc3[a][0][2] + bv.z;
            f1z[n0 + 3] = acc3[a][0][3] + bv.w;
        }
    }
}

// ---------------------------------------------------------------------------
// Fused pre/sub/self f1 kernel: blockIdx.y selects path (hi/lo core).
// ---------------------------------------------------------------------------
struct F1Args { const float* X[3]; MlpPack P[3]; float* f1[3]; float* ut[3]; };

__global__ __launch_bounds__(256) void mlp_f1_fused(F1Args A, const float* __restrict__ attn)
{
    __shared__ ush Xh[64 * 32], Xl[64 * 32];
    __shared__ ush Hh[64 * 256], Hl[64 * 256];
    __shared__ float UT[64];
    const int p = blockIdx.y;
    const float* Xg = A.X[p];
    const MlpPack P = A.P[p];
    float* f1_out = A.f1[p];
    float* ut_out = A.ut[p];
    const int tid = threadIdx.x;
    const int row0 = blockIdx.x * 64;
    if (tid < 64) UT[tid] = 0.f;
    for (int idx = tid; idx < 64 * 32; idx += 256) {
        const int row = idx >> 5, k = idx & 31;
        float v = 0.f;
        if (k < 16) v = Xg[(size_t)(row0 + row) * 16 + k];
        const ush hi = f2bf(v);
        Xh[idx] = hi;
        Xl[idx] = f2bf(v - bf2f(hi));
    }
    __syncthreads();
    f32x4 acc3[2][4];
    mlp3_core<1>(P, Xh, Xl, Hh, Hl, acc3);

    const int wv = tid >> 6, lane = tid & 63, r = lane & 15, g = lane >> 4;
    float utp[4] = {0.f, 0.f, 0.f, 0.f};
    #pragma unroll
    for (int a = 0; a < 2; ++a) {
        const int n0 = (wv * 2 + a) * 16 + 4 * g;
        const float4 bv = *(const float4*)(P.b3 + n0);
        const float4 av = *(const float4*)(attn + n0);
        #pragma unroll
        for (int m = 0; m < 4; ++m) {
            float4 y;
            y.x = acc3[a][m][0] + bv.x;
            y.y = acc3[a][m][1] + bv.y;
            y.z = acc3[a][m][2] + bv.z;
            y.w = acc3[a][m][3] + bv.w;
            *(float4*)&f1_out[(size_t)(row0 + 16 * m + r) * OUTc + n0] = y;
            utp[m] += y.x * av.x + y.y * av.y + y.z * av.z + y.w * av.w;
        }
    }
    #pragma unroll
    for (int m = 0; m < 4; ++m) {
        float v = utp[m];
        v += __shfl_xor(v, 16);
        v += __shfl_xor(v, 32);
        if (lane < 16) atomicAdd(&UT[16 * m + r], v);
    }
    __syncthreads();
    if (tid < 64) ut_out[row0 + tid] = UT[tid];
}

// ---------------------------------------------------------------------------
// MLP4 path (hi/lo core, KB1=4, KINR=128).
// ---------------------------------------------------------------------------
__global__ __launch_bounds__(256) void mlp4_kernel(
    const float* __restrict__ Xg, MlpPack P, const float* __restrict__ attn,
    float* __restrict__ f1_out, float* __restrict__ ut_out)
{
    constexpr int KX = 128;
    __shared__ ush Xh[64 * KX], Xl[64 * KX];
    __shared__ ush Hh[64 * 256], Hl[64 * 256];
    __shared__ float UT[64];
    const int tid = threadIdx.x;
    const int row0 = blockIdx.x * 64;
    if (tid < 64) UT[tid] = 0.f;
    for (int idx = tid; idx < 64 * KX; idx += 256) {
        const float v = Xg[(size_t)row0 * KX + idx];
        const ush hi = f2bf(v);
        Xh[idx] = hi;
        Xl[idx] = f2bf(v - bf2f(hi));
    }
    __syncthreads();
    f32x4 acc3[2][4];
    mlp3_core<4>(P, Xh, Xl, Hh, Hl, acc3);

    const int wv = tid >> 6, lane = tid & 63, r = lane & 15, g = lane >> 4;
    float utp[4] = {0.f, 0.f, 0.f, 0.f};
    #pragma unroll
    for (int a = 0; a < 2; ++a) {
        const int n0 = (wv * 2 + a) * 16 + 4 * g;
        const float4 bv = *(const float4*)(P.b3 + n0);
        const float4 av = *(const float4*)(attn + n0);
        #pragma unroll
        for (int m = 0; m < 4; ++m) {
            float4 y;
            y.x = acc3[a][m][0] + bv.x;
            y.y = acc3[a][m][1] + bv.y;
            y.z = acc3[a][m][2] + bv.z;
            y.w = acc3[a][m][3] + bv.w;
            *(float4*)&f1_out[(size_t)(row0 + 16 * m + r) * OUTc + n0] = y;
            utp[m] += y.x * av.x + y.y * av.y + y.z * av.z + y.w * av.w;
        }
    }
    #pragma unroll
    for (int m = 0; m < 4; ++m) {
        float v = utp[m];
        v += __shfl_xor(v, 16);
        v += __shfl_xor(v, 32);
        if (lane < 16) atomicAdd(&UT[16 * m + r], v);
    }
    __syncthreads();
    if (tid < 64) ut_out[row0 + tid] = UT[tid];
}

// ---------------------------------------------------------------------------
// ma path v2: one block per (b, 8-i group). Compact active edges of the
// group into a row queue; full 64-row tiles through the single-plane core;
// segmented pooling via LDS f1 buffer (aliased onto Hh) + LDS atomics.
// ---------------------------------------------------------------------------
__global__ __launch_bounds__(256) void ma_mlp0_v2_kernel(
    const float* __restrict__ ma, const float* __restrict__ eg,
    const int* __restrict__ ma_adj, const int* __restrict__ bidx,
    MlpPack P, const float* __restrict__ f1z, float* __restrict__ x2_out)
{
    __shared__ ush Xh[64 * 32];
    __shared__ ush Hh[64 * 256];            // aliased as f32 f1buf[64][128] after L3
    __shared__ float SUM2[8 * 128], CNT2[8 * 128];
    __shared__ unsigned long long masks[8];
    __shared__ int naA[8], base[8];
    __shared__ unsigned char rowi[512], rowj[512];
    __shared__ int NAsh;

    const int i0 = blockIdx.x * 8, b = blockIdx.y;
    const int tid = threadIdx.x;
    const int wv = tid >> 6, lane = tid & 63, r = lane & 15, g = lane >> 4;
    const int bi = bidx[b];

    for (int idx = tid; idx < 1024; idx += 256) { SUM2[idx] = 0.f; CNT2[idx] = 0.f; }

    #pragma unroll
    for (int half = 0; half < 2; ++half) {
        const int ii = wv + 4 * half;
        const int* adjr = ma_adj + ((size_t)bi * NOPc + (i0 + ii)) * NMAc;
        const int active = (adjr[lane] != 0) ? 1 : 0;
        const unsigned long long mk = __ballot(active);
        if (lane == 0) { masks[ii] = mk; naA[ii] = (int)__popcll(mk); }
    }
    __syncthreads();
    if (tid == 0) {
        int s = 0;
        #pragma unroll
        for (int k = 0; k < 8; ++k) { base[k] = s; s += naA[k]; }
        NAsh = s;
    }
    __syncthreads();
    #pragma unroll
    for (int half = 0; half < 2; ++half) {
        const int ii = wv + 4 * half;
        const unsigned long long mk = masks[ii];
        if ((mk >> lane) & 1ull) {
            const int pos = base[ii] + (int)__popcll(mk & ((1ull << lane) - 1ull));
            rowi[pos] = (unsigned char)ii;
            rowj[pos] = (unsigned char)lane;
        }
    }
    __syncthreads();

    const int NA = NAsh;
    for (int c0 = 0; c0 < NA; c0 += 64) {
        const int rows = min(64, NA - c0);
        const int MB = (rows + 15) >> 4;
        // stage compacted rows: cols 0..7 = ma, 8..15 = eg, 16..31 = 0
        {
            const int rl = tid >> 2, qt = tid & 3;
            ushx8 v = {0, 0, 0, 0, 0, 0, 0, 0};
            if (rl < rows && qt < 2) {
                const int rr = c0 + rl;
                const int ii = rowi[rr], j = rowj[rr];
                const float4* src = (qt == 0)
                    ? (const float4*)(ma + ((size_t)b * NMAc + j) * 8)
                    : (const float4*)(eg + (((size_t)b * NOPc + (i0 + ii)) * NMAc + j) * 8);
                const float4 s0 = src[0], s1 = src[1];
                v[0] = f2bf(s0.x); v[1] = f2bf(s0.y); v[2] = f2bf(s0.z); v[3] = f2bf(s0.w);
                v[4] = f2bf(s1.x); v[5] = f2bf(s1.y); v[6] = f2bf(s1.z); v[7] = f2bf(s1.w);
            }
            *(ushx8*)(Xh + rl * 32 + 8 * qt) = v;
        }
        __syncthreads();

        f32x4 acc3[2][4];
        mlp3_core_1p(P, MB, Xh, Hh, acc3);
        __syncthreads();           // all L3 Hh reads complete before alias-write

        float* f1buf = (float*)Hh;
        #pragma unroll
        for (int a = 0; a < 2; ++a) {
            const int n0 = (wv * 2 + a) * 16 + 4 * g;
            const float4 bv = *(const float4*)(P.b3 + n0);
            #pragma unroll
            for (int m = 0; m < 4; ++m) {
                if (m < MB) {
                    const int row = 16 * m + r;
                    float4 y;
                    y.x = acc3[a][m][0] + bv.x;
                    y.y = acc3[a][m][1] + bv.y;
                    y.z = acc3[a][m][2] + bv.z;
                    y.w = acc3[a][m][3] + bv.w;
                    *(float4*)&f1buf[row * 128 + (n0 ^ ((row & 7) << 2))] = y;
                }
            }
        }
        __syncthreads();
        // segmented pooling: thread = (col, row-half); rows sorted by ii
        {
            const int c = tid & 127, h = tid >> 7;
            const int r0p = h * 32, r1p = min(r0p + 32, rows);
            float accS = 0.f, accC = 0.f;
            int curi = -1;
            for (int rl = r0p; rl < r1p; ++rl) {
                const int ii = rowi[c0 + rl];
                if (ii != curi) {
                    if (curi >= 0) {
                        atomicAdd(&SUM2[curi * 128 + c], accS);
                        atomicAdd(&CNT2[curi * 128 + c], accC);
                    }
                    curi = ii; accS = 0.f; accC = 0.f;
                }
                const float y = f1buf[rl * 128 + (c ^ ((rl & 7) << 2))];
                accS += y;
                accC += (y != 0.f) ? 1.f : 0.f;
            }
            if (curi >= 0) {
                atomicAdd(&SUM2[curi * 128 + c], accS);
                atomicAdd(&CNT2[curi * 128 + c], accC);
            }
        }
        __syncthreads();
    }

    for (int idx = tid; idx < 1024; idx += 256) {
        const int ii = idx >> 7, c = idx & 127;
        const float fz = f1z[c];
        const float nz = (float)(64 - naA[ii]);
        const float s = SUM2[idx] + nz * fz;
        const float cn = CNT2[idx] + nz * ((fz != 0.f) ? 1.f : 0.f);
        x2_out[((size_t)b * NOPc + (i0 + ii)) * 128 + c] = s / cn;
    }
}

// ---------------------------------------------------------------------------
// pre_agg / sub_agg.
// ---------------------------------------------------------------------------
__global__ __launch_bounds__(256) void agg_kernel(const float* __restrict__ op,
                                                  const int* __restrict__ pre_adj,
                                                  const int* __restrict__ sub_adj,
                                                  const int* __restrict__ bidx,
                                                  float* __restrict__ pre_agg,
                                                  float* __restrict__ sub_agg)
{
    const int i = blockIdx.x, b = blockIdx.y;
    const int bi = bidx[b];
    const int t = threadIdx.x, d = t & 15, g = t >> 4;
    const int* pr = pre_adj + ((size_t)bi * NOPc + i) * NOPc;
    const int* sr = sub_adj + ((size_t)bi * NOPc + i) * NOPc;
    const float* opb = op + (size_t)b * NOPc * 16;
    float ap = 0.f, as = 0.f;
    for (int j = g; j < NOPc; j += 16) {
        const float v = opb[j * 16 + d];
        if (pr[j]) ap += v;
        if (sr[j]) as += v;
    }
    __shared__ float red[2][16][16];
    red[0][g][d] = ap;
    red[1][g][d] = as;
    __syncthreads();
    if (t < 32) {
        const int which = t >> 4, dd = t & 15;
        float s = 0.f;
        #pragma unroll
        for (int gg = 0; gg < 16; ++gg) s += red[which][gg][dd];
        float* dst = which ? sub_agg : pre_agg;
        dst[((size_t)b * NOPc + i) * 16 + dd] = s;
    }
}

// ---------------------------------------------------------------------------
// scores: per-batch joint softmax -> alpha[b][4][512].
// ---------------------------------------------------------------------------
__global__ __launch_bounds__(256) void scores_kernel(const float* __restrict__ uts,
                                                     float* __restrict__ alpha)
{
    const int b = blockIdx.x, t = threadIdx.x;
    __shared__ float sc[4 * NOPc];
    __shared__ float red[256];
    const float* put = uts + 0 * NBb * NOPc + (size_t)b * NOPc;
    const float* sut = uts + 1 * NBb * NOPc + (size_t)b * NOPc;
    const float* eut = uts + 2 * NBb * NOPc + (size_t)b * NOPc;
    const float* mut = uts + 3 * NBb * NOPc + (size_t)b * NOPc;
    for (int i = t; i < NOPc; i += 256) {
        const float se = eut[i];
        const float s0 = put[i] + se, s1 = sut[i] + se, s2 = se + se, s3 = mut[i] + se;
        sc[0 * NOPc + i] = s0 > 0.f ? s0 : 0.2f * s0;
        sc[1 * NOPc + i] = s1 > 0.f ? s1 : 0.2f * s1;
        sc[2 * NOPc + i] = s2 > 0.f ? s2 : 0.2f * s2;
        sc[3 * NOPc + i] = s3 > 0.f ? s3 : 0.2f * s3;
    }
    __syncthreads();
    float mx = -INFINITY;
    for (int idx = t; idx < 4 * NOPc; idx += 256) mx = fmaxf(mx, sc[idx]);
    red[t] = mx;
    __syncthreads();
    for (int s = 128; s > 0; s >>= 1) { if (t < s) red[t] = fmaxf(red[t], red[t + s]); __syncthreads(); }
    mx = red[0];
    __syncthreads();
    float ps = 0.f;
    for (int idx = t; idx < 4 * NOPc; idx += 256) {
        const float e = expf(sc[idx] - mx);
        sc[idx] = e;
        ps += e;
    }
    red[t] = ps;
    __syncthreads();
    for (int s = 128; s > 0; s >>= 1) { if (t < s) red[t] += red[t + s]; __syncthreads(); }
    const float invZ = 1.f / red[0];
    for (int idx = t; idx < 4 * NOPc; idx += 256)
        alpha[(size_t)b * 4 * NOPc + idx] = sc[idx] * invZ;
}

// ---------------------------------------------------------------------------
// combine: out = sigmoid(Σ alpha_k * f_k). Pure streaming, 1024 blocks.
// ---------------------------------------------------------------------------
__global__ __launch_bounds__(256) void combine_kernel(const float* __restrict__ pre_f1,
                                                      const float* __restrict__ sub_f1,
                                                      const float* __restrict__ self_f1,
                                                      const float* __restrict__ ma_f2,
                                                      const float* __restrict__ alpha,
                                                      float* __restrict__ out)
{
    const size_t e4 = (size_t)blockIdx.x * 256 + threadIdx.x;   // float4 index; grid covers exactly
    const int b = (int)(e4 >> 14);          // 16384 float4 per batch
    const int rem = (int)(e4 & 16383);
    const int i = rem >> 5;                  // 32 float4 per row
    const float* al = alpha + (size_t)b * 4 * NOPc;
    const float a0 = al[0 * NOPc + i], a1 = al[1 * NOPc + i];
    const float a2 = al[2 * NOPc + i], a3 = al[3 * NOPc + i];
    const float4 vp = ((const float4*)pre_f1)[e4];
    const float4 vs = ((const float4*)sub_f1)[e4];
    const float4 ve = ((const float4*)self_f1)[e4];
    const float4 vm = ((const float4*)ma_f2)[e4];
    float4 o;
    o.x = 1.f / (1.f + expf(-(a0 * vp.x + a1 * vs.x + a2 * ve.x + a3 * vm.x)));
    o.y = 1.f / (1.f + expf(-(a0 * vp.y + a1 * vs.y + a2 * ve.y + a3 * vm.y)));
    o.z = 1.f / (1.f + expf(-(a0 * vp.z + a1 * vs.z + a2 * ve.z + a3 * vm.z)));
    o.w = 1.f / (1.f + expf(-(a0 * vp.w + a1 * vs.w + a2 * ve.w + a3 * vm.w)));
    ((float4*)out)[e4] = o;
}

extern "C" void kernel_launch(void* const* d_in, const int* in_sizes, int n_in,
                              void* d_out, int out_size, void* d_ws, size_t ws_size,
                              hipStream_t stream) {
    const float* op      = (const float*)d_in[0];
    const float* ma      = (const float*)d_in[1];
    const float* eg      = (const float*)d_in[2];
    const int*   ma_adj  = (const int*)d_in[3];
    const int*   pre_adj = (const int*)d_in[4];
    const int*   sub_adj = (const int*)d_in[5];
    const int*   bidx    = (const int*)d_in[6];
    const float* attn    = (const float*)d_in[7];
    float* out = (float*)d_out;
    const float* Wraw[5][6];
    for (int m = 0; m < 5; ++m)
        for (int j = 0; j < 6; ++j)
            Wraw[m][j] = (const float*)d_in[8 + 6 * m + j];

    // ---- workspace layout ----
    float* wsf = (float*)d_ws;
    float* pre_agg = wsf;  wsf += (size_t)NBb * NOPc * 16;
    float* sub_agg = wsf;  wsf += (size_t)NBb * NOPc * 16;
    float* pre_f1  = wsf;  wsf += (size_t)NBb * NOPc * OUTc;
    float* sub_f1  = wsf;  wsf += (size_t)NBb * NOPc * OUTc;
    float* self_f1 = wsf;  wsf += (size_t)NBb * NOPc * OUTc;
    float* ma_f2   = wsf;  wsf += (size_t)NBb * NOPc * OUTc;
    float* x2      = wsf;  wsf += (size_t)NBb * NOPc * OUTc;
    float* uts     = wsf;  wsf += (size_t)4 * NBb * NOPc;
    float* alpha   = wsf;  wsf += (size_t)NBb * 4 * NOPc;
    float* f1z     = wsf;  wsf += 128;
    ush* packp = (ush*)wsf;

    PackArgs pa;
    MlpPack pk[5];
    for (int m = 0; m < 5; ++m) {
        const int kre[3] = { (m == 4 ? 128 : 16), 256, 256 };
        const int kbn[3] = { (m == 4 ? 4 : 1), 8, 8 };
        const int nbn[3] = { 16, 16, 8 };
        const ush* dh[3]; const ush* dl[3];
        for (int j = 0; j < 3; ++j) {
            const int id = m * 3 + j;
            pa.d[id].src = Wraw[m][2 * j];
            pa.d[id].kreal = kre[j];
            pa.d[id].kbn = kbn[j];
            pa.d[id].nbn = nbn[j];
            const int cnt = kbn[j] * nbn[j] * 512;
            pa.d[id].dh = packp; dh[j] = packp; packp += cnt;
            pa.d[id].dl = packp; dl[j] = packp; packp += cnt;
        }
        pk[m].w1h = dh[0]; pk[m].w1l = dl[0];
        pk[m].w2h = dh[1]; pk[m].w2l = dl[1];
        pk[m].w3h = dh[2]; pk[m].w3l = dl[2];
        pk[m].b1 = Wraw[m][1]; pk[m].b2 = Wraw[m][3]; pk[m].b3 = Wraw[m][5];
    }

    F1Args fa;
    fa.X[0] = pre_agg; fa.X[1] = sub_agg; fa.X[2] = op;
    fa.P[0] = pk[1];   fa.P[1] = pk[2];   fa.P[2] = pk[3];
    fa.f1[0] = pre_f1; fa.f1[1] = sub_f1; fa.f1[2] = self_f1;
    fa.ut[0] = uts + 0 * NBb * NOPc;
    fa.ut[1] = uts + 1 * NBb * NOPc;
    fa.ut[2] = uts + 2 * NBb * NOPc;

    pack_kernel<<<dim3(64, 15), 256, 0, stream>>>(pa);
    zero_f1_kernel<<<1, 256, 0, stream>>>(pk[0], f1z);
    agg_kernel<<<dim3(NOPc, NBb), 256, 0, stream>>>(op, pre_adj, sub_adj, bidx, pre_agg, sub_agg);
    ma_mlp0_v2_kernel<<<dim3(NOPc / 8, NBb), 256, 0, stream>>>(ma, eg, ma_adj, bidx, pk[0], f1z, x2);
    mlp_f1_fused<<<dim3(128, 3), 256, 0, stream>>>(fa, attn);
    mlp4_kernel<<<dim3(128), 256, 0, stream>>>(x2, pk[4], attn, ma_f2, uts + 3 * NBb * NOPc);
    scores_kernel<<<NBb, 256, 0, stream>>>(uts, alpha);
    combine_kernel<<<dim3(1024), 256, 0, stream>>>(pre_f1, sub_f1, self_f1, ma_f2, alpha, out);
}

// Round 6
// 273.495 us; speedup vs baseline: 7.5929x; 1.1027x over previous
//
#include <hip/hip_runtime.h>
#include <math.h>

#define NBb  16
#define NOPc 512
#define NMAc 64
#define HIDc 256
#define OUTc 128

typedef unsigned int uint32;
typedef unsigned short ush;
typedef __attribute__((ext_vector_type(8))) short bf16x8;
typedef __attribute__((ext_vector_type(4))) float f32x4;
typedef __attribute__((ext_vector_type(4))) ush ushx4;

__device__ __forceinline__ ush f2bf(float v) {
    uint32 u = __float_as_uint(v);
    u += 0x7FFFu + ((u >> 16) & 1u);
    return (ush)(u >> 16);
}
__device__ __forceinline__ float bf2f(ush b) { return __uint_as_float(((uint32)b) << 16); }
__device__ __forceinline__ float eluf(float x) { return x > 0.f ? x : expm1f(x); }
__device__ __forceinline__ float eluf_fast(float x) { return x > 0.f ? x : __expf(x) - 1.f; }
// pack two floats' truncated bf16 into one u32: low = bf16(a), high = bf16(b)
__device__ __forceinline__ uint32 pkbf(float a, float b) {
    return __builtin_amdgcn_perm(__float_as_uint(b), __float_as_uint(a), 0x07060302u);
}

#define MFMA(A, B, C) __builtin_amdgcn_mfma_f32_16x16x32_bf16((A), (B), (C), 0, 0, 0)

// pack[((kb*nbn + nb)*64 + lane)*8 + e] = W[kb*32 + 8*(lane>>4) + e][nb*16 + (lane&15)]
struct MlpPack {
    const ush *w1h, *w1l, *w2h, *w2l, *w3h, *w3l;
    const float *b1, *b2, *b3;
};

// ---------------------------------------------------------------------------
// Hi/lo (bf16x3) 3-layer core (pre/sub/self/MLP4 — large-magnitude operands).
// ---------------------------------------------------------------------------
template<int KB1>
__device__ __forceinline__ void mlp3_core(
    const MlpPack& P,
    const ush* Xh, const ush* Xl, ush* Hh, ush* Hl, f32x4 acc3[2][4])
{
    const int tid = threadIdx.x;
    const int wv = tid >> 6, lane = tid & 63, r = lane & 15, g = lane >> 4;
    constexpr int KX = KB1 * 32;

    // layer 1
    {
        f32x4 acc[4][4];
        #pragma unroll
        for (int a = 0; a < 4; ++a)
            #pragma unroll
            for (int m = 0; m < 4; ++m) acc[a][m] = f32x4{0.f, 0.f, 0.f, 0.f};
        #pragma unroll 1
        for (int kb = 0; kb < KB1; ++kb) {
            bf16x8 wh[4], wl[4];
            #pragma unroll
            for (int a = 0; a < 4; ++a) {
                const size_t o = ((size_t)(kb * 16 + (wv * 4 + a)) * 64 + lane) * 8;
                wh[a] = *(const bf16x8*)(P.w1h + o);
                wl[a] = *(const bf16x8*)(P.w1l + o);
            }
            #pragma unroll
            for (int m = 0; m < 4; ++m) {
                const int row = 16 * m + r;
                const int ki = kb * 32 + 8 * g;
                bf16x8 xh = *(const bf16x8*)(Xh + row * KX + ki);
                bf16x8 xl = *(const bf16x8*)(Xl + row * KX + ki);
                #pragma unroll
                for (int a = 0; a < 4; ++a) {
                    acc[a][m] = MFMA(wh[a], xh, acc[a][m]);
                    acc[a][m] = MFMA(wh[a], xl, acc[a][m]);
                    acc[a][m] = MFMA(wl[a], xh, acc[a][m]);
                }
            }
        }
        #pragma unroll
        for (int a = 0; a < 4; ++a) {
            const int n0 = (wv * 4 + a) * 16 + 4 * g;
            const float4 bv = *(const float4*)(P.b1 + n0);
            const float bb[4] = {bv.x, bv.y, bv.z, bv.w};
            #pragma unroll
            for (int m = 0; m < 4; ++m) {
                const int row = 16 * m + r;
                ushx4 vh, vl;
                #pragma unroll
                for (int q = 0; q < 4; ++q) {
                    float y = eluf(acc[a][m][q] + bb[q]);
                    const ush hi = f2bf(y);
                    vh[q] = hi;
                    vl[q] = f2bf(y - bf2f(hi));
                }
                const int idx = row * 256 + (n0 ^ (8 * (row & 7)));
                *(ushx4*)(Hh + idx) = vh;
                *(ushx4*)(Hl + idx) = vl;
            }
        }
    }
    __syncthreads();

    // layer 2
    {
        f32x4 acc[4][4];
        #pragma unroll
        for (int a = 0; a < 4; ++a)
            #pragma unroll
            for (int m = 0; m < 4; ++m) acc[a][m] = f32x4{0.f, 0.f, 0.f, 0.f};
        #pragma unroll 1
        for (int kb = 0; kb < 8; ++kb) {
            bf16x8 wh[4], wl[4];
            #pragma unroll
            for (int a = 0; a < 4; ++a) {
                const size_t o = ((size_t)(kb * 16 + (wv * 4 + a)) * 64 + lane) * 8;
                wh[a] = *(const bf16x8*)(P.w2h + o);
                wl[a] = *(const bf16x8*)(P.w2l + o);
            }
            #pragma unroll
            for (int m = 0; m < 4; ++m) {
                const int row = 16 * m + r;
                const int k0 = kb * 32 + 8 * g;
                const int idx = row * 256 + (k0 ^ (8 * (row & 7)));
                bf16x8 hh = *(const bf16x8*)(Hh + idx);
                bf16x8 hl = *(const bf16x8*)(Hl + idx);
                #pragma unroll
                for (int a = 0; a < 4; ++a) {
                    acc[a][m] = MFMA(wh[a], hh, acc[a][m]);
                    acc[a][m] = MFMA(wh[a], hl, acc[a][m]);
                    acc[a][m] = MFMA(wl[a], hh, acc[a][m]);
                }
            }
        }
        __syncthreads();
        #pragma unroll
        for (int a = 0; a < 4; ++a) {
            const int n0 = (wv * 4 + a) * 16 + 4 * g;
            const float4 bv = *(const float4*)(P.b2 + n0);
            const float bb[4] = {bv.x, bv.y, bv.z, bv.w};
            #pragma unroll
            for (int m = 0; m < 4; ++m) {
                const int row = 16 * m + r;
                ushx4 vh, vl;
                #pragma unroll
                for (int q = 0; q < 4; ++q) {
                    float y = eluf(acc[a][m][q] + bb[q]);
                    const ush hi = f2bf(y);
                    vh[q] = hi;
                    vl[q] = f2bf(y - bf2f(hi));
                }
                const int idx = row * 256 + (n0 ^ (8 * (row & 7)));
                *(ushx4*)(Hh + idx) = vh;
                *(ushx4*)(Hl + idx) = vl;
            }
        }
    }
    __syncthreads();

    // layer 3
    {
        #pragma unroll
        for (int a = 0; a < 2; ++a)
            #pragma unroll
            for (int m = 0; m < 4; ++m) acc3[a][m] = f32x4{0.f, 0.f, 0.f, 0.f};
        #pragma unroll 1
        for (int kb = 0; kb < 8; ++kb) {
            bf16x8 wh[2], wl[2];
            #pragma unroll
            for (int a = 0; a < 2; ++a) {
                const size_t o = ((size_t)(kb * 8 + (wv * 2 + a)) * 64 + lane) * 8;
                wh[a] = *(const bf16x8*)(P.w3h + o);
                wl[a] = *(const bf16x8*)(P.w3l + o);
            }
            #pragma unroll
            for (int m = 0; m < 4; ++m) {
                const int row = 16 * m + r;
                const int k0 = kb * 32 + 8 * g;
                const int idx = row * 256 + (k0 ^ (8 * (row & 7)));
                bf16x8 hh = *(const bf16x8*)(Hh + idx);
                bf16x8 hl = *(const bf16x8*)(Hl + idx);
                #pragma unroll
                for (int a = 0; a < 2; ++a) {
                    acc3[a][m] = MFMA(wh[a], hh, acc3[a][m]);
                    acc3[a][m] = MFMA(wh[a], hl, acc3[a][m]);
                    acc3[a][m] = MFMA(wl[a], hh, acc3[a][m]);
                }
            }
        }
    }
}

// ---------------------------------------------------------------------------
// prep kernel: pack (blocks [0,960)) + agg (blocks [960,9152)) + f1z raw (last).
// ---------------------------------------------------------------------------
struct PackDesc { const float* src; ush* dh; ush* dl; int kreal; int kbn; int nbn; };
struct PrepArgs {
    PackDesc d[15];
    const float* op; const int* pre_adj; const int* sub_adj; const int* bidx;
    float* pre_agg; float* sub_agg;
    const float *z_b1, *z_w2, *z_b2, *z_w3, *z_b3;   // raw MLP0 weights for f1z
    float* f1z;
};

__global__ __launch_bounds__(256) void prep_kernel(PrepArgs A)
{
    __shared__ float shmem[544];
    const int blk = blockIdx.x;
    const int t = threadIdx.x;
    if (blk < 960) {
        // ---- weight pack ----
        const PackDesc d = A.d[blk >> 6];
        const int sub = blk & 63;
        const int total = d.kbn * d.nbn * 512;
        const int N = d.nbn * 16;
        for (int idx = sub * 256 + t; idx < total; idx += 64 * 256) {
            const int e = idx & 7;
            const int l = (idx >> 3) & 63;
            const int t2 = idx >> 9;
            const int nb = t2 % d.nbn;
            const int kb = t2 / d.nbn;
            const int k = kb * 32 + ((l >> 4) << 3) + e;
            const int n = nb * 16 + (l & 15);
            const float v = (k < d.kreal) ? d.src[(size_t)k * N + n] : 0.f;
            const ush hi = f2bf(v);
            d.dh[idx] = hi;
            d.dl[idx] = f2bf(v - bf2f(hi));
        }
    } else if (blk < 960 + 8192) {
        // ---- pre/sub adjacency-gated row sums ----
        const int e = blk - 960;
        const int i = e & 511, b = e >> 9;
        const int bi = A.bidx[b];
        const int d = t & 15, g = t >> 4;
        const int* pr = A.pre_adj + ((size_t)bi * NOPc + i) * NOPc;
        const int* sr = A.sub_adj + ((size_t)bi * NOPc + i) * NOPc;
        const float* opb = A.op + (size_t)b * NOPc * 16;
        float ap = 0.f, as = 0.f;
        for (int j = g; j < NOPc; j += 16) {
            const float v = opb[j * 16 + d];
            if (pr[j]) ap += v;
            if (sr[j]) as += v;
        }
        shmem[0 * 256 + g * 16 + d] = ap;
        shmem[1 * 256 + g * 16 + d] = as;
        __syncthreads();
        if (t < 32) {
            const int which = t >> 4, dd = t & 15;
            float s = 0.f;
            #pragma unroll
            for (int gg = 0; gg < 16; ++gg) s += shmem[which * 256 + gg * 16 + dd];
            float* dst = which ? A.sub_agg : A.pre_agg;
            dst[((size_t)b * NOPc + i) * 16 + dd] = s;
        }
    } else {
        // ---- f1z = MLP0(0) in raw f32 (no pack dependency) ----
        shmem[t] = eluf(A.z_b1[t]);                 // h1 = elu(b1)
        __syncthreads();
        float acc = A.z_b2[t];
        for (int k = 0; k < 256; ++k) acc += shmem[k] * A.z_w2[(size_t)k * 256 + t];
        shmem[256 + t < 544 ? 256 + t : 0] = 0.f;   // no-op guard (t<256 always)
        shmem[256 + t] = eluf(acc);                 // h2
        __syncthreads();
        if (t < 128) {
            float a = A.z_b3[t];
            for (int k = 0; k < 256; ++k) a += shmem[256 + k] * A.z_w3[(size_t)k * 128 + t];
            A.f1z[t] = a;
        }
    }
}

// ---------------------------------------------------------------------------
// ma path v3: per-(b,i) block. X direct global->reg, single-plane bf16,
// perm-truncation packing, register pooling -> x2 (no LDS SUM/CNT, no atomics).
// ---------------------------------------------------------------------------
__global__ __launch_bounds__(256) void ma_mlp0_v3_kernel(
    const float* __restrict__ ma, const float* __restrict__ eg,
    const int* __restrict__ ma_adj, const int* __restrict__ bidx,
    MlpPack P, const float* __restrict__ f1z, float* __restrict__ x2_out)
{
    __shared__ ush Hh[64 * 256];
    __shared__ unsigned char idxs[64];
    __shared__ int naSh;
    const int i = blockIdx.x, b = blockIdx.y;
    const int tid = threadIdx.x;
    const int wv = tid >> 6, lane = tid & 63, r = lane & 15, g = lane >> 4;
    const int bi = bidx[b];
    const int* adjr = ma_adj + ((size_t)bi * NOPc + i) * NMAc;
    if (tid < 64) {
        const int active = (adjr[tid] != 0) ? 1 : 0;
        const unsigned long long mk = __ballot(active);
        if (active) idxs[(int)__popcll(mk & ((1ull << tid) - 1ull))] = (unsigned char)tid;
        if (tid == 0) naSh = (int)__popcll(mk);
    }
    __syncthreads();
    const int na = naSh;
    const int MB = (na + 15) >> 4;

    // ---- layer 1: 32 -> 256, X fragments straight from global ----
    {
        f32x4 acc[4][4];
        #pragma unroll
        for (int a = 0; a < 4; ++a)
            #pragma unroll
            for (int m = 0; m < 4; ++m) acc[a][m] = f32x4{0.f, 0.f, 0.f, 0.f};
        bf16x8 wh[4];
        #pragma unroll
        for (int a = 0; a < 4; ++a)
            wh[a] = *(const bf16x8*)(P.w1h + ((size_t)(wv * 4 + a) * 64 + lane) * 8);
        #pragma unroll
        for (int m = 0; m < 4; ++m) {
            if (m < MB) {
                const int row = 16 * m + r;
                bf16x8 xh = {0, 0, 0, 0, 0, 0, 0, 0};
                if (row < na && g < 2) {
                    const int j = idxs[row];
                    const float4* src = (g == 0)
                        ? (const float4*)(ma + ((size_t)b * NMAc + j) * 8)
                        : (const float4*)(eg + (((size_t)b * NOPc + i) * NMAc + j) * 8);
                    const float4 f0 = src[0], f1v = src[1];
                    xh[0] = (short)f2bf(f0.x);  xh[1] = (short)f2bf(f0.y);
                    xh[2] = (short)f2bf(f0.z);  xh[3] = (short)f2bf(f0.w);
                    xh[4] = (short)f2bf(f1v.x); xh[5] = (short)f2bf(f1v.y);
                    xh[6] = (short)f2bf(f1v.z); xh[7] = (short)f2bf(f1v.w);
                }
                #pragma unroll
                for (int a = 0; a < 4; ++a) acc[a][m] = MFMA(wh[a], xh, acc[a][m]);
            }
        }
        #pragma unroll
        for (int a = 0; a < 4; ++a) {
            const int n0 = (wv * 4 + a) * 16 + 4 * g;
            const float4 bv = *(const float4*)(P.b1 + n0);
            #pragma unroll
            for (int m = 0; m < 4; ++m) {
                if (m < MB) {
                    const int row = 16 * m + r;
                    const float y0 = eluf_fast(acc[a][m][0] + bv.x);
                    const float y1 = eluf_fast(acc[a][m][1] + bv.y);
                    const float y2 = eluf_fast(acc[a][m][2] + bv.z);
                    const float y3 = eluf_fast(acc[a][m][3] + bv.w);
                    uint2 u; u.x = pkbf(y0, y1); u.y = pkbf(y2, y3);
                    *(uint2*)(Hh + row * 256 + (n0 ^ (8 * (row & 7)))) = u;
                }
            }
        }
    }
    __syncthreads();

    // ---- layer 2: 256 -> 256 (in place) ----
    {
        f32x4 acc[4][4];
        #pragma unroll
        for (int a = 0; a < 4; ++a)
            #pragma unroll
            for (int m = 0; m < 4; ++m) acc[a][m] = f32x4{0.f, 0.f, 0.f, 0.f};
        #pragma unroll 1
        for (int kb = 0; kb < 8; ++kb) {
            bf16x8 wh[4];
            #pragma unroll
            for (int a = 0; a < 4; ++a)
                wh[a] = *(const bf16x8*)(P.w2h + ((size_t)(kb * 16 + (wv * 4 + a)) * 64 + lane) * 8);
            #pragma unroll
            for (int m = 0; m < 4; ++m) {
                if (m < MB) {
                    const int row = 16 * m + r;
                    const int k0 = kb * 32 + 8 * g;
                    bf16x8 hh = *(const bf16x8*)(Hh + row * 256 + (k0 ^ (8 * (row & 7))));
                    #pragma unroll
                    for (int a = 0; a < 4; ++a) acc[a][m] = MFMA(wh[a], hh, acc[a][m]);
                }
            }
        }
        __syncthreads();
        #pragma unroll
        for (int a = 0; a < 4; ++a) {
            const int n0 = (wv * 4 + a) * 16 + 4 * g;
            const float4 bv = *(const float4*)(P.b2 + n0);
            #pragma unroll
            for (int m = 0; m < 4; ++m) {
                if (m < MB) {
                    const int row = 16 * m + r;
                    const float y0 = eluf_fast(acc[a][m][0] + bv.x);
                    const float y1 = eluf_fast(acc[a][m][1] + bv.y);
                    const float y2 = eluf_fast(acc[a][m][2] + bv.z);
                    const float y3 = eluf_fast(acc[a][m][3] + bv.w);
                    uint2 u; u.x = pkbf(y0, y1); u.y = pkbf(y2, y3);
                    *(uint2*)(Hh + row * 256 + (n0 ^ (8 * (row & 7)))) = u;
                }
            }
        }
    }
    __syncthreads();

    // ---- layer 3: 256 -> 128 + register pooling -> x2 ----
    f32x4 acc3[2][4];
    #pragma unroll
    for (int a = 0; a < 2; ++a)
        #pragma unroll
        for (int m = 0; m < 4; ++m) acc3[a][m] = f32x4{0.f, 0.f, 0.f, 0.f};
    #pragma unroll 1
    for (int kb = 0; kb < 8; ++kb) {
        bf16x8 wh[2];
        #pragma unroll
        for (int a = 0; a < 2; ++a)
            wh[a] = *(const bf16x8*)(P.w3h + ((size_t)(kb * 8 + (wv * 2 + a)) * 64 + lane) * 8);
        #pragma unroll
        for (int m = 0; m < 4; ++m) {
            if (m < MB) {
                const int row = 16 * m + r;
                const int k0 = kb * 32 + 8 * g;
                bf16x8 hh = *(const bf16x8*)(Hh + row * 256 + (k0 ^ (8 * (row & 7))));
                #pragma unroll
                for (int a = 0; a < 2; ++a) acc3[a][m] = MFMA(wh[a], hh, acc3[a][m]);
            }
        }
    }
    const float nz = (float)(64 - na);
    #pragma unroll
    for (int a = 0; a < 2; ++a) {
        const int n0 = (wv * 2 + a) * 16 + 4 * g;
        const float4 bv = *(const float4*)(P.b3 + n0);
        const float bb[4] = {bv.x, bv.y, bv.z, bv.w};
        float s[4] = {0.f, 0.f, 0.f, 0.f}, c[4] = {0.f, 0.f, 0.f, 0.f};
        #pragma unroll
        for (int m = 0; m < 4; ++m) {
            if (m < MB) {
                const int row = 16 * m + r;
                const float ok = (row < na) ? 1.f : 0.f;
                #pragma unroll
                for (int q = 0; q < 4; ++q) {
                    const float y = acc3[a][m][q] + bb[q];
                    s[q] += ok * y;
                    c[q] += ok * ((y != 0.f) ? 1.f : 0.f);
                }
            }
        }
        #pragma unroll
        for (int q = 0; q < 4; ++q) {
            #pragma unroll
            for (int o = 1; o < 16; o <<= 1) {
                s[q] += __shfl_xor(s[q], o);
                c[q] += __shfl_xor(c[q], o);
            }
        }
        if (r == 0) {
            const float4 fz = *(const float4*)(f1z + n0);
            float4 o;
            o.x = (s[0] + nz * fz.x) / (c[0] + nz * ((fz.x != 0.f) ? 1.f : 0.f));
            o.y = (s[1] + nz * fz.y) / (c[1] + nz * ((fz.y != 0.f) ? 1.f : 0.f));
            o.z = (s[2] + nz * fz.z) / (c[2] + nz * ((fz.z != 0.f) ? 1.f : 0.f));
            o.w = (s[3] + nz * fz.w) / (c[3] + nz * ((fz.w != 0.f) ? 1.f : 0.f));
            *(float4*)&x2_out[((size_t)b * NOPc + i) * 128 + n0] = o;
        }
    }
}

// ---------------------------------------------------------------------------
// Fused pre/sub/self f1 kernel (hi/lo core).
// ---------------------------------------------------------------------------
struct F1Args { const float* X[3]; MlpPack P[3]; float* f1[3]; float* ut[3]; };

__global__ __launch_bounds__(256) void mlp_f1_fused(F1Args A, const float* __restrict__ attn)
{
    __shared__ ush Xh[64 * 32], Xl[64 * 32];
    __shared__ ush Hh[64 * 256], Hl[64 * 256];
    __shared__ float UT[64];
    const int p = blockIdx.y;
    const float* Xg = A.X[p];
    const MlpPack P = A.P[p];
    float* f1_out = A.f1[p];
    float* ut_out = A.ut[p];
    const int tid = threadIdx.x;
    const int row0 = blockIdx.x * 64;
    if (tid < 64) UT[tid] = 0.f;
    for (int idx = tid; idx < 64 * 32; idx += 256) {
        const int row = idx >> 5, k = idx & 31;
        float v = 0.f;
        if (k < 16) v = Xg[(size_t)(row0 + row) * 16 + k];
        const ush hi = f2bf(v);
        Xh[idx] = hi;
        Xl[idx] = f2bf(v - bf2f(hi));
    }
    __syncthreads();
    f32x4 acc3[2][4];
    mlp3_core<1>(P, Xh, Xl, Hh, Hl, acc3);

    const int wv = tid >> 6, lane = tid & 63, r = lane & 15, g = lane >> 4;
    float utp[4] = {0.f, 0.f, 0.f, 0.f};
    #pragma unroll
    for (int a = 0; a < 2; ++a) {
        const int n0 = (wv * 2 + a) * 16 + 4 * g;
        const float4 bv = *(const float4*)(P.b3 + n0);
        const float4 av = *(const float4*)(attn + n0);
        #pragma unroll
        for (int m = 0; m < 4; ++m) {
            float4 y;
            y.x = acc3[a][m][0] + bv.x;
            y.y = acc3[a][m][1] + bv.y;
            y.z = acc3[a][m][2] + bv.z;
            y.w = acc3[a][m][3] + bv.w;
            *(float4*)&f1_out[(size_t)(row0 + 16 * m + r) * OUTc + n0] = y;
            utp[m] += y.x * av.x + y.y * av.y + y.z * av.z + y.w * av.w;
        }
    }
    #pragma unroll
    for (int m = 0; m < 4; ++m) {
        float v = utp[m];
        v += __shfl_xor(v, 16);
        v += __shfl_xor(v, 32);
        if (lane < 16) atomicAdd(&UT[16 * m + r], v);
    }
    __syncthreads();
    if (tid < 64) ut_out[row0 + tid] = UT[tid];
}

// ---------------------------------------------------------------------------
// MLP4 path (hi/lo core, KB1=4, KINR=128).
// ---------------------------------------------------------------------------
__global__ __launch_bounds__(256) void mlp4_kernel(
    const float* __restrict__ Xg, MlpPack P, const float* __restrict__ attn,
    float* __restrict__ f1_out, float* __restrict__ ut_out)
{
    constexpr int KX = 128;
    __shared__ ush Xh[64 * KX], Xl[64 * KX];
    __shared__ ush Hh[64 * 256], Hl[64 * 256];
    __shared__ float UT[64];
    const int tid = threadIdx.x;
    const int row0 = blockIdx.x * 64;
    if (tid < 64) UT[tid] = 0.f;
    for (int idx = tid; idx < 64 * KX; idx += 256) {
        const float v = Xg[(size_t)row0 * KX + idx];
        const ush hi = f2bf(v);
        Xh[idx] = hi;
        Xl[idx] = f2bf(v - bf2f(hi));
    }
    __syncthreads();
    f32x4 acc3[2][4];
    mlp3_core<4>(P, Xh, Xl, Hh, Hl, acc3);

    const int wv = tid >> 6, lane = tid & 63, r = lane & 15, g = lane >> 4;
    float utp[4] = {0.f, 0.f, 0.f, 0.f};
    #pragma unroll
    for (int a = 0; a < 2; ++a) {
        const int n0 = (wv * 2 + a) * 16 + 4 * g;
        const float4 bv = *(const float4*)(P.b3 + n0);
        const float4 av = *(const float4*)(attn + n0);
        #pragma unroll
        for (int m = 0; m < 4; ++m) {
            float4 y;
            y.x = acc3[a][m][0] + bv.x;
            y.y = acc3[a][m][1] + bv.y;
            y.z = acc3[a][m][2] + bv.z;
            y.w = acc3[a][m][3] + bv.w;
            *(float4*)&f1_out[(size_t)(row0 + 16 * m + r) * OUTc + n0] = y;
            utp[m] += y.x * av.x + y.y * av.y + y.z * av.z + y.w * av.w;
        }
    }
    #pragma unroll
    for (int m = 0; m < 4; ++m) {
        float v = utp[m];
        v += __shfl_xor(v, 16);
        v += __shfl_xor(v, 32);
        if (lane < 16) atomicAdd(&UT[16 * m + r], v);
    }
    __syncthreads();
    if (tid < 64) ut_out[row0 + tid] = UT[tid];
}

// ---------------------------------------------------------------------------
// scores: per-batch joint softmax -> alpha.
// ---------------------------------------------------------------------------
__global__ __launch_bounds__(256) void scores_kernel(const float* __restrict__ uts,
                                                     float* __restrict__ alpha)
{
    const int b = blockIdx.x, t = threadIdx.x;
    __shared__ float sc[4 * NOPc];
    __shared__ float red[256];
    const float* put = uts + 0 * NBb * NOPc + (size_t)b * NOPc;
    const float* sut = uts + 1 * NBb * NOPc + (size_t)b * NOPc;
    const float* eut = uts + 2 * NBb * NOPc + (size_t)b * NOPc;
    const float* mut = uts + 3 * NBb * NOPc + (size_t)b * NOPc;
    for (int i = t; i < NOPc; i += 256) {
        const float se = eut[i];
        const float s0 = put[i] + se, s1 = sut[i] + se, s2 = se + se, s3 = mut[i] + se;
        sc[0 * NOPc + i] = s0 > 0.f ? s0 : 0.2f * s0;
        sc[1 * NOPc + i] = s1 > 0.f ? s1 : 0.2f * s1;
        sc[2 * NOPc + i] = s2 > 0.f ? s2 : 0.2f * s2;
        sc[3 * NOPc + i] = s3 > 0.f ? s3 : 0.2f * s3;
    }
    __syncthreads();
    float mx = -INFINITY;
    for (int idx = t; idx < 4 * NOPc; idx += 256) mx = fmaxf(mx, sc[idx]);
    red[t] = mx;
    __syncthreads();
    for (int s = 128; s > 0; s >>= 1) { if (t < s) red[t] = fmaxf(red[t], red[t + s]); __syncthreads(); }
    mx = red[0];
    __syncthreads();
    float ps = 0.f;
    for (int idx = t; idx < 4 * NOPc; idx += 256) {
        const float e = expf(sc[idx] - mx);
        sc[idx] = e;
        ps += e;
    }
    red[t] = ps;
    __syncthreads();
    for (int s = 128; s > 0; s >>= 1) { if (t < s) red[t] += red[t + s]; __syncthreads(); }
    const float invZ = 1.f / red[0];
    for (int idx = t; idx < 4 * NOPc; idx += 256)
        alpha[(size_t)b * 4 * NOPc + idx] = sc[idx] * invZ;
}

// ---------------------------------------------------------------------------
// combine: out = sigmoid(Σ alpha_k * f_k).
// ---------------------------------------------------------------------------
__global__ __launch_bounds__(256) void combine_kernel(const float* __restrict__ pre_f1,
                                                      const float* __restrict__ sub_f1,
                                                      const float* __restrict__ self_f1,
                                                      const float* __restrict__ ma_f2,
                                                      const float* __restrict__ alpha,
                                                      float* __restrict__ out)
{
    const size_t e4 = (size_t)blockIdx.x * 256 + threadIdx.x;
    const int b = (int)(e4 >> 14);
    const int rem = (int)(e4 & 16383);
    const int i = rem >> 5;
    const float* al = alpha + (size_t)b * 4 * NOPc;
    const float a0 = al[0 * NOPc + i], a1 = al[1 * NOPc + i];
    const float a2 = al[2 * NOPc + i], a3 = al[3 * NOPc + i];
    const float4 vp = ((const float4*)pre_f1)[e4];
    const float4 vs = ((const float4*)sub_f1)[e4];
    const float4 ve = ((const float4*)self_f1)[e4];
    const float4 vm = ((const float4*)ma_f2)[e4];
    float4 o;
    o.x = 1.f / (1.f + expf(-(a0 * vp.x + a1 * vs.x + a2 * ve.x + a3 * vm.x)));
    o.y = 1.f / (1.f + expf(-(a0 * vp.y + a1 * vs.y + a2 * ve.y + a3 * vm.y)));
    o.z = 1.f / (1.f + expf(-(a0 * vp.z + a1 * vs.z + a2 * ve.z + a3 * vm.z)));
    o.w = 1.f / (1.f + expf(-(a0 * vp.w + a1 * vs.w + a2 * ve.w + a3 * vm.w)));
    ((float4*)out)[e4] = o;
}

extern "C" void kernel_launch(void* const* d_in, const int* in_sizes, int n_in,
                              void* d_out, int out_size, void* d_ws, size_t ws_size,
                              hipStream_t stream) {
    const float* op      = (const float*)d_in[0];
    const float* ma      = (const float*)d_in[1];
    const float* eg      = (const float*)d_in[2];
    const int*   ma_adj  = (const int*)d_in[3];
    const int*   pre_adj = (const int*)d_in[4];
    const int*   sub_adj = (const int*)d_in[5];
    const int*   bidx    = (const int*)d_in[6];
    const float* attn    = (const float*)d_in[7];
    float* out = (float*)d_out;
    const float* Wraw[5][6];
    for (int m = 0; m < 5; ++m)
        for (int j = 0; j < 6; ++j)
            Wraw[m][j] = (const float*)d_in[8 + 6 * m + j];

    // ---- workspace layout ----
    float* wsf = (float*)d_ws;
    float* pre_agg = wsf;  wsf += (size_t)NBb * NOPc * 16;
    float* sub_agg = wsf;  wsf += (size_t)NBb * NOPc * 16;
    float* pre_f1  = wsf;  wsf += (size_t)NBb * NOPc * OUTc;
    float* sub_f1  = wsf;  wsf += (size_t)NBb * NOPc * OUTc;
    float* self_f1 = wsf;  wsf += (size_t)NBb * NOPc * OUTc;
    float* ma_f2   = wsf;  wsf += (size_t)NBb * NOPc * OUTc;
    float* x2      = wsf;  wsf += (size_t)NBb * NOPc * OUTc;
    float* uts     = wsf;  wsf += (size_t)4 * NBb * NOPc;
    float* alpha   = wsf;  wsf += (size_t)NBb * 4 * NOPc;
    float* f1z     = wsf;  wsf += 128;
    ush* packp = (ush*)wsf;

    PrepArgs pa;
    MlpPack pk[5];
    for (int m = 0; m < 5; ++m) {
        const int kre[3] = { (m == 4 ? 128 : 16), 256, 256 };
        const int kbn[3] = { (m == 4 ? 4 : 1), 8, 8 };
        const int nbn[3] = { 16, 16, 8 };
        const ush* dh[3]; const ush* dl[3];
        for (int j = 0; j < 3; ++j) {
            const int id = m * 3 + j;
            pa.d[id].src = Wraw[m][2 * j];
            pa.d[id].kreal = kre[j];
            pa.d[id].kbn = kbn[j];
            pa.d[id].nbn = nbn[j];
            const int cnt = kbn[j] * nbn[j] * 512;
            pa.d[id].dh = packp; dh[j] = packp; packp += cnt;
            pa.d[id].dl = packp; dl[j] = packp; packp += cnt;
        }
        pk[m].w1h = dh[0]; pk[m].w1l = dl[0];
        pk[m].w2h = dh[1]; pk[m].w2l = dl[1];
        pk[m].w3h = dh[2]; pk[m].w3l = dl[2];
        pk[m].b1 = Wraw[m][1]; pk[m].b2 = Wraw[m][3]; pk[m].b3 = Wraw[m][5];
    }
    pa.op = op; pa.pre_adj = pre_adj; pa.sub_adj = sub_adj; pa.bidx = bidx;
    pa.pre_agg = pre_agg; pa.sub_agg = sub_agg;
    pa.z_b1 = Wraw[0][1]; pa.z_w2 = Wraw[0][2]; pa.z_b2 = Wraw[0][3];
    pa.z_w3 = Wraw[0][4]; pa.z_b3 = Wraw[0][5];
    pa.f1z = f1z;

    F1Args fa;
    fa.X[0] = pre_agg; fa.X[1] = sub_agg; fa.X[2] = op;
    fa.P[0] = pk[1];   fa.P[1] = pk[2];   fa.P[2] = pk[3];
    fa.f1[0] = pre_f1; fa.f1[1] = sub_f1; fa.f1[2] = self_f1;
    fa.ut[0] = uts + 0 * NBb * NOPc;
    fa.ut[1] = uts + 1 * NBb * NOPc;
    fa.ut[2] = uts + 2 * NBb * NOPc;

    prep_kernel<<<dim3(960 + 8192 + 1), 256, 0, stream>>>(pa);
    ma_mlp0_v3_kernel<<<dim3(NOPc, NBb), 256, 0, stream>>>(ma, eg, ma_adj, bidx, pk[0], f1z, x2);
    mlp_f1_fused<<<dim3(128, 3), 256, 0, stream>>>(fa, attn);
    mlp4_kernel<<<dim3(128), 256, 0, stream>>>(x2, pk[4], attn, ma_f2, uts + 3 * NBb * NOPc);
    scores_kernel<<<NBb, 256, 0, stream>>>(uts, alpha);
    combine_kernel<<<dim3(1024), 256, 0, stream>>>(pre_f1, sub_f1, self_f1, ma_f2, alpha, out);
}

// Round 7
// 252.853 us; speedup vs baseline: 8.2128x; 1.0816x over previous
//
#include <hip/hip_runtime.h>
#include <math.h>

#define NBb  16
#define NOPc 512
#define NMAc 64
#define HIDc 256
#define OUTc 128

typedef unsigned int uint32;
typedef unsigned short ush;
typedef __attribute__((ext_vector_type(8))) short bf16x8;
typedef __attribute__((ext_vector_type(4))) float f32x4;
typedef __attribute__((ext_vector_type(4))) ush ushx4;

__device__ __forceinline__ ush f2bf(float v) {
    uint32 u = __float_as_uint(v);
    u += 0x7FFFu + ((u >> 16) & 1u);
    return (ush)(u >> 16);
}
__device__ __forceinline__ float bf2f(ush b) { return __uint_as_float(((uint32)b) << 16); }
__device__ __forceinline__ float eluf(float x) { return x > 0.f ? x : expm1f(x); }
__device__ __forceinline__ float eluf_fast(float x) { return x > 0.f ? x : __expf(x) - 1.f; }
// pack two floats' truncated bf16 into one u32: low = bf16(a), high = bf16(b)
__device__ __forceinline__ uint32 pkbf(float a, float b) {
    return __builtin_amdgcn_perm(__float_as_uint(b), __float_as_uint(a), 0x07060302u);
}

#define MFMA(A, B, C) __builtin_amdgcn_mfma_f32_16x16x32_bf16((A), (B), (C), 0, 0, 0)

// pack[((kb*nbn + nb)*64 + lane)*8 + e] = W[kb*32 + 8*(lane>>4) + e][nb*16 + (lane&15)]
struct MlpPack {
    const ush *w1h, *w1l, *w2h, *w2l, *w3h, *w3l;
    const float *b1, *b2, *b3;
};

// ---------------------------------------------------------------------------
// Hi/lo (bf16x3) 3-layer core over a 32-row tile. KB1 runtime (1 or 4).
// Leaves layer-3 pre-bias accs in acc3[a][m]: col n0=(wv*2+a)*16+4g+q,
// row = 16m + r.
// ---------------------------------------------------------------------------
__device__ __forceinline__ void mlp3_core32(
    const MlpPack& P, const int KB1,
    const ush* Xh, const ush* Xl, ush* Hh, ush* Hl, f32x4 acc3[2][2])
{
    const int tid = threadIdx.x;
    const int wv = tid >> 6, lane = tid & 63, r = lane & 15, g = lane >> 4;
    const int KX = KB1 * 32;

    // layer 1: KX -> 256
    {
        f32x4 acc[4][2];
        #pragma unroll
        for (int a = 0; a < 4; ++a)
            #pragma unroll
            for (int m = 0; m < 2; ++m) acc[a][m] = f32x4{0.f, 0.f, 0.f, 0.f};
        #pragma unroll 1
        for (int kb = 0; kb < KB1; ++kb) {
            bf16x8 wh[4], wl[4];
            #pragma unroll
            for (int a = 0; a < 4; ++a) {
                const size_t o = ((size_t)(kb * 16 + (wv * 4 + a)) * 64 + lane) * 8;
                wh[a] = *(const bf16x8*)(P.w1h + o);
                wl[a] = *(const bf16x8*)(P.w1l + o);
            }
            #pragma unroll
            for (int m = 0; m < 2; ++m) {
                const int row = 16 * m + r;
                const int ki = kb * 32 + 8 * g;
                bf16x8 xh = *(const bf16x8*)(Xh + row * KX + ki);
                bf16x8 xl = *(const bf16x8*)(Xl + row * KX + ki);
                #pragma unroll
                for (int a = 0; a < 4; ++a) {
                    acc[a][m] = MFMA(wh[a], xh, acc[a][m]);
                    acc[a][m] = MFMA(wh[a], xl, acc[a][m]);
                    acc[a][m] = MFMA(wl[a], xh, acc[a][m]);
                }
            }
        }
        #pragma unroll
        for (int a = 0; a < 4; ++a) {
            const int n0 = (wv * 4 + a) * 16 + 4 * g;
            const float4 bv = *(const float4*)(P.b1 + n0);
            const float bb[4] = {bv.x, bv.y, bv.z, bv.w};
            #pragma unroll
            for (int m = 0; m < 2; ++m) {
                const int row = 16 * m + r;
                ushx4 vh, vl;
                #pragma unroll
                for (int q = 0; q < 4; ++q) {
                    float y = eluf(acc[a][m][q] + bb[q]);
                    const ush hi = f2bf(y);
                    vh[q] = hi;
                    vl[q] = f2bf(y - bf2f(hi));
                }
                const int idx = row * 256 + (n0 ^ (8 * (row & 7)));
                *(ushx4*)(Hh + idx) = vh;
                *(ushx4*)(Hl + idx) = vl;
            }
        }
    }
    __syncthreads();

    // layer 2: 256 -> 256 (in place)
    {
        f32x4 acc[4][2];
        #pragma unroll
        for (int a = 0; a < 4; ++a)
            #pragma unroll
            for (int m = 0; m < 2; ++m) acc[a][m] = f32x4{0.f, 0.f, 0.f, 0.f};
        #pragma unroll 1
        for (int kb = 0; kb < 8; ++kb) {
            bf16x8 wh[4], wl[4];
            #pragma unroll
            for (int a = 0; a < 4; ++a) {
                const size_t o = ((size_t)(kb * 16 + (wv * 4 + a)) * 64 + lane) * 8;
                wh[a] = *(const bf16x8*)(P.w2h + o);
                wl[a] = *(const bf16x8*)(P.w2l + o);
            }
            #pragma unroll
            for (int m = 0; m < 2; ++m) {
                const int row = 16 * m + r;
                const int k0 = kb * 32 + 8 * g;
                const int idx = row * 256 + (k0 ^ (8 * (row & 7)));
                bf16x8 hh = *(const bf16x8*)(Hh + idx);
                bf16x8 hl = *(const bf16x8*)(Hl + idx);
                #pragma unroll
                for (int a = 0; a < 4; ++a) {
                    acc[a][m] = MFMA(wh[a], hh, acc[a][m]);
                    acc[a][m] = MFMA(wh[a], hl, acc[a][m]);
                    acc[a][m] = MFMA(wl[a], hh, acc[a][m]);
                }
            }
        }
        __syncthreads();   // all reads complete before in-place overwrite
        #pragma unroll
        for (int a = 0; a < 4; ++a) {
            const int n0 = (wv * 4 + a) * 16 + 4 * g;
            const float4 bv = *(const float4*)(P.b2 + n0);
            const float bb[4] = {bv.x, bv.y, bv.z, bv.w};
            #pragma unroll
            for (int m = 0; m < 2; ++m) {
                const int row = 16 * m + r;
                ushx4 vh, vl;
                #pragma unroll
                for (int q = 0; q < 4; ++q) {
                    float y = eluf(acc[a][m][q] + bb[q]);
                    const ush hi = f2bf(y);
                    vh[q] = hi;
                    vl[q] = f2bf(y - bf2f(hi));
                }
                const int idx = row * 256 + (n0 ^ (8 * (row & 7)));
                *(ushx4*)(Hh + idx) = vh;
                *(ushx4*)(Hl + idx) = vl;
            }
        }
    }
    __syncthreads();

    // layer 3: 256 -> 128
    {
        #pragma unroll
        for (int a = 0; a < 2; ++a)
            #pragma unroll
            for (int m = 0; m < 2; ++m) acc3[a][m] = f32x4{0.f, 0.f, 0.f, 0.f};
        #pragma unroll 1
        for (int kb = 0; kb < 8; ++kb) {
            bf16x8 wh[2], wl[2];
            #pragma unroll
            for (int a = 0; a < 2; ++a) {
                const size_t o = ((size_t)(kb * 8 + (wv * 2 + a)) * 64 + lane) * 8;
                wh[a] = *(const bf16x8*)(P.w3h + o);
                wl[a] = *(const bf16x8*)(P.w3l + o);
            }
            #pragma unroll
            for (int m = 0; m < 2; ++m) {
                const int row = 16 * m + r;
                const int k0 = kb * 32 + 8 * g;
                const int idx = row * 256 + (k0 ^ (8 * (row & 7)));
                bf16x8 hh = *(const bf16x8*)(Hh + idx);
                bf16x8 hl = *(const bf16x8*)(Hl + idx);
                #pragma unroll
                for (int a = 0; a < 2; ++a) {
                    acc3[a][m] = MFMA(wh[a], hh, acc3[a][m]);
                    acc3[a][m] = MFMA(wh[a], hl, acc3[a][m]);
                    acc3[a][m] = MFMA(wl[a], hh, acc3[a][m]);
                }
            }
        }
    }
}

// ---------------------------------------------------------------------------
// prep kernel: pack (blocks [0,960)) + agg (blocks [960,9152)) + f1z (last).
// ---------------------------------------------------------------------------
struct PackDesc { const float* src; ush* dh; ush* dl; int kreal; int kbn; int nbn; };
struct PrepArgs {
    PackDesc d[15];
    const float* op; const int* pre_adj; const int* sub_adj; const int* bidx;
    float* pre_agg; float* sub_agg;
    const float *z_b1, *z_w2, *z_b2, *z_w3, *z_b3;
    float* f1z;
};

__global__ __launch_bounds__(256) void prep_kernel(PrepArgs A)
{
    __shared__ float shmem[544];
    const int blk = blockIdx.x;
    const int t = threadIdx.x;
    if (blk < 960) {
        const PackDesc d = A.d[blk >> 6];
        const int sub = blk & 63;
        const int total = d.kbn * d.nbn * 512;
        const int N = d.nbn * 16;
        for (int idx = sub * 256 + t; idx < total; idx += 64 * 256) {
            const int e = idx & 7;
            const int l = (idx >> 3) & 63;
            const int t2 = idx >> 9;
            const int nb = t2 % d.nbn;
            const int kb = t2 / d.nbn;
            const int k = kb * 32 + ((l >> 4) << 3) + e;
            const int n = nb * 16 + (l & 15);
            const float v = (k < d.kreal) ? d.src[(size_t)k * N + n] : 0.f;
            const ush hi = f2bf(v);
            d.dh[idx] = hi;
            d.dl[idx] = f2bf(v - bf2f(hi));
        }
    } else if (blk < 960 + 8192) {
        const int e = blk - 960;
        const int i = e & 511, b = e >> 9;
        const int bi = A.bidx[b];
        const int d = t & 15, g = t >> 4;
        const int* pr = A.pre_adj + ((size_t)bi * NOPc + i) * NOPc;
        const int* sr = A.sub_adj + ((size_t)bi * NOPc + i) * NOPc;
        const float* opb = A.op + (size_t)b * NOPc * 16;
        float ap = 0.f, as = 0.f;
        for (int j = g; j < NOPc; j += 16) {
            const float v = opb[j * 16 + d];
            if (pr[j]) ap += v;
            if (sr[j]) as += v;
        }
        shmem[0 * 256 + g * 16 + d] = ap;
        shmem[1 * 256 + g * 16 + d] = as;
        __syncthreads();
        if (t < 32) {
            const int which = t >> 4, dd = t & 15;
            float s = 0.f;
            #pragma unroll
            for (int gg = 0; gg < 16; ++gg) s += shmem[which * 256 + gg * 16 + dd];
            float* dst = which ? A.sub_agg : A.pre_agg;
            dst[((size_t)b * NOPc + i) * 16 + dd] = s;
        }
    } else {
        // f1z = MLP0(0) in raw f32
        shmem[t] = eluf(A.z_b1[t]);
        __syncthreads();
        float acc = A.z_b2[t];
        for (int k = 0; k < 256; ++k) acc += shmem[k] * A.z_w2[(size_t)k * 256 + t];
        __syncthreads();
        shmem[256 + t] = eluf(acc);
        __syncthreads();
        if (t < 128) {
            float a = A.z_b3[t];
            for (int k = 0; k < 256; ++k) a += shmem[256 + k] * A.z_w3[(size_t)k * 128 + t];
            A.f1z[t] = a;
        }
    }
}

// ---------------------------------------------------------------------------
// ma path v4: per-(b,i) block, 32-row H tile (16.5 KB LDS), na>32 via a
// second in-block pass. Single-plane bf16, X direct global->reg, register
// pooling persistent across passes.
// ---------------------------------------------------------------------------
__global__ __launch_bounds__(256, 5) void ma_mlp0_v4_kernel(
    const float* __restrict__ ma, const float* __restrict__ eg,
    const int* __restrict__ ma_adj, const int* __restrict__ bidx,
    MlpPack P, const float* __restrict__ f1z, float* __restrict__ x2_out)
{
    __shared__ ush Hh[32 * 256];          // 16 KB
    __shared__ unsigned char idxs[64];
    __shared__ int naSh;
    const int i = blockIdx.x, b = blockIdx.y;
    const int tid = threadIdx.x;
    const int wv = tid >> 6, lane = tid & 63, r = lane & 15, g = lane >> 4;
    const int bi = bidx[b];
    const int* adjr = ma_adj + ((size_t)bi * NOPc + i) * NMAc;
    if (tid < 64) {
        const int active = (adjr[tid] != 0) ? 1 : 0;
        const unsigned long long mk = __ballot(active);
        if (active) idxs[(int)__popcll(mk & ((1ull << tid) - 1ull))] = (unsigned char)tid;
        if (tid == 0) naSh = (int)__popcll(mk);
    }
    __syncthreads();
    const int na = naSh;
    const int npass = (na + 31) >> 5;

    float sA[2][4], cA[2][4];
    #pragma unroll
    for (int a = 0; a < 2; ++a)
        #pragma unroll
        for (int q = 0; q < 4; ++q) { sA[a][q] = 0.f; cA[a][q] = 0.f; }

    for (int p = 0; p < npass; ++p) {
        if (p) __syncthreads();            // Hh reads of prev pass done
        const int r0 = p * 32;
        const int rows = min(32, na - r0);
        const int MB = (rows + 15) >> 4;

        // ---- layer 1: 32 -> 256, X straight from global ----
        {
            f32x4 acc[4][2];
            #pragma unroll
            for (int a = 0; a < 4; ++a)
                #pragma unroll
                for (int m = 0; m < 2; ++m) acc[a][m] = f32x4{0.f, 0.f, 0.f, 0.f};
            bf16x8 wh[4];
            #pragma unroll
            for (int a = 0; a < 4; ++a)
                wh[a] = *(const bf16x8*)(P.w1h + ((size_t)(wv * 4 + a) * 64 + lane) * 8);
            #pragma unroll
            for (int m = 0; m < 2; ++m) {
                if (m < MB) {
                    const int grow = r0 + 16 * m + r;
                    bf16x8 xh = {0, 0, 0, 0, 0, 0, 0, 0};
                    if (grow < na && g < 2) {
                        const int j = idxs[grow];
                        const float4* src = (g == 0)
                            ? (const float4*)(ma + ((size_t)b * NMAc + j) * 8)
                            : (const float4*)(eg + (((size_t)b * NOPc + i) * NMAc + j) * 8);
                        const float4 f0 = src[0], f1v = src[1];
                        xh[0] = (short)f2bf(f0.x);  xh[1] = (short)f2bf(f0.y);
                        xh[2] = (short)f2bf(f0.z);  xh[3] = (short)f2bf(f0.w);
                        xh[4] = (short)f2bf(f1v.x); xh[5] = (short)f2bf(f1v.y);
                        xh[6] = (short)f2bf(f1v.z); xh[7] = (short)f2bf(f1v.w);
                    }
                    #pragma unroll
                    for (int a = 0; a < 4; ++a) acc[a][m] = MFMA(wh[a], xh, acc[a][m]);
                }
            }
            #pragma unroll
            for (int a = 0; a < 4; ++a) {
                const int n0 = (wv * 4 + a) * 16 + 4 * g;
                const float4 bv = *(const float4*)(P.b1 + n0);
                #pragma unroll
                for (int m = 0; m < 2; ++m) {
                    if (m < MB) {
                        const int row = 16 * m + r;
                        const float y0 = eluf_fast(acc[a][m][0] + bv.x);
                        const float y1 = eluf_fast(acc[a][m][1] + bv.y);
                        const float y2 = eluf_fast(acc[a][m][2] + bv.z);
                        const float y3 = eluf_fast(acc[a][m][3] + bv.w);
                        uint2 u; u.x = pkbf(y0, y1); u.y = pkbf(y2, y3);
                        *(uint2*)(Hh + row * 256 + (n0 ^ (8 * (row & 7)))) = u;
                    }
                }
            }
        }
        __syncthreads();

        // ---- layer 2: 256 -> 256 (in place) ----
        {
            f32x4 acc[4][2];
            #pragma unroll
            for (int a = 0; a < 4; ++a)
                #pragma unroll
                for (int m = 0; m < 2; ++m) acc[a][m] = f32x4{0.f, 0.f, 0.f, 0.f};
            #pragma unroll 1
            for (int kb = 0; kb < 8; ++kb) {
                bf16x8 wh[4];
                #pragma unroll
                for (int a = 0; a < 4; ++a)
                    wh[a] = *(const bf16x8*)(P.w2h + ((size_t)(kb * 16 + (wv * 4 + a)) * 64 + lane) * 8);
                #pragma unroll
                for (int m = 0; m < 2; ++m) {
                    if (m < MB) {
                        const int row = 16 * m + r;
                        const int k0 = kb * 32 + 8 * g;
                        bf16x8 hh = *(const bf16x8*)(Hh + row * 256 + (k0 ^ (8 * (row & 7))));
                        #pragma unroll
                        for (int a = 0; a < 4; ++a) acc[a][m] = MFMA(wh[a], hh, acc[a][m]);
                    }
                }
            }
            __syncthreads();
            #pragma unroll
            for (int a = 0; a < 4; ++a) {
                const int n0 = (wv * 4 + a) * 16 + 4 * g;
                const float4 bv = *(const float4*)(P.b2 + n0);
                #pragma unroll
                for (int m = 0; m < 2; ++m) {
                    if (m < MB) {
                        const int row = 16 * m + r;
                        const float y0 = eluf_fast(acc[a][m][0] + bv.x);
                        const float y1 = eluf_fast(acc[a][m][1] + bv.y);
                        const float y2 = eluf_fast(acc[a][m][2] + bv.z);
                        const float y3 = eluf_fast(acc[a][m][3] + bv.w);
                        uint2 u; u.x = pkbf(y0, y1); u.y = pkbf(y2, y3);
                        *(uint2*)(Hh + row * 256 + (n0 ^ (8 * (row & 7)))) = u;
                    }
                }
            }
        }
        __syncthreads();

        // ---- layer 3: 256 -> 128 + pool accumulate ----
        f32x4 acc3[2][2];
        #pragma unroll
        for (int a = 0; a < 2; ++a)
            #pragma unroll
            for (int m = 0; m < 2; ++m) acc3[a][m] = f32x4{0.f, 0.f, 0.f, 0.f};
        #pragma unroll 1
        for (int kb = 0; kb < 8; ++kb) {
            bf16x8 wh[2];
            #pragma unroll
            for (int a = 0; a < 2; ++a)
                wh[a] = *(const bf16x8*)(P.w3h + ((size_t)(kb * 8 + (wv * 2 + a)) * 64 + lane) * 8);
            #pragma unroll
            for (int m = 0; m < 2; ++m) {
                if (m < MB) {
                    const int row = 16 * m + r;
                    const int k0 = kb * 32 + 8 * g;
                    bf16x8 hh = *(const bf16x8*)(Hh + row * 256 + (k0 ^ (8 * (row & 7))));
                    #pragma unroll
                    for (int a = 0; a < 2; ++a) acc3[a][m] = MFMA(wh[a], hh, acc3[a][m]);
                }
            }
        }
        #pragma unroll
        for (int a = 0; a < 2; ++a) {
            const int n0 = (wv * 2 + a) * 16 + 4 * g;
            const float4 bv = *(const float4*)(P.b3 + n0);
            const float bb[4] = {bv.x, bv.y, bv.z, bv.w};
            #pragma unroll
            for (int m = 0; m < 2; ++m) {
                if (m < MB) {
                    const float ok = ((r0 + 16 * m + r) < na) ? 1.f : 0.f;
                    #pragma unroll
                    for (int q = 0; q < 4; ++q) {
                        const float y = acc3[a][m][q] + bb[q];
                        sA[a][q] += ok * y;
                        cA[a][q] += ok * ((y != 0.f) ? 1.f : 0.f);
                    }
                }
            }
        }
    }

    // ---- reduce over r lanes and write x2 ----
    const float nz = (float)(64 - na);
    #pragma unroll
    for (int a = 0; a < 2; ++a) {
        #pragma unroll
        for (int q = 0; q < 4; ++q) {
            #pragma unroll
            for (int o = 1; o < 16; o <<= 1) {
                sA[a][q] += __shfl_xor(sA[a][q], o);
                cA[a][q] += __shfl_xor(cA[a][q], o);
            }
        }
        if (r == 0) {
            const int n0 = (wv * 2 + a) * 16 + 4 * g;
            const float4 fz = *(const float4*)(f1z + n0);
            float4 o;
            o.x = (sA[a][0] + nz * fz.x) / (cA[a][0] + nz * ((fz.x != 0.f) ? 1.f : 0.f));
            o.y = (sA[a][1] + nz * fz.y) / (cA[a][1] + nz * ((fz.y != 0.f) ? 1.f : 0.f));
            o.z = (sA[a][2] + nz * fz.z) / (cA[a][2] + nz * ((fz.z != 0.f) ? 1.f : 0.f));
            o.w = (sA[a][3] + nz * fz.w) / (cA[a][3] + nz * ((fz.w != 0.f) ? 1.f : 0.f));
            *(float4*)&x2_out[((size_t)b * NOPc + i) * 128 + n0] = o;
        }
    }
}

// ---------------------------------------------------------------------------
// Merged f1 kernel: blockIdx.y = path (0=pre,1=sub,2=self,3=mlp4), 32 rows/blk.
// ---------------------------------------------------------------------------
struct F1Args { const float* X[4]; MlpPack P[4]; float* f1[4]; float* ut[4]; };

__global__ __launch_bounds__(256, 3) void f1_kernel(F1Args A, const float* __restrict__ attn)
{
    __shared__ ush Xh[32 * 128], Xl[32 * 128];
    __shared__ ush Hh[32 * 256], Hl[32 * 256];
    __shared__ float UT[32];
    const int p = blockIdx.y;
    const int KB1 = (p == 3) ? 4 : 1;
    const int KINR = (p == 3) ? 128 : 16;
    const int KX = KB1 * 32;
    const int sh = (p == 3) ? 7 : 5;
    const float* Xg = A.X[p];
    const MlpPack P = A.P[p];
    float* f1_out = A.f1[p];
    float* ut_out = A.ut[p];
    const int tid = threadIdx.x;
    const int row0 = blockIdx.x * 32;
    if (tid < 32) UT[tid] = 0.f;
    for (int idx = tid; idx < 32 * KX; idx += 256) {
        const int row = idx >> sh, k = idx & (KX - 1);
        float v = 0.f;
        if (k < KINR) v = Xg[(size_t)(row0 + row) * KINR + k];
        const ush hi = f2bf(v);
        Xh[idx] = hi;
        Xl[idx] = f2bf(v - bf2f(hi));
    }
    __syncthreads();
    f32x4 acc3[2][2];
    mlp3_core32(P, KB1, Xh, Xl, Hh, Hl, acc3);

    const int wv = tid >> 6, lane = tid & 63, r = lane & 15, g = lane >> 4;
    float utp[2] = {0.f, 0.f};
    #pragma unroll
    for (int a = 0; a < 2; ++a) {
        const int n0 = (wv * 2 + a) * 16 + 4 * g;
        const float4 bv = *(const float4*)(P.b3 + n0);
        const float4 av = *(const float4*)(attn + n0);
        #pragma unroll
        for (int m = 0; m < 2; ++m) {
            float4 y;
            y.x = acc3[a][m][0] + bv.x;
            y.y = acc3[a][m][1] + bv.y;
            y.z = acc3[a][m][2] + bv.z;
            y.w = acc3[a][m][3] + bv.w;
            *(float4*)&f1_out[(size_t)(row0 + 16 * m + r) * OUTc + n0] = y;
            utp[m] += y.x * av.x + y.y * av.y + y.z * av.z + y.w * av.w;
        }
    }
    #pragma unroll
    for (int m = 0; m < 2; ++m) {
        float v = utp[m];
        v += __shfl_xor(v, 16);
        v += __shfl_xor(v, 32);
        if (lane < 16) atomicAdd(&UT[16 * m + r], v);
    }
    __syncthreads();
    if (tid < 32) ut_out[row0 + tid] = UT[tid];
}

// ---------------------------------------------------------------------------
// combine with inline per-batch softmax: block = (b, 32-row chunk).
// ---------------------------------------------------------------------------
__global__ __launch_bounds__(256) void combine2_kernel(
    const float* __restrict__ uts,
    const float* __restrict__ pre_f1, const float* __restrict__ sub_f1,
    const float* __restrict__ self_f1, const float* __restrict__ ma_f2,
    float* __restrict__ out)
{
    __shared__ float sc[4 * NOPc];
    __shared__ float red[256];
    const int b = blockIdx.x >> 4, chunk = blockIdx.x & 15;
    const int t = threadIdx.x;
    const float* put = uts + 0 * NBb * NOPc + (size_t)b * NOPc;
    const float* sut = uts + 1 * NBb * NOPc + (size_t)b * NOPc;
    const float* eut = uts + 2 * NBb * NOPc + (size_t)b * NOPc;
    const float* mut = uts + 3 * NBb * NOPc + (size_t)b * NOPc;
    for (int i = t; i < NOPc; i += 256) {
        const float se = eut[i];
        const float s0 = put[i] + se, s1 = sut[i] + se, s2 = se + se, s3 = mut[i] + se;
        sc[0 * NOPc + i] = s0 > 0.f ? s0 : 0.2f * s0;
        sc[1 * NOPc + i] = s1 > 0.f ? s1 : 0.2f * s1;
        sc[2 * NOPc + i] = s2 > 0.f ? s2 : 0.2f * s2;
        sc[3 * NOPc + i] = s3 > 0.f ? s3 : 0.2f * s3;
    }
    __syncthreads();
    float mx = -INFINITY;
    for (int idx = t; idx < 4 * NOPc; idx += 256) mx = fmaxf(mx, sc[idx]);
    red[t] = mx;
    __syncthreads();
    for (int s = 128; s > 0; s >>= 1) { if (t < s) red[t] = fmaxf(red[t], red[t + s]); __syncthreads(); }
    mx = red[0];
    __syncthreads();
    float ps = 0.f;
    for (int idx = t; idx < 4 * NOPc; idx += 256) {
        const float e = expf(sc[idx] - mx);
        sc[idx] = e;
        ps += e;
    }
    red[t] = ps;
    __syncthreads();
    for (int s = 128; s > 0; s >>= 1) { if (t < s) red[t] += red[t + s]; __syncthreads(); }
    const float invZ = 1.f / red[0];

    const size_t base4 = (size_t)b * 16384 + (size_t)chunk * 1024;   // float4 units
    #pragma unroll
    for (int k = 0; k < 4; ++k) {
        const size_t e4 = base4 + k * 256 + t;
        const int i = (int)((e4 >> 5) & 511);
        const float a0 = sc[0 * NOPc + i] * invZ;
        const float a1 = sc[1 * NOPc + i] * invZ;
        const float a2 = sc[2 * NOPc + i] * invZ;
        const float a3 = sc[3 * NOPc + i] * invZ;
        const float4 vp = ((const float4*)pre_f1)[e4];
        const float4 vs = ((const float4*)sub_f1)[e4];
        const float4 ve = ((const float4*)self_f1)[e4];
        const float4 vm = ((const float4*)ma_f2)[e4];
        float4 o;
        o.x = 1.f / (1.f + expf(-(a0 * vp.x + a1 * vs.x + a2 * ve.x + a3 * vm.x)));
        o.y = 1.f / (1.f + expf(-(a0 * vp.y + a1 * vs.y + a2 * ve.y + a3 * vm.y)));
        o.z = 1.f / (1.f + expf(-(a0 * vp.z + a1 * vs.z + a2 * ve.z + a3 * vm.z)));
        o.w = 1.f / (1.f + expf(-(a0 * vp.w + a1 * vs.w + a2 * ve.w + a3 * vm.w)));
        ((float4*)out)[e4] = o;
    }
}

extern "C" void kernel_launch(void* const* d_in, const int* in_sizes, int n_in,
                              void* d_out, int out_size, void* d_ws, size_t ws_size,
                              hipStream_t stream) {
    const float* op      = (const float*)d_in[0];
    const float* ma      = (const float*)d_in[1];
    const float* eg      = (const float*)d_in[2];
    const int*   ma_adj  = (const int*)d_in[3];
    const int*   pre_adj = (const int*)d_in[4];
    const int*   sub_adj = (const int*)d_in[5];
    const int*   bidx    = (const int*)d_in[6];
    const float* attn    = (const float*)d_in[7];
    float* out = (float*)d_out;
    const float* Wraw[5][6];
    for (int m = 0; m < 5; ++m)
        for (int j = 0; j < 6; ++j)
            Wraw[m][j] = (const float*)d_in[8 + 6 * m + j];

    // ---- workspace layout ----
    float* wsf = (float*)d_ws;
    float* pre_agg = wsf;  wsf += (size_t)NBb * NOPc * 16;
    float* sub_agg = wsf;  wsf += (size_t)NBb * NOPc * 16;
    float* pre_f1  = wsf;  wsf += (size_t)NBb * NOPc * OUTc;
    float* sub_f1  = wsf;  wsf += (size_t)NBb * NOPc * OUTc;
    float* self_f1 = wsf;  wsf += (size_t)NBb * NOPc * OUTc;
    float* ma_f2   = wsf;  wsf += (size_t)NBb * NOPc * OUTc;
    float* x2      = wsf;  wsf += (size_t)NBb * NOPc * OUTc;
    float* uts     = wsf;  wsf += (size_t)4 * NBb * NOPc;
    float* f1z     = wsf;  wsf += 128;
    ush* packp = (ush*)wsf;

    PrepArgs pa;
    MlpPack pk[5];
    for (int m = 0; m < 5; ++m) {
        const int kre[3] = { (m == 4 ? 128 : 16), 256, 256 };
        const int kbn[3] = { (m == 4 ? 4 : 1), 8, 8 };
        const int nbn[3] = { 16, 16, 8 };
        const ush* dh[3]; const ush* dl[3];
        for (int j = 0; j < 3; ++j) {
            const int id = m * 3 + j;
            pa.d[id].src = Wraw[m][2 * j];
            pa.d[id].kreal = kre[j];
            pa.d[id].kbn = kbn[j];
            pa.d[id].nbn = nbn[j];
            const int cnt = kbn[j] * nbn[j] * 512;
            pa.d[id].dh = packp; dh[j] = packp; packp += cnt;
            pa.d[id].dl = packp; dl[j] = packp; packp += cnt;
        }
        pk[m].w1h = dh[0]; pk[m].w1l = dl[0];
        pk[m].w2h = dh[1]; pk[m].w2l = dl[1];
        pk[m].w3h = dh[2]; pk[m].w3l = dl[2];
        pk[m].b1 = Wraw[m][1]; pk[m].b2 = Wraw[m][3]; pk[m].b3 = Wraw[m][5];
    }
    pa.op = op; pa.pre_adj = pre_adj; pa.sub_adj = sub_adj; pa.bidx = bidx;
    pa.pre_agg = pre_agg; pa.sub_agg = sub_agg;
    pa.z_b1 = Wraw[0][1]; pa.z_w2 = Wraw[0][2]; pa.z_b2 = Wraw[0][3];
    pa.z_w3 = Wraw[0][4]; pa.z_b3 = Wraw[0][5];
    pa.f1z = f1z;

    F1Args fa;
    fa.X[0] = pre_agg; fa.X[1] = sub_agg; fa.X[2] = op;  fa.X[3] = x2;
    fa.P[0] = pk[1];   fa.P[1] = pk[2];   fa.P[2] = pk[3]; fa.P[3] = pk[4];
    fa.f1[0] = pre_f1; fa.f1[1] = sub_f1; fa.f1[2] = self_f1; fa.f1[3] = ma_f2;
    fa.ut[0] = uts + 0 * NBb * NOPc;
    fa.ut[1] = uts + 1 * NBb * NOPc;
    fa.ut[2] = uts + 2 * NBb * NOPc;
    fa.ut[3] = uts + 3 * NBb * NOPc;

    prep_kernel<<<dim3(960 + 8192 + 1), 256, 0, stream>>>(pa);
    ma_mlp0_v4_kernel<<<dim3(NOPc, NBb), 256, 0, stream>>>(ma, eg, ma_adj, bidx, pk[0], f1z, x2);
    f1_kernel<<<dim3(256, 4), 256, 0, stream>>>(fa, attn);
    combine2_kernel<<<dim3(NBb * 16), 256, 0, stream>>>(uts, pre_f1, sub_f1, self_f1, ma_f2, out);
}

// Round 8
// 223.527 us; speedup vs baseline: 9.2902x; 1.1312x over previous
//
#include <hip/hip_runtime.h>
#include <math.h>

#define NBb  16
#define NOPc 512
#define NMAc 64
#define HIDc 256
#define OUTc 128
#define NROW (NBb * NOPc)          // 8192 (b,i) rows
#define NEMAX (NROW * NMAc)        // 524288 max edges

typedef unsigned int uint32;
typedef unsigned short ush;
typedef __attribute__((ext_vector_type(8))) short bf16x8;
typedef __attribute__((ext_vector_type(4))) float f32x4;
typedef __attribute__((ext_vector_type(4))) ush ushx4;

__device__ __forceinline__ ush f2bf(float v) {
    uint32 u = __float_as_uint(v);
    u += 0x7FFFu + ((u >> 16) & 1u);
    return (ush)(u >> 16);
}
__device__ __forceinline__ float bf2f(ush b) { return __uint_as_float(((uint32)b) << 16); }
__device__ __forceinline__ float eluf(float x) { return x > 0.f ? x : expm1f(x); }
__device__ __forceinline__ float eluf_fast(float x) { return x > 0.f ? x : __expf(x) - 1.f; }
// pack two floats' truncated bf16 into one u32: low = bf16(a), high = bf16(b)
__device__ __forceinline__ uint32 pkbf(float a, float b) {
    return __builtin_amdgcn_perm(__float_as_uint(b), __float_as_uint(a), 0x07060302u);
}
__device__ __forceinline__ uint32 pkbf_rne(float a, float b) {
    return (uint32)f2bf(a) | ((uint32)f2bf(b) << 16);
}

#define MFMA(A, B, C) __builtin_amdgcn_mfma_f32_16x16x32_bf16((A), (B), (C), 0, 0, 0)

// pack[((kb*nbn + nb)*64 + lane)*8 + e] = W[kb*32 + 8*(lane>>4) + e][nb*16 + (lane&15)]
struct MlpPack {
    const ush *w1h, *w1l, *w2h, *w2l, *w3h, *w3l;
    const float *b1, *b2, *b3;
};

// ---------------------------------------------------------------------------
// Hi/lo (bf16x3) 3-layer core over a 32-row tile (pre/sub/self/MLP4 paths).
// ---------------------------------------------------------------------------
__device__ __forceinline__ void mlp3_core32(
    const MlpPack& P, const int KB1,
    const ush* Xh, const ush* Xl, ush* Hh, ush* Hl, f32x4 acc3[2][2])
{
    const int tid = threadIdx.x;
    const int wv = tid >> 6, lane = tid & 63, r = lane & 15, g = lane >> 4;
    const int KX = KB1 * 32;

    // layer 1: KX -> 256
    {
        f32x4 acc[4][2];
        #pragma unroll
        for (int a = 0; a < 4; ++a)
            #pragma unroll
            for (int m = 0; m < 2; ++m) acc[a][m] = f32x4{0.f, 0.f, 0.f, 0.f};
        #pragma unroll 1
        for (int kb = 0; kb < KB1; ++kb) {
            bf16x8 wh[4], wl[4];
            #pragma unroll
            for (int a = 0; a < 4; ++a) {
                const size_t o = ((size_t)(kb * 16 + (wv * 4 + a)) * 64 + lane) * 8;
                wh[a] = *(const bf16x8*)(P.w1h + o);
                wl[a] = *(const bf16x8*)(P.w1l + o);
            }
            #pragma unroll
            for (int m = 0; m < 2; ++m) {
                const int row = 16 * m + r;
                const int ki = kb * 32 + 8 * g;
                bf16x8 xh = *(const bf16x8*)(Xh + row * KX + ki);
                bf16x8 xl = *(const bf16x8*)(Xl + row * KX + ki);
                #pragma unroll
                for (int a = 0; a < 4; ++a) {
                    acc[a][m] = MFMA(wh[a], xh, acc[a][m]);
                    acc[a][m] = MFMA(wh[a], xl, acc[a][m]);
                    acc[a][m] = MFMA(wl[a], xh, acc[a][m]);
                }
            }
        }
        #pragma unroll
        for (int a = 0; a < 4; ++a) {
            const int n0 = (wv * 4 + a) * 16 + 4 * g;
            const float4 bv = *(const float4*)(P.b1 + n0);
            const float bb[4] = {bv.x, bv.y, bv.z, bv.w};
            #pragma unroll
            for (int m = 0; m < 2; ++m) {
                const int row = 16 * m + r;
                ushx4 vh, vl;
                #pragma unroll
                for (int q = 0; q < 4; ++q) {
                    float y = eluf(acc[a][m][q] + bb[q]);
                    const ush hi = f2bf(y);
                    vh[q] = hi;
                    vl[q] = f2bf(y - bf2f(hi));
                }
                const int idx = row * 256 + (n0 ^ (8 * (row & 7)));
                *(ushx4*)(Hh + idx) = vh;
                *(ushx4*)(Hl + idx) = vl;
            }
        }
    }
    __syncthreads();

    // layer 2: 256 -> 256 (in place)
    {
        f32x4 acc[4][2];
        #pragma unroll
        for (int a = 0; a < 4; ++a)
            #pragma unroll
            for (int m = 0; m < 2; ++m) acc[a][m] = f32x4{0.f, 0.f, 0.f, 0.f};
        #pragma unroll 1
        for (int kb = 0; kb < 8; ++kb) {
            bf16x8 wh[4], wl[4];
            #pragma unroll
            for (int a = 0; a < 4; ++a) {
                const size_t o = ((size_t)(kb * 16 + (wv * 4 + a)) * 64 + lane) * 8;
                wh[a] = *(const bf16x8*)(P.w2h + o);
                wl[a] = *(const bf16x8*)(P.w2l + o);
            }
            #pragma unroll
            for (int m = 0; m < 2; ++m) {
                const int row = 16 * m + r;
                const int k0 = kb * 32 + 8 * g;
                const int idx = row * 256 + (k0 ^ (8 * (row & 7)));
                bf16x8 hh = *(const bf16x8*)(Hh + idx);
                bf16x8 hl = *(const bf16x8*)(Hl + idx);
                #pragma unroll
                for (int a = 0; a < 4; ++a) {
                    acc[a][m] = MFMA(wh[a], hh, acc[a][m]);
                    acc[a][m] = MFMA(wh[a], hl, acc[a][m]);
                    acc[a][m] = MFMA(wl[a], hh, acc[a][m]);
                }
            }
        }
        __syncthreads();
        #pragma unroll
        for (int a = 0; a < 4; ++a) {
            const int n0 = (wv * 4 + a) * 16 + 4 * g;
            const float4 bv = *(const float4*)(P.b2 + n0);
            const float bb[4] = {bv.x, bv.y, bv.z, bv.w};
            #pragma unroll
            for (int m = 0; m < 2; ++m) {
                const int row = 16 * m + r;
                ushx4 vh, vl;
                #pragma unroll
                for (int q = 0; q < 4; ++q) {
                    float y = eluf(acc[a][m][q] + bb[q]);
                    const ush hi = f2bf(y);
                    vh[q] = hi;
                    vl[q] = f2bf(y - bf2f(hi));
                }
                const int idx = row * 256 + (n0 ^ (8 * (row & 7)));
                *(ushx4*)(Hh + idx) = vh;
                *(ushx4*)(Hl + idx) = vl;
            }
        }
    }
    __syncthreads();

    // layer 3: 256 -> 128
    {
        #pragma unroll
        for (int a = 0; a < 2; ++a)
            #pragma unroll
            for (int m = 0; m < 2; ++m) acc3[a][m] = f32x4{0.f, 0.f, 0.f, 0.f};
        #pragma unroll 1
        for (int kb = 0; kb < 8; ++kb) {
            bf16x8 wh[2], wl[2];
            #pragma unroll
            for (int a = 0; a < 2; ++a) {
                const size_t o = ((size_t)(kb * 8 + (wv * 2 + a)) * 64 + lane) * 8;
                wh[a] = *(const bf16x8*)(P.w3h + o);
                wl[a] = *(const bf16x8*)(P.w3l + o);
            }
            #pragma unroll
            for (int m = 0; m < 2; ++m) {
                const int row = 16 * m + r;
                const int k0 = kb * 32 + 8 * g;
                const int idx = row * 256 + (k0 ^ (8 * (row & 7)));
                bf16x8 hh = *(const bf16x8*)(Hh + idx);
                bf16x8 hl = *(const bf16x8*)(Hl + idx);
                #pragma unroll
                for (int a = 0; a < 2; ++a) {
                    acc3[a][m] = MFMA(wh[a], hh, acc3[a][m]);
                    acc3[a][m] = MFMA(wh[a], hl, acc3[a][m]);
                    acc3[a][m] = MFMA(wl[a], hh, acc3[a][m]);
                }
            }
        }
    }
}

// ---------------------------------------------------------------------------
// prep: pack (blocks [0,960)) + agg/ma-count ([960,9152)) + f1z (last).
// ---------------------------------------------------------------------------
struct PackDesc { const float* src; ush* dh; ush* dl; int kreal; int kbn; int nbn; };
struct PrepArgs {
    PackDesc d[15];
    const float* op; const int* pre_adj; const int* sub_adj; const int* ma_adj;
    const int* bidx;
    float* pre_agg; float* sub_agg; int* counts;
    const float *z_b1, *z_w2, *z_b2, *z_w3, *z_b3;
    float* f1z;
};

__global__ __launch_bounds__(256) void prep_kernel(PrepArgs A)
{
    __shared__ float shmem[544];
    const int blk = blockIdx.x;
    const int t = threadIdx.x;
    if (blk < 960) {
        const PackDesc d = A.d[blk >> 6];
        const int sub = blk & 63;
        const int total = d.kbn * d.nbn * 512;
        const int N = d.nbn * 16;
        for (int idx = sub * 256 + t; idx < total; idx += 64 * 256) {
            const int e = idx & 7;
            const int l = (idx >> 3) & 63;
            const int t2 = idx >> 9;
            const int nb = t2 % d.nbn;
            const int kb = t2 / d.nbn;
            const int k = kb * 32 + ((l >> 4) << 3) + e;
            const int n = nb * 16 + (l & 15);
            const float v = (k < d.kreal) ? d.src[(size_t)k * N + n] : 0.f;
            const ush hi = f2bf(v);
            d.dh[idx] = hi;
            d.dl[idx] = f2bf(v - bf2f(hi));
        }
    } else if (blk < 960 + NROW) {
        const int e = blk - 960;
        const int i = e & 511, b = e >> 9;
        const int bi = A.bidx[b];
        // ma-edge count (wave 0)
        if (t < 64) {
            const int active = (A.ma_adj[((size_t)bi * NOPc + i) * NMAc + t] != 0) ? 1 : 0;
            const unsigned long long mk = __ballot(active);
            if (t == 0) A.counts[(size_t)b * NOPc + i] = (int)__popcll(mk);
        }
        const int d = t & 15, g = t >> 4;
        const int* pr = A.pre_adj + ((size_t)bi * NOPc + i) * NOPc;
        const int* sr = A.sub_adj + ((size_t)bi * NOPc + i) * NOPc;
        const float* opb = A.op + (size_t)b * NOPc * 16;
        float ap = 0.f, as = 0.f;
        for (int j = g; j < NOPc; j += 16) {
            const float v = opb[j * 16 + d];
            if (pr[j]) ap += v;
            if (sr[j]) as += v;
        }
        shmem[0 * 256 + g * 16 + d] = ap;
        shmem[1 * 256 + g * 16 + d] = as;
        __syncthreads();
        if (t < 32) {
            const int which = t >> 4, dd = t & 15;
            float s = 0.f;
            #pragma unroll
            for (int gg = 0; gg < 16; ++gg) s += shmem[which * 256 + gg * 16 + dd];
            float* dst = which ? A.sub_agg : A.pre_agg;
            dst[((size_t)b * NOPc + i) * 16 + dd] = s;
        }
    } else {
        // f1z = MLP0(0) in raw f32
        shmem[t] = eluf(A.z_b1[t]);
        __syncthreads();
        float acc = A.z_b2[t];
        for (int k = 0; k < 256; ++k) acc += shmem[k] * A.z_w2[(size_t)k * 256 + t];
        __syncthreads();
        shmem[256 + t] = eluf(acc);
        __syncthreads();
        if (t < 128) {
            float a = A.z_b3[t];
            for (int k = 0; k < 256; ++k) a += shmem[256 + k] * A.z_w3[(size_t)k * 128 + t];
            A.f1z[t] = a;
        }
    }
}

// ---------------------------------------------------------------------------
// scan: exclusive prefix over counts[8192] -> bases, natot; zero Xq pad rows.
// ---------------------------------------------------------------------------
__global__ __launch_bounds__(1024) void scan_kernel(const int* __restrict__ counts,
                                                    int* __restrict__ bases,
                                                    int* __restrict__ natot,
                                                    ush* __restrict__ Xq)
{
    __shared__ int tot[1024];
    const int t = threadIdx.x;
    int loc[8];
    int s = 0;
    #pragma unroll
    for (int k = 0; k < 8; ++k) { loc[k] = s; s += counts[t * 8 + k]; }
    tot[t] = s;
    __syncthreads();
    for (int off = 1; off < 1024; off <<= 1) {
        const int v = (t >= off) ? tot[t - off] : 0;
        __syncthreads();
        tot[t] += v;
        __syncthreads();
    }
    const int base = tot[t] - s;   // exclusive
    #pragma unroll
    for (int k = 0; k < 8; ++k) bases[t * 8 + k] = base + loc[k];
    const int NA = tot[1023];
    if (t == 0) *natot = NA;
    __syncthreads();
    const int NApad = (NA + 63) & ~63;
    for (int idx = NA * 16 + t; idx < NApad * 16; idx += 1024) Xq[idx] = 0;
}

// ---------------------------------------------------------------------------
// scatter: build dense bf16 edge matrix Xq[NA][16] (sorted by rid=(b,i)),
// rowseg[NA]; zero sum/cnt.
// ---------------------------------------------------------------------------
__global__ __launch_bounds__(256) void scatter_kernel(
    const float* __restrict__ ma, const float* __restrict__ eg,
    const int* __restrict__ ma_adj, const int* __restrict__ bidx,
    const int* __restrict__ bases,
    ush* __restrict__ Xq, ush* __restrict__ rowseg,
    float* __restrict__ sumG, float* __restrict__ cntG)
{
    const int tid = threadIdx.x;
    const int rid = blockIdx.x * 4 + (tid >> 6);
    const int lane = tid & 63;
    const int b = rid >> 9, i = rid & 511;
    const int bi = bidx[b];
    const int act = (ma_adj[((size_t)bi * NOPc + i) * NMAc + lane] != 0) ? 1 : 0;
    const unsigned long long mk = __ballot(act);
    if (act) {
        const int pos = bases[rid] + (int)__popcll(mk & ((1ull << lane) - 1ull));
        const float4* mp = (const float4*)(ma + ((size_t)b * NMAc + lane) * 8);
        const float4* ep = (const float4*)(eg + (((size_t)b * NOPc + i) * NMAc + lane) * 8);
        const float4 m0 = mp[0], m1 = mp[1], e0 = ep[0], e1 = ep[1];
        uint4 u0, u1;
        u0.x = pkbf_rne(m0.x, m0.y); u0.y = pkbf_rne(m0.z, m0.w);
        u0.z = pkbf_rne(m1.x, m1.y); u0.w = pkbf_rne(m1.z, m1.w);
        u1.x = pkbf_rne(e0.x, e0.y); u1.y = pkbf_rne(e0.z, e0.w);
        u1.z = pkbf_rne(e1.x, e1.y); u1.w = pkbf_rne(e1.z, e1.w);
        uint4* dst = (uint4*)(Xq + (size_t)pos * 16);
        dst[0] = u0;
        dst[1] = u1;
        rowseg[pos] = (ush)rid;
    }
    // zero sum/cnt for this rid (two 64-col halves per wave)
    sumG[(size_t)rid * 128 + lane] = 0.f;
    sumG[(size_t)rid * 128 + 64 + lane] = 0.f;
    cntG[(size_t)rid * 128 + lane] = 0.f;
    cntG[(size_t)rid * 128 + 64 + lane] = 0.f;
}

// ---------------------------------------------------------------------------
// edge_mlp: dense 64-row tiles over the edge queue, single-plane bf16,
// in-LDS segmented pooling -> global atomic sum/cnt.
// ---------------------------------------------------------------------------
__global__ __launch_bounds__(256) void edge_mlp_kernel(
    const ush* __restrict__ Xq, const ush* __restrict__ rowseg,
    const int* __restrict__ natot, MlpPack P,
    float* __restrict__ sumG, float* __restrict__ cntG)
{
    const int NA = *natot;
    const int tile = blockIdx.x;
    if (tile * 64 >= NA) return;
    __shared__ ush Hh[64 * 256];           // 32 KB; aliased as f32 f1buf[64][128] later
    __shared__ ush segid[64];
    const int tid = threadIdx.x;
    const int wv = tid >> 6, lane = tid & 63, r = lane & 15, g = lane >> 4;
    const int rows = min(64, NA - tile * 64);
    if (tid < 64) segid[tid] = rowseg[(size_t)tile * 64 + tid];   // pad rows unused

    // ---- layer 1: 32 -> 256, X direct from dense global queue ----
    {
        f32x4 acc[4][4];
        #pragma unroll
        for (int a = 0; a < 4; ++a)
            #pragma unroll
            for (int m = 0; m < 4; ++m) acc[a][m] = f32x4{0.f, 0.f, 0.f, 0.f};
        bf16x8 wh[4];
        #pragma unroll
        for (int a = 0; a < 4; ++a)
            wh[a] = *(const bf16x8*)(P.w1h + ((size_t)(wv * 4 + a) * 64 + lane) * 8);
        #pragma unroll
        for (int m = 0; m < 4; ++m) {
            const int gr = tile * 64 + 16 * m + r;
            bf16x8 xh = {0, 0, 0, 0, 0, 0, 0, 0};
            if (g < 2) xh = *(const bf16x8*)(Xq + (size_t)gr * 16 + 8 * g);
            #pragma unroll
            for (int a = 0; a < 4; ++a) acc[a][m] = MFMA(wh[a], xh, acc[a][m]);
        }
        #pragma unroll
        for (int a = 0; a < 4; ++a) {
            const int n0 = (wv * 4 + a) * 16 + 4 * g;
            const float4 bv = *(const float4*)(P.b1 + n0);
            #pragma unroll
            for (int m = 0; m < 4; ++m) {
                const int row = 16 * m + r;
                const float y0 = eluf_fast(acc[a][m][0] + bv.x);
                const float y1 = eluf_fast(acc[a][m][1] + bv.y);
                const float y2 = eluf_fast(acc[a][m][2] + bv.z);
                const float y3 = eluf_fast(acc[a][m][3] + bv.w);
                uint2 u; u.x = pkbf(y0, y1); u.y = pkbf(y2, y3);
                *(uint2*)(Hh + row * 256 + (n0 ^ (8 * (row & 7)))) = u;
            }
        }
    }
    __syncthreads();

    // ---- layer 2: 256 -> 256 (in place) ----
    {
        f32x4 acc[4][4];
        #pragma unroll
        for (int a = 0; a < 4; ++a)
            #pragma unroll
            for (int m = 0; m < 4; ++m) acc[a][m] = f32x4{0.f, 0.f, 0.f, 0.f};
        #pragma unroll 1
        for (int kb = 0; kb < 8; ++kb) {
            bf16x8 wh[4];
            #pragma unroll
            for (int a = 0; a < 4; ++a)
                wh[a] = *(const bf16x8*)(P.w2h + ((size_t)(kb * 16 + (wv * 4 + a)) * 64 + lane) * 8);
            #pragma unroll
            for (int m = 0; m < 4; ++m) {
                const int row = 16 * m + r;
                const int k0 = kb * 32 + 8 * g;
                bf16x8 hh = *(const bf16x8*)(Hh + row * 256 + (k0 ^ (8 * (row & 7))));
                #pragma unroll
                for (int a = 0; a < 4; ++a) acc[a][m] = MFMA(wh[a], hh, acc[a][m]);
            }
        }
        __syncthreads();
        #pragma unroll
        for (int a = 0; a < 4; ++a) {
            const int n0 = (wv * 4 + a) * 16 + 4 * g;
            const float4 bv = *(const float4*)(P.b2 + n0);
            #pragma unroll
            for (int m = 0; m < 4; ++m) {
                const int row = 16 * m + r;
                const float y0 = eluf_fast(acc[a][m][0] + bv.x);
                const float y1 = eluf_fast(acc[a][m][1] + bv.y);
                const float y2 = eluf_fast(acc[a][m][2] + bv.z);
                const float y3 = eluf_fast(acc[a][m][3] + bv.w);
                uint2 u; u.x = pkbf(y0, y1); u.y = pkbf(y2, y3);
                *(uint2*)(Hh + row * 256 + (n0 ^ (8 * (row & 7)))) = u;
            }
        }
    }
    __syncthreads();

    // ---- layer 3: 256 -> 128 ----
    f32x4 acc3[2][4];
    #pragma unroll
    for (int a = 0; a < 2; ++a)
        #pragma unroll
        for (int m = 0; m < 4; ++m) acc3[a][m] = f32x4{0.f, 0.f, 0.f, 0.f};
    #pragma unroll 1
    for (int kb = 0; kb < 8; ++kb) {
        bf16x8 wh[2];
        #pragma unroll
        for (int a = 0; a < 2; ++a)
            wh[a] = *(const bf16x8*)(P.w3h + ((size_t)(kb * 8 + (wv * 2 + a)) * 64 + lane) * 8);
        #pragma unroll
        for (int m = 0; m < 4; ++m) {
            const int row = 16 * m + r;
            const int k0 = kb * 32 + 8 * g;
            bf16x8 hh = *(const bf16x8*)(Hh + row * 256 + (k0 ^ (8 * (row & 7))));
            #pragma unroll
            for (int a = 0; a < 2; ++a) acc3[a][m] = MFMA(wh[a], hh, acc3[a][m]);
        }
    }
    __syncthreads();            // all Hh reads complete before aliasing as f1buf

    // ---- write y rows to LDS f1buf (f32, XOR-swizzled) ----
    float* f1buf = (float*)Hh;
    #pragma unroll
    for (int a = 0; a < 2; ++a) {
        const int n0 = (wv * 2 + a) * 16 + 4 * g;
        const float4 bv = *(const float4*)(P.b3 + n0);
        #pragma unroll
        for (int m = 0; m < 4; ++m) {
            const int row = 16 * m + r;
            float4 y;
            y.x = acc3[a][m][0] + bv.x;
            y.y = acc3[a][m][1] + bv.y;
            y.z = acc3[a][m][2] + bv.z;
            y.w = acc3[a][m][3] + bv.w;
            *(float4*)&f1buf[row * 128 + (n0 ^ ((row & 7) << 2))] = y;
        }
    }
    __syncthreads();

    // ---- segmented pooling: thread = (col, row-half); rows sorted by rid ----
    {
        const int c = tid & 127, h = tid >> 7;
        const int r0p = h * 32, r1p = min(r0p + 32, rows);
        float accS = 0.f, accC = 0.f;
        int cur = -1;
        for (int rl = r0p; rl < r1p; ++rl) {
            const int sg = (int)segid[rl];
            if (sg != cur) {
                if (cur >= 0) {
                    atomicAdd(&sumG[(size_t)cur * 128 + c], accS);
                    atomicAdd(&cntG[(size_t)cur * 128 + c], accC);
                }
                cur = sg; accS = 0.f; accC = 0.f;
            }
            const float y = f1buf[rl * 128 + (c ^ ((rl & 7) << 2))];
            accS += y;
            accC += (y != 0.f) ? 1.f : 0.f;
        }
        if (cur >= 0) {
            atomicAdd(&sumG[(size_t)cur * 128 + c], accS);
            atomicAdd(&cntG[(size_t)cur * 128 + c], accC);
        }
    }
}

// ---------------------------------------------------------------------------
// Merged f1 kernel: blockIdx.y = path (0=pre,1=sub,2=self,3=mlp4), 32 rows/blk.
// Path 3 finalizes x2 inline from sum/cnt (+f1z correction).
// ---------------------------------------------------------------------------
struct F1Args {
    const float* X[4]; MlpPack P[4]; float* f1[4]; float* ut[4];
    const float* sumG; const float* cntG; const int* counts; const float* f1z;
};

__global__ __launch_bounds__(256, 3) void f1_kernel(F1Args A, const float* __restrict__ attn)
{
    __shared__ ush Xh[32 * 128], Xl[32 * 128];
    __shared__ ush Hh[32 * 256], Hl[32 * 256];
    __shared__ float UT[32];
    const int p = blockIdx.y;
    const int KB1 = (p == 3) ? 4 : 1;
    const int KX = KB1 * 32;
    const MlpPack P = A.P[p];
    float* f1_out = A.f1[p];
    float* ut_out = A.ut[p];
    const int tid = threadIdx.x;
    const int row0 = blockIdx.x * 32;
    if (tid < 32) UT[tid] = 0.f;
    if (p == 3) {
        for (int idx = tid; idx < 32 * 128; idx += 256) {
            const int row = idx >> 7, k = idx & 127;
            const size_t rid = (size_t)(row0 + row);
            const float nz = (float)(64 - A.counts[rid]);
            const float fz = A.f1z[k];
            const float v = (A.sumG[rid * 128 + k] + nz * fz)
                          / (A.cntG[rid * 128 + k] + nz * ((fz != 0.f) ? 1.f : 0.f));
            const ush hi = f2bf(v);
            Xh[idx] = hi;
            Xl[idx] = f2bf(v - bf2f(hi));
        }
    } else {
        const float* Xg = A.X[p];
        for (int idx = tid; idx < 32 * 32; idx += 256) {
            const int row = idx >> 5, k = idx & 31;
            float v = 0.f;
            if (k < 16) v = Xg[(size_t)(row0 + row) * 16 + k];
            const ush hi = f2bf(v);
            Xh[idx] = hi;
            Xl[idx] = f2bf(v - bf2f(hi));
        }
    }
    __syncthreads();
    f32x4 acc3[2][2];
    mlp3_core32(P, KB1, Xh, Xl, Hh, Hl, acc3);

    const int wv = tid >> 6, lane = tid & 63, r = lane & 15, g = lane >> 4;
    float utp[2] = {0.f, 0.f};
    #pragma unroll
    for (int a = 0; a < 2; ++a) {
        const int n0 = (wv * 2 + a) * 16 + 4 * g;
        const float4 bv = *(const float4*)(P.b3 + n0);
        const float4 av = *(const float4*)(attn + n0);
        #pragma unroll
        for (int m = 0; m < 2; ++m) {
            float4 y;
            y.x = acc3[a][m][0] + bv.x;
            y.y = acc3[a][m][1] + bv.y;
            y.z = acc3[a][m][2] + bv.z;
            y.w = acc3[a][m][3] + bv.w;
            *(float4*)&f1_out[(size_t)(row0 + 16 * m + r) * OUTc + n0] = y;
            utp[m] += y.x * av.x + y.y * av.y + y.z * av.z + y.w * av.w;
        }
    }
    #pragma unroll
    for (int m = 0; m < 2; ++m) {
        float v = utp[m];
        v += __shfl_xor(v, 16);
        v += __shfl_xor(v, 32);
        if (lane < 16) atomicAdd(&UT[16 * m + r], v);
    }
    __syncthreads();
    if (tid < 32) ut_out[row0 + tid] = UT[tid];
}

// ---------------------------------------------------------------------------
// combine with inline per-batch softmax: block = (b, 32-row chunk).
// ---------------------------------------------------------------------------
__global__ __launch_bounds__(256) void combine2_kernel(
    const float* __restrict__ uts,
    const float* __restrict__ pre_f1, const float* __restrict__ sub_f1,
    const float* __restrict__ self_f1, const float* __restrict__ ma_f2,
    float* __restrict__ out)
{
    __shared__ float sc[4 * NOPc];
    __shared__ float red[256];
    const int b = blockIdx.x >> 4, chunk = blockIdx.x & 15;
    const int t = threadIdx.x;
    const float* put = uts + 0 * NBb * NOPc + (size_t)b * NOPc;
    const float* sut = uts + 1 * NBb * NOPc + (size_t)b * NOPc;
    const float* eut = uts + 2 * NBb * NOPc + (size_t)b * NOPc;
    const float* mut = uts + 3 * NBb * NOPc + (size_t)b * NOPc;
    for (int i = t; i < NOPc; i += 256) {
        const float se = eut[i];
        const float s0 = put[i] + se, s1 = sut[i] + se, s2 = se + se, s3 = mut[i] + se;
        sc[0 * NOPc + i] = s0 > 0.f ? s0 : 0.2f * s0;
        sc[1 * NOPc + i] = s1 > 0.f ? s1 : 0.2f * s1;
        sc[2 * NOPc + i] = s2 > 0.f ? s2 : 0.2f * s2;
        sc[3 * NOPc + i] = s3 > 0.f ? s3 : 0.2f * s3;
    }
    __syncthreads();
    float mx = -INFINITY;
    for (int idx = t; idx < 4 * NOPc; idx += 256) mx = fmaxf(mx, sc[idx]);
    red[t] = mx;
    __syncthreads();
    for (int s = 128; s > 0; s >>= 1) { if (t < s) red[t] = fmaxf(red[t], red[t + s]); __syncthreads(); }
    mx = red[0];
    __syncthreads();
    float ps = 0.f;
    for (int idx = t; idx < 4 * NOPc; idx += 256) {
        const float e = expf(sc[idx] - mx);
        sc[idx] = e;
        ps += e;
    }
    red[t] = ps;
    __syncthreads();
    for (int s = 128; s > 0; s >>= 1) { if (t < s) red[t] += red[t + s]; __syncthreads(); }
    const float invZ = 1.f / red[0];

    const size_t base4 = (size_t)b * 16384 + (size_t)chunk * 1024;   // float4 units
    #pragma unroll
    for (int k = 0; k < 4; ++k) {
        const size_t e4 = base4 + k * 256 + t;
        const int i = (int)((e4 >> 5) & 511);
        const float a0 = sc[0 * NOPc + i] * invZ;
        const float a1 = sc[1 * NOPc + i] * invZ;
        const float a2 = sc[2 * NOPc + i] * invZ;
        const float a3 = sc[3 * NOPc + i] * invZ;
        const float4 vp = ((const float4*)pre_f1)[e4];
        const float4 vs = ((const float4*)sub_f1)[e4];
        const float4 ve = ((const float4*)self_f1)[e4];
        const float4 vm = ((const float4*)ma_f2)[e4];
        float4 o;
        o.x = 1.f / (1.f + expf(-(a0 * vp.x + a1 * vs.x + a2 * ve.x + a3 * vm.x)));
        o.y = 1.f / (1.f + expf(-(a0 * vp.y + a1 * vs.y + a2 * ve.y + a3 * vm.y)));
        o.z = 1.f / (1.f + expf(-(a0 * vp.z + a1 * vs.z + a2 * ve.z + a3 * vm.z)));
        o.w = 1.f / (1.f + expf(-(a0 * vp.w + a1 * vs.w + a2 * ve.w + a3 * vm.w)));
        ((float4*)out)[e4] = o;
    }
}

extern "C" void kernel_launch(void* const* d_in, const int* in_sizes, int n_in,
                              void* d_out, int out_size, void* d_ws, size_t ws_size,
                              hipStream_t stream) {
    const float* op      = (const float*)d_in[0];
    const float* ma      = (const float*)d_in[1];
    const float* eg      = (const float*)d_in[2];
    const int*   ma_adj  = (const int*)d_in[3];
    const int*   pre_adj = (const int*)d_in[4];
    const int*   sub_adj = (const int*)d_in[5];
    const int*   bidx    = (const int*)d_in[6];
    const float* attn    = (const float*)d_in[7];
    float* out = (float*)d_out;
    const float* Wraw[5][6];
    for (int m = 0; m < 5; ++m)
        for (int j = 0; j < 6; ++j)
            Wraw[m][j] = (const float*)d_in[8 + 6 * m + j];

    // ---- workspace layout ----
    float* wsf = (float*)d_ws;
    float* pre_agg = wsf;  wsf += (size_t)NROW * 16;
    float* sub_agg = wsf;  wsf += (size_t)NROW * 16;
    float* pre_f1  = wsf;  wsf += (size_t)NROW * OUTc;
    float* sub_f1  = wsf;  wsf += (size_t)NROW * OUTc;
    float* self_f1 = wsf;  wsf += (size_t)NROW * OUTc;
    float* ma_f2   = wsf;  wsf += (size_t)NROW * OUTc;
    float* uts     = wsf;  wsf += (size_t)4 * NROW;
    float* f1z     = wsf;  wsf += 128;
    float* sumG    = wsf;  wsf += (size_t)NROW * 128;
    float* cntG    = wsf;  wsf += (size_t)NROW * 128;
    int*   counts  = (int*)wsf;   wsf += NROW;
    int*   bases   = (int*)wsf;   wsf += NROW;
    int*   natot   = (int*)wsf;   wsf += 16;
    ush*   rowseg  = (ush*)wsf;   wsf += NEMAX / 2;
    ush*   Xq      = (ush*)wsf;   wsf += (size_t)NEMAX * 8;   // NEMAX rows * 16 ush
    ush*   packp   = (ush*)wsf;

    PrepArgs pa;
    MlpPack pk[5];
    for (int m = 0; m < 5; ++m) {
        const int kre[3] = { (m == 4 ? 128 : 16), 256, 256 };
        const int kbn[3] = { (m == 4 ? 4 : 1), 8, 8 };
        const int nbn[3] = { 16, 16, 8 };
        const ush* dh[3]; const ush* dl[3];
        for (int j = 0; j < 3; ++j) {
            const int id = m * 3 + j;
            pa.d[id].src = Wraw[m][2 * j];
            pa.d[id].kreal = kre[j];
            pa.d[id].kbn = kbn[j];
            pa.d[id].nbn = nbn[j];
            const int cnt = kbn[j] * nbn[j] * 512;
            pa.d[id].dh = packp; dh[j] = packp; packp += cnt;
            pa.d[id].dl = packp; dl[j] = packp; packp += cnt;
        }
        pk[m].w1h = dh[0]; pk[m].w1l = dl[0];
        pk[m].w2h = dh[1]; pk[m].w2l = dl[1];
        pk[m].w3h = dh[2]; pk[m].w3l = dl[2];
        pk[m].b1 = Wraw[m][1]; pk[m].b2 = Wraw[m][3]; pk[m].b3 = Wraw[m][5];
    }
    pa.op = op; pa.pre_adj = pre_adj; pa.sub_adj = sub_adj; pa.ma_adj = ma_adj;
    pa.bidx = bidx;
    pa.pre_agg = pre_agg; pa.sub_agg = sub_agg; pa.counts = counts;
    pa.z_b1 = Wraw[0][1]; pa.z_w2 = Wraw[0][2]; pa.z_b2 = Wraw[0][3];
    pa.z_w3 = Wraw[0][4]; pa.z_b3 = Wraw[0][5];
    pa.f1z = f1z;

    F1Args fa;
    fa.X[0] = pre_agg; fa.X[1] = sub_agg; fa.X[2] = op;  fa.X[3] = nullptr;
    fa.P[0] = pk[1];   fa.P[1] = pk[2];   fa.P[2] = pk[3]; fa.P[3] = pk[4];
    fa.f1[0] = pre_f1; fa.f1[1] = sub_f1; fa.f1[2] = self_f1; fa.f1[3] = ma_f2;
    fa.ut[0] = uts + 0 * NROW;
    fa.ut[1] = uts + 1 * NROW;
    fa.ut[2] = uts + 2 * NROW;
    fa.ut[3] = uts + 3 * NROW;
    fa.sumG = sumG; fa.cntG = cntG; fa.counts = counts; fa.f1z = f1z;

    prep_kernel<<<dim3(960 + NROW + 1), 256, 0, stream>>>(pa);
    scan_kernel<<<1, 1024, 0, stream>>>(counts, bases, natot, Xq);
    scatter_kernel<<<dim3(NROW / 4), 256, 0, stream>>>(ma, eg, ma_adj, bidx, bases,
                                                       Xq, rowseg, sumG, cntG);
    edge_mlp_kernel<<<dim3(NEMAX / 64), 256, 0, stream>>>(Xq, rowseg, natot, pk[0], sumG, cntG);
    f1_kernel<<<dim3(256, 4), 256, 0, stream>>>(fa, attn);
    combine2_kernel<<<dim3(NBb * 16), 256, 0, stream>>>(uts, pre_f1, sub_f1, self_f1, ma_f2, out);
}

// Round 9
// 186.090 us; speedup vs baseline: 11.1592x; 1.2012x over previous
//
#include <hip/hip_runtime.h>
#include <math.h>

#define NBb  16
#define NOPc 512
#define NMAc 64
#define HIDc 256
#define OUTc 128
#define NROW (NBb * NOPc)          // 8192 (b,i) rows
#define NEMAX (NROW * NMAc)        // 524288 max edges

typedef unsigned int uint32;
typedef unsigned short ush;
typedef __attribute__((ext_vector_type(8))) short bf16x8;
typedef __attribute__((ext_vector_type(4))) float f32x4;

__device__ __forceinline__ ush f2bf(float v) {
    uint32 u = __float_as_uint(v);
    u += 0x7FFFu + ((u >> 16) & 1u);
    return (ush)(u >> 16);
}
__device__ __forceinline__ float bf2f(ush b) { return __uint_as_float(((uint32)b) << 16); }
__device__ __forceinline__ float eluf(float x) { return x > 0.f ? x : expm1f(x); }
__device__ __forceinline__ float eluf_fast(float x) { return x > 0.f ? x : __expf(x) - 1.f; }
// pack two floats' truncated bf16 into one u32: low = bf16(a), high = bf16(b)
__device__ __forceinline__ uint32 pkbf(float a, float b) {
    return __builtin_amdgcn_perm(__float_as_uint(b), __float_as_uint(a), 0x07060302u);
}
__device__ __forceinline__ uint32 pkbf_rne(float a, float b) {
    return (uint32)f2bf(a) | ((uint32)f2bf(b) << 16);
}
// truncation hi/lo split of 2 floats (residual captured exactly by lo plane)
__device__ __forceinline__ void split2(float a, float b, uint32& hp, uint32& lp) {
    const uint32 ua = __float_as_uint(a), ub = __float_as_uint(b);
    hp = __builtin_amdgcn_perm(ub, ua, 0x07060302u);
    const float ra = a - __uint_as_float(ua & 0xFFFF0000u);
    const float rb = b - __uint_as_float(ub & 0xFFFF0000u);
    lp = __builtin_amdgcn_perm(__float_as_uint(rb), __float_as_uint(ra), 0x07060302u);
}

#define MFMA(A, B, C) __builtin_amdgcn_mfma_f32_16x16x32_bf16((A), (B), (C), 0, 0, 0)

// pack[((kb*nbn + nb)*64 + lane)*8 + e] = W[kb*32 + 8*(lane>>4) + e][nb*16 + (lane&15)]
struct MlpPack {
    const ush *w1h, *w1l, *w2h, *w2l, *w3h, *w3l;
    const float *b1, *b2, *b3;
};

// ---------------------------------------------------------------------------
// Hi/lo (bf16x3) 3-layer core over a 32-row tile (pre/sub/self/MLP4 paths).
// Fast-ELU + truncation split epilogues.
// ---------------------------------------------------------------------------
__device__ __forceinline__ void mlp3_core32(
    const MlpPack& P, const int KB1,
    const ush* Xh, const ush* Xl, ush* Hh, ush* Hl, f32x4 acc3[2][2])
{
    const int tid = threadIdx.x;
    const int wv = tid >> 6, lane = tid & 63, r = lane & 15, g = lane >> 4;
    const int KX = KB1 * 32;

    // layer 1: KX -> 256
    {
        f32x4 acc[4][2];
        #pragma unroll
        for (int a = 0; a < 4; ++a)
            #pragma unroll
            for (int m = 0; m < 2; ++m) acc[a][m] = f32x4{0.f, 0.f, 0.f, 0.f};
        #pragma unroll 1
        for (int kb = 0; kb < KB1; ++kb) {
            bf16x8 wh[4], wl[4];
            #pragma unroll
            for (int a = 0; a < 4; ++a) {
                const size_t o = ((size_t)(kb * 16 + (wv * 4 + a)) * 64 + lane) * 8;
                wh[a] = *(const bf16x8*)(P.w1h + o);
                wl[a] = *(const bf16x8*)(P.w1l + o);
            }
            #pragma unroll
            for (int m = 0; m < 2; ++m) {
                const int row = 16 * m + r;
                const int ki = kb * 32 + 8 * g;
                bf16x8 xh = *(const bf16x8*)(Xh + row * KX + ki);
                bf16x8 xl = *(const bf16x8*)(Xl + row * KX + ki);
                #pragma unroll
                for (int a = 0; a < 4; ++a) {
                    acc[a][m] = MFMA(wh[a], xh, acc[a][m]);
                    acc[a][m] = MFMA(wh[a], xl, acc[a][m]);
                    acc[a][m] = MFMA(wl[a], xh, acc[a][m]);
                }
            }
        }
        #pragma unroll
        for (int a = 0; a < 4; ++a) {
            const int n0 = (wv * 4 + a) * 16 + 4 * g;
            const float4 bv = *(const float4*)(P.b1 + n0);
            #pragma unroll
            for (int m = 0; m < 2; ++m) {
                const int row = 16 * m + r;
                const float y0 = eluf_fast(acc[a][m][0] + bv.x);
                const float y1 = eluf_fast(acc[a][m][1] + bv.y);
                const float y2 = eluf_fast(acc[a][m][2] + bv.z);
                const float y3 = eluf_fast(acc[a][m][3] + bv.w);
                uint2 uh, ul;
                split2(y0, y1, uh.x, ul.x);
                split2(y2, y3, uh.y, ul.y);
                const int idx = row * 256 + (n0 ^ (8 * (row & 7)));
                *(uint2*)(Hh + idx) = uh;
                *(uint2*)(Hl + idx) = ul;
            }
        }
    }
    __syncthreads();

    // layer 2: 256 -> 256 (in place)
    {
        f32x4 acc[4][2];
        #pragma unroll
        for (int a = 0; a < 4; ++a)
            #pragma unroll
            for (int m = 0; m < 2; ++m) acc[a][m] = f32x4{0.f, 0.f, 0.f, 0.f};
        #pragma unroll 1
        for (int kb = 0; kb < 8; ++kb) {
            bf16x8 wh[4], wl[4];
            #pragma unroll
            for (int a = 0; a < 4; ++a) {
                const size_t o = ((size_t)(kb * 16 + (wv * 4 + a)) * 64 + lane) * 8;
                wh[a] = *(const bf16x8*)(P.w2h + o);
                wl[a] = *(const bf16x8*)(P.w2l + o);
            }
            #pragma unroll
            for (int m = 0; m < 2; ++m) {
                const int row = 16 * m + r;
                const int k0 = kb * 32 + 8 * g;
                const int idx = row * 256 + (k0 ^ (8 * (row & 7)));
                bf16x8 hh = *(const bf16x8*)(Hh + idx);
                bf16x8 hl = *(const bf16x8*)(Hl + idx);
                #pragma unroll
                for (int a = 0; a < 4; ++a) {
                    acc[a][m] = MFMA(wh[a], hh, acc[a][m]);
                    acc[a][m] = MFMA(wh[a], hl, acc[a][m]);
                    acc[a][m] = MFMA(wl[a], hh, acc[a][m]);
                }
            }
        }
        __syncthreads();
        #pragma unroll
        for (int a = 0; a < 4; ++a) {
            const int n0 = (wv * 4 + a) * 16 + 4 * g;
            const float4 bv = *(const float4*)(P.b2 + n0);
            #pragma unroll
            for (int m = 0; m < 2; ++m) {
                const int row = 16 * m + r;
                const float y0 = eluf_fast(acc[a][m][0] + bv.x);
                const float y1 = eluf_fast(acc[a][m][1] + bv.y);
                const float y2 = eluf_fast(acc[a][m][2] + bv.z);
                const float y3 = eluf_fast(acc[a][m][3] + bv.w);
                uint2 uh, ul;
                split2(y0, y1, uh.x, ul.x);
                split2(y2, y3, uh.y, ul.y);
                const int idx = row * 256 + (n0 ^ (8 * (row & 7)));
                *(uint2*)(Hh + idx) = uh;
                *(uint2*)(Hl + idx) = ul;
            }
        }
    }
    __syncthreads();

    // layer 3: 256 -> 128
    {
        #pragma unroll
        for (int a = 0; a < 2; ++a)
            #pragma unroll
            for (int m = 0; m < 2; ++m) acc3[a][m] = f32x4{0.f, 0.f, 0.f, 0.f};
        #pragma unroll 1
        for (int kb = 0; kb < 8; ++kb) {
            bf16x8 wh[2], wl[2];
            #pragma unroll
            for (int a = 0; a < 2; ++a) {
                const size_t o = ((size_t)(kb * 8 + (wv * 2 + a)) * 64 + lane) * 8;
                wh[a] = *(const bf16x8*)(P.w3h + o);
                wl[a] = *(const bf16x8*)(P.w3l + o);
            }
            #pragma unroll
            for (int m = 0; m < 2; ++m) {
                const int row = 16 * m + r;
                const int k0 = kb * 32 + 8 * g;
                const int idx = row * 256 + (k0 ^ (8 * (row & 7)));
                bf16x8 hh = *(const bf16x8*)(Hh + idx);
                bf16x8 hl = *(const bf16x8*)(Hl + idx);
                #pragma unroll
                for (int a = 0; a < 2; ++a) {
                    acc3[a][m] = MFMA(wh[a], hh, acc3[a][m]);
                    acc3[a][m] = MFMA(wh[a], hl, acc3[a][m]);
                    acc3[a][m] = MFMA(wl[a], hh, acc3[a][m]);
                }
            }
        }
    }
}

// ---------------------------------------------------------------------------
// prep: pack (blocks [0,960)) + agg/ma-count ([960,9152)) + f1z (last).
// ---------------------------------------------------------------------------
struct PackDesc { const float* src; ush* dh; ush* dl; int kreal; int kbn; int nbn; };
struct PrepArgs {
    PackDesc d[15];
    const float* op; const int* pre_adj; const int* sub_adj; const int* ma_adj;
    const int* bidx;
    float* pre_agg; float* sub_agg; int* counts;
    const float *z_b1, *z_w2, *z_b2, *z_w3, *z_b3;
    float* f1z;
};

__global__ __launch_bounds__(256) void prep_kernel(PrepArgs A)
{
    __shared__ float shmem[544];
    const int blk = blockIdx.x;
    const int t = threadIdx.x;
    if (blk < 960) {
        const PackDesc d = A.d[blk >> 6];
        const int sub = blk & 63;
        const int total = d.kbn * d.nbn * 512;
        const int N = d.nbn * 16;
        for (int idx = sub * 256 + t; idx < total; idx += 64 * 256) {
            const int e = idx & 7;
            const int l = (idx >> 3) & 63;
            const int t2 = idx >> 9;
            const int nb = t2 % d.nbn;
            const int kb = t2 / d.nbn;
            const int k = kb * 32 + ((l >> 4) << 3) + e;
            const int n = nb * 16 + (l & 15);
            const float v = (k < d.kreal) ? d.src[(size_t)k * N + n] : 0.f;
            const ush hi = f2bf(v);
            d.dh[idx] = hi;
            d.dl[idx] = f2bf(v - bf2f(hi));
        }
    } else if (blk < 960 + NROW) {
        const int e = blk - 960;
        const int i = e & 511, b = e >> 9;
        const int bi = A.bidx[b];
        if (t < 64) {
            const int active = (A.ma_adj[((size_t)bi * NOPc + i) * NMAc + t] != 0) ? 1 : 0;
            const unsigned long long mk = __ballot(active);
            if (t == 0) A.counts[(size_t)b * NOPc + i] = (int)__popcll(mk);
        }
        const int d = t & 15, g = t >> 4;
        const int* pr = A.pre_adj + ((size_t)bi * NOPc + i) * NOPc;
        const int* sr = A.sub_adj + ((size_t)bi * NOPc + i) * NOPc;
        const float* opb = A.op + (size_t)b * NOPc * 16;
        float ap = 0.f, as = 0.f;
        for (int j = g; j < NOPc; j += 16) {
            const float v = opb[j * 16 + d];
            if (pr[j]) ap += v;
            if (sr[j]) as += v;
        }
        shmem[0 * 256 + g * 16 + d] = ap;
        shmem[1 * 256 + g * 16 + d] = as;
        __syncthreads();
        if (t < 32) {
            const int which = t >> 4, dd = t & 15;
            float s = 0.f;
            #pragma unroll
            for (int gg = 0; gg < 16; ++gg) s += shmem[which * 256 + gg * 16 + dd];
            float* dst = which ? A.sub_agg : A.pre_agg;
            dst[((size_t)b * NOPc + i) * 16 + dd] = s;
        }
    } else {
        // f1z = MLP0(0) in raw f32
        shmem[t] = eluf(A.z_b1[t]);
        __syncthreads();
        float acc = A.z_b2[t];
        for (int k = 0; k < 256; ++k) acc += shmem[k] * A.z_w2[(size_t)k * 256 + t];
        __syncthreads();
        shmem[256 + t] = eluf(acc);
        __syncthreads();
        if (t < 128) {
            float a = A.z_b3[t];
            for (int k = 0; k < 256; ++k) a += shmem[256 + k] * A.z_w3[(size_t)k * 128 + t];
            A.f1z[t] = a;
        }
    }
}

// ---------------------------------------------------------------------------
// scan: exclusive prefix over counts[8192] -> bases, natot; zero/sentinel pad.
// ---------------------------------------------------------------------------
__global__ __launch_bounds__(1024) void scan_kernel(const int* __restrict__ counts,
                                                    int* __restrict__ bases,
                                                    int* __restrict__ natot,
                                                    ush* __restrict__ Xq,
                                                    ush* __restrict__ rowseg)
{
    __shared__ int tot[1024];
    const int t = threadIdx.x;
    int loc[8];
    int s = 0;
    #pragma unroll
    for (int k = 0; k < 8; ++k) { loc[k] = s; s += counts[t * 8 + k]; }
    tot[t] = s;
    __syncthreads();
    for (int off = 1; off < 1024; off <<= 1) {
        const int v = (t >= off) ? tot[t - off] : 0;
        __syncthreads();
        tot[t] += v;
        __syncthreads();
    }
    const int base = tot[t] - s;   // exclusive
    #pragma unroll
    for (int k = 0; k < 8; ++k) bases[t * 8 + k] = base + loc[k];
    const int NA = tot[1023];
    if (t == 0) *natot = NA;
    __syncthreads();
    const int NApad = (NA + 63) & ~63;
    for (int idx = NA * 16 + t; idx < NApad * 16; idx += 1024) Xq[idx] = 0;
    for (int idx = NA + t; idx < NApad; idx += 1024) rowseg[idx] = (ush)0xFFFFu;
}

// ---------------------------------------------------------------------------
// scatter: build dense bf16 edge matrix Xq[NA][16] (sorted by rid=(b,i)),
// rowseg[NA]; zero sum/cnt.
// ---------------------------------------------------------------------------
__global__ __launch_bounds__(256) void scatter_kernel(
    const float* __restrict__ ma, const float* __restrict__ eg,
    const int* __restrict__ ma_adj, const int* __restrict__ bidx,
    const int* __restrict__ bases,
    ush* __restrict__ Xq, ush* __restrict__ rowseg,
    float* __restrict__ sumG, float* __restrict__ cntG)
{
    const int tid = threadIdx.x;
    const int rid = blockIdx.x * 4 + (tid >> 6);
    const int lane = tid & 63;
    const int b = rid >> 9, i = rid & 511;
    const int bi = bidx[b];
    const int act = (ma_adj[((size_t)bi * NOPc + i) * NMAc + lane] != 0) ? 1 : 0;
    const unsigned long long mk = __ballot(act);
    if (act) {
        const int pos = bases[rid] + (int)__popcll(mk & ((1ull << lane) - 1ull));
        const float4* mp = (const float4*)(ma + ((size_t)b * NMAc + lane) * 8);
        const float4* ep = (const float4*)(eg + (((size_t)b * NOPc + i) * NMAc + lane) * 8);
        const float4 m0 = mp[0], m1 = mp[1], e0 = ep[0], e1 = ep[1];
        uint4 u0, u1;
        u0.x = pkbf_rne(m0.x, m0.y); u0.y = pkbf_rne(m0.z, m0.w);
        u0.z = pkbf_rne(m1.x, m1.y); u0.w = pkbf_rne(m1.z, m1.w);
        u1.x = pkbf_rne(e0.x, e0.y); u1.y = pkbf_rne(e0.z, e0.w);
        u1.z = pkbf_rne(e1.x, e1.y); u1.w = pkbf_rne(e1.z, e1.w);
        uint4* dst = (uint4*)(Xq + (size_t)pos * 16);
        dst[0] = u0;
        dst[1] = u1;
        rowseg[pos] = (ush)rid;
    }
    sumG[(size_t)rid * 128 + lane] = 0.f;
    sumG[(size_t)rid * 128 + 64 + lane] = 0.f;
    cntG[(size_t)rid * 128 + lane] = 0.f;
    cntG[(size_t)rid * 128 + 64 + lane] = 0.f;
}

// ---------------------------------------------------------------------------
// Fused kernel: blocks [0,8192) = edge MLP0 tiles; [8192, 8960) = f1 paths
// 0..2 (pre/sub/self), 32 rows each.
// ---------------------------------------------------------------------------
struct EF1Args {
    const ush* Xq; const ush* rowseg; const int* natot; MlpPack P0;
    float* sumG; float* cntG;
    const float* X[3]; MlpPack P[3]; float* f1[3]; float* ut[3];
};

__global__ __launch_bounds__(256, 4) void edge_f1_kernel(EF1Args A, const float* __restrict__ attn)
{
    __shared__ unsigned char smem[36992];
    const int blk = blockIdx.x;
    const int tid = threadIdx.x;
    const int wv = tid >> 6, lane = tid & 63, r = lane & 15, g = lane >> 4;

    if (blk < 8192) {
        // ================= edge path =================
        const int NA = *A.natot;
        const int tile = blk;
        if (tile * 64 >= NA) return;
        ush* Hh = (ush*)smem;                       // 64*256 ush = 32768 B
        ush* segid = (ush*)(smem + 32768);          // 64 ush
        const MlpPack& P = A.P0;
        if (tid < 64) segid[tid] = A.rowseg[(size_t)tile * 64 + tid];

        // ---- layer 1: 32 -> 256, X direct from dense global queue ----
        {
            f32x4 acc[4][4];
            #pragma unroll
            for (int a = 0; a < 4; ++a)
                #pragma unroll
                for (int m = 0; m < 4; ++m) acc[a][m] = f32x4{0.f, 0.f, 0.f, 0.f};
            bf16x8 wh[4];
            #pragma unroll
            for (int a = 0; a < 4; ++a)
                wh[a] = *(const bf16x8*)(P.w1h + ((size_t)(wv * 4 + a) * 64 + lane) * 8);
            #pragma unroll
            for (int m = 0; m < 4; ++m) {
                const int gr = tile * 64 + 16 * m + r;
                bf16x8 xh = {0, 0, 0, 0, 0, 0, 0, 0};
                if (g < 2) xh = *(const bf16x8*)(A.Xq + (size_t)gr * 16 + 8 * g);
                #pragma unroll
                for (int a = 0; a < 4; ++a) acc[a][m] = MFMA(wh[a], xh, acc[a][m]);
            }
            #pragma unroll
            for (int a = 0; a < 4; ++a) {
                const int n0 = (wv * 4 + a) * 16 + 4 * g;
                const float4 bv = *(const float4*)(P.b1 + n0);
                #pragma unroll
                for (int m = 0; m < 4; ++m) {
                    const int row = 16 * m + r;
                    const float y0 = eluf_fast(acc[a][m][0] + bv.x);
                    const float y1 = eluf_fast(acc[a][m][1] + bv.y);
                    const float y2 = eluf_fast(acc[a][m][2] + bv.z);
                    const float y3 = eluf_fast(acc[a][m][3] + bv.w);
                    uint2 u; u.x = pkbf(y0, y1); u.y = pkbf(y2, y3);
                    *(uint2*)(Hh + row * 256 + (n0 ^ (8 * (row & 7)))) = u;
                }
            }
        }
        __syncthreads();

        // ---- layer 2: 256 -> 256 (in place) ----
        {
            f32x4 acc[4][4];
            #pragma unroll
            for (int a = 0; a < 4; ++a)
                #pragma unroll
                for (int m = 0; m < 4; ++m) acc[a][m] = f32x4{0.f, 0.f, 0.f, 0.f};
            #pragma unroll 1
            for (int kb = 0; kb < 8; ++kb) {
                bf16x8 wh[4];
                #pragma unroll
                for (int a = 0; a < 4; ++a)
                    wh[a] = *(const bf16x8*)(P.w2h + ((size_t)(kb * 16 + (wv * 4 + a)) * 64 + lane) * 8);
                #pragma unroll
                for (int m = 0; m < 4; ++m) {
                    const int row = 16 * m + r;
                    const int k0 = kb * 32 + 8 * g;
                    bf16x8 hh = *(const bf16x8*)(Hh + row * 256 + (k0 ^ (8 * (row & 7))));
                    #pragma unroll
                    for (int a = 0; a < 4; ++a) acc[a][m] = MFMA(wh[a], hh, acc[a][m]);
                }
            }
            __syncthreads();
            #pragma unroll
            for (int a = 0; a < 4; ++a) {
                const int n0 = (wv * 4 + a) * 16 + 4 * g;
                const float4 bv = *(const float4*)(P.b2 + n0);
                #pragma unroll
                for (int m = 0; m < 4; ++m) {
                    const int row = 16 * m + r;
                    const float y0 = eluf_fast(acc[a][m][0] + bv.x);
                    const float y1 = eluf_fast(acc[a][m][1] + bv.y);
                    const float y2 = eluf_fast(acc[a][m][2] + bv.z);
                    const float y3 = eluf_fast(acc[a][m][3] + bv.w);
                    uint2 u; u.x = pkbf(y0, y1); u.y = pkbf(y2, y3);
                    *(uint2*)(Hh + row * 256 + (n0 ^ (8 * (row & 7)))) = u;
                }
            }
        }
        __syncthreads();

        // ---- layer 3: 256 -> 128 ----
        f32x4 acc3[2][4];
        #pragma unroll
        for (int a = 0; a < 2; ++a)
            #pragma unroll
            for (int m = 0; m < 4; ++m) acc3[a][m] = f32x4{0.f, 0.f, 0.f, 0.f};
        #pragma unroll 1
        for (int kb = 0; kb < 8; ++kb) {
            bf16x8 wh[2];
            #pragma unroll
            for (int a = 0; a < 2; ++a)
                wh[a] = *(const bf16x8*)(P.w3h + ((size_t)(kb * 8 + (wv * 2 + a)) * 64 + lane) * 8);
            #pragma unroll
            for (int m = 0; m < 4; ++m) {
                const int row = 16 * m + r;
                const int k0 = kb * 32 + 8 * g;
                bf16x8 hh = *(const bf16x8*)(Hh + row * 256 + (k0 ^ (8 * (row & 7))));
                #pragma unroll
                for (int a = 0; a < 2; ++a) acc3[a][m] = MFMA(wh[a], hh, acc3[a][m]);
            }
        }
        __syncthreads();            // all Hh reads complete before aliasing as f1buf

        // ---- write y rows to LDS f1buf (f32, XOR-swizzled) ----
        float* f1buf = (float*)Hh;
        #pragma unroll
        for (int a = 0; a < 2; ++a) {
            const int n0 = (wv * 2 + a) * 16 + 4 * g;
            const float4 bv = *(const float4*)(P.b3 + n0);
            #pragma unroll
            for (int m = 0; m < 4; ++m) {
                const int row = 16 * m + r;
                float4 y;
                y.x = acc3[a][m][0] + bv.x;
                y.y = acc3[a][m][1] + bv.y;
                y.z = acc3[a][m][2] + bv.z;
                y.w = acc3[a][m][3] + bv.w;
                *(float4*)&f1buf[row * 128 + (n0 ^ ((row & 7) << 2))] = y;
            }
        }
        __syncthreads();

        // ---- segmented pooling, fully unrolled; sentinel 0xFFFF guards pad ----
        {
            const int c = tid & 127, h = tid >> 7;
            const int r0p = h * 32;
            float accS = 0.f, accC = 0.f;
            int cur = -1;
            #pragma unroll
            for (int blk8 = 0; blk8 < 4; ++blk8) {
                #pragma unroll
                for (int k8 = 0; k8 < 8; ++k8) {
                    const int rl = r0p + blk8 * 8 + k8;    // rl & 7 == k8
                    const int sg = (int)segid[rl];
                    if (sg != cur) {
                        if ((unsigned)cur < (unsigned)NROW) {
                            atomicAdd(&A.sumG[(size_t)cur * 128 + c], accS);
                            atomicAdd(&A.cntG[(size_t)cur * 128 + c], accC);
                        }
                        cur = sg; accS = 0.f; accC = 0.f;
                    }
                    const float y = f1buf[rl * 128 + (c ^ (k8 << 2))];
                    accS += y;
                    accC += (y != 0.f) ? 1.f : 0.f;
                }
            }
            if ((unsigned)cur < (unsigned)NROW) {
                atomicAdd(&A.sumG[(size_t)cur * 128 + c], accS);
                atomicAdd(&A.cntG[(size_t)cur * 128 + c], accC);
            }
        }
    } else {
        // ================= f1 paths 0..2 (32-row tiles) =================
        const int pb = blk - 8192;
        const int p = pb >> 8;
        const int row0 = (pb & 255) * 32;
        ush* Xh = (ush*)smem;                        // 32*32 = 2048 B
        ush* Xl = (ush*)(smem + 2048);
        ush* Hh = (ush*)(smem + 4096);               // 32*256 = 16384 B
        ush* Hl = (ush*)(smem + 20480);
        float* UT = (float*)(smem + 36864);          // 32 floats
        const float* Xg = A.X[p];
        const MlpPack P = A.P[p];
        float* f1_out = A.f1[p];
        float* ut_out = A.ut[p];
        if (tid < 32) UT[tid] = 0.f;
        for (int idx = tid; idx < 32 * 32; idx += 256) {
            const int row = idx >> 5, k = idx & 31;
            float v = 0.f;
            if (k < 16) v = Xg[(size_t)(row0 + row) * 16 + k];
            const uint32 uv = __float_as_uint(v);
            Xh[idx] = (ush)(uv >> 16);
            const float rest = v - __uint_as_float(uv & 0xFFFF0000u);
            Xl[idx] = (ush)(__float_as_uint(rest) >> 16);
        }
        __syncthreads();
        f32x4 acc3[2][2];
        mlp3_core32(P, 1, Xh, Xl, Hh, Hl, acc3);

        float utp[2] = {0.f, 0.f};
        #pragma unroll
        for (int a = 0; a < 2; ++a) {
            const int n0 = (wv * 2 + a) * 16 + 4 * g;
            const float4 bv = *(const float4*)(P.b3 + n0);
            const float4 av = *(const float4*)(attn + n0);
            #pragma unroll
            for (int m = 0; m < 2; ++m) {
                float4 y;
                y.x = acc3[a][m][0] + bv.x;
                y.y = acc3[a][m][1] + bv.y;
                y.z = acc3[a][m][2] + bv.z;
                y.w = acc3[a][m][3] + bv.w;
                *(float4*)&f1_out[(size_t)(row0 + 16 * m + r) * OUTc + n0] = y;
                utp[m] += y.x * av.x + y.y * av.y + y.z * av.z + y.w * av.w;
            }
        }
        #pragma unroll
        for (int m = 0; m < 2; ++m) {
            float v = utp[m];
            v += __shfl_xor(v, 16);
            v += __shfl_xor(v, 32);
            if (lane < 16) atomicAdd(&UT[16 * m + r], v);
        }
        __syncthreads();
        if (tid < 32) ut_out[row0 + tid] = UT[tid];
    }
}

// ---------------------------------------------------------------------------
// MLP4 path (depends on edge results): 32 rows/block, finalizes x2 inline.
// ---------------------------------------------------------------------------
__global__ __launch_bounds__(256, 3) void p3_kernel(
    MlpPack P, const float* __restrict__ attn,
    const float* __restrict__ sumG, const float* __restrict__ cntG,
    const int* __restrict__ counts, const float* __restrict__ f1z,
    float* __restrict__ f1_out, float* __restrict__ ut_out)
{
    __shared__ ush Xh[32 * 128], Xl[32 * 128];
    __shared__ ush Hh[32 * 256], Hl[32 * 256];
    __shared__ float UT[32];
    const int tid = threadIdx.x;
    const int row0 = blockIdx.x * 32;
    if (tid < 32) UT[tid] = 0.f;
    for (int idx = tid; idx < 32 * 128; idx += 256) {
        const int row = idx >> 7, k = idx & 127;
        const size_t rid = (size_t)(row0 + row);
        const float nz = (float)(64 - counts[rid]);
        const float fz = f1z[k];
        const float v = (sumG[rid * 128 + k] + nz * fz)
                      / (cntG[rid * 128 + k] + nz * ((fz != 0.f) ? 1.f : 0.f));
        const uint32 uv = __float_as_uint(v);
        Xh[idx] = (ush)(uv >> 16);
        const float rest = v - __uint_as_float(uv & 0xFFFF0000u);
        Xl[idx] = (ush)(__float_as_uint(rest) >> 16);
    }
    __syncthreads();
    f32x4 acc3[2][2];
    mlp3_core32(P, 4, Xh, Xl, Hh, Hl, acc3);

    const int wv = tid >> 6, lane = tid & 63, r = lane & 15, g = lane >> 4;
    float utp[2] = {0.f, 0.f};
    #pragma unroll
    for (int a = 0; a < 2; ++a) {
        const int n0 = (wv * 2 + a) * 16 + 4 * g;
        const float4 bv = *(const float4*)(P.b3 + n0);
        const float4 av = *(const float4*)(attn + n0);
        #pragma unroll
        for (int m = 0; m < 2; ++m) {
            float4 y;
            y.x = acc3[a][m][0] + bv.x;
            y.y = acc3[a][m][1] + bv.y;
            y.z = acc3[a][m][2] + bv.z;
            y.w = acc3[a][m][3] + bv.w;
            *(float4*)&f1_out[(size_t)(row0 + 16 * m + r) * OUTc + n0] = y;
            utp[m] += y.x * av.x + y.y * av.y + y.z * av.z + y.w * av.w;
        }
    }
    #pragma unroll
    for (int m = 0; m < 2; ++m) {
        float v = utp[m];
        v += __shfl_xor(v, 16);
        v += __shfl_xor(v, 32);
        if (lane < 16) atomicAdd(&UT[16 * m + r], v);
    }
    __syncthreads();
    if (tid < 32) ut_out[row0 + tid] = UT[tid];
}

// ---------------------------------------------------------------------------
// combine with inline per-batch softmax: block = (b, 32-row chunk).
// ---------------------------------------------------------------------------
__global__ __launch_bounds__(256) void combine2_kernel(
    const float* __restrict__ uts,
    const float* __restrict__ pre_f1, const float* __restrict__ sub_f1,
    const float* __restrict__ self_f1, const float* __restrict__ ma_f2,
    float* __restrict__ out)
{
    __shared__ float sc[4 * NOPc];
    __shared__ float red[256];
    const int b = blockIdx.x >> 4, chunk = blockIdx.x & 15;
    const int t = threadIdx.x;
    const float* put = uts + 0 * NROW + (size_t)b * NOPc;
    const float* sut = uts + 1 * NROW + (size_t)b * NOPc;
    const float* eut = uts + 2 * NROW + (size_t)b * NOPc;
    const float* mut = uts + 3 * NROW + (size_t)b * NOPc;
    for (int i = t; i < NOPc; i += 256) {
        const float se = eut[i];
        const float s0 = put[i] + se, s1 = sut[i] + se, s2 = se + se, s3 = mut[i] + se;
        sc[0 * NOPc + i] = s0 > 0.f ? s0 : 0.2f * s0;
        sc[1 * NOPc + i] = s1 > 0.f ? s1 : 0.2f * s1;
        sc[2 * NOPc + i] = s2 > 0.f ? s2 : 0.2f * s2;
        sc[3 * NOPc + i] = s3 > 0.f ? s3 : 0.2f * s3;
    }
    __syncthreads();
    float mx = -INFINITY;
    for (int idx = t; idx < 4 * NOPc; idx += 256) mx = fmaxf(mx, sc[idx]);
    red[t] = mx;
    __syncthreads();
    for (int s = 128; s > 0; s >>= 1) { if (t < s) red[t] = fmaxf(red[t], red[t + s]); __syncthreads(); }
    mx = red[0];
    __syncthreads();
    float ps = 0.f;
    for (int idx = t; idx < 4 * NOPc; idx += 256) {
        const float e = expf(sc[idx] - mx);
        sc[idx] = e;
        ps += e;
    }
    red[t] = ps;
    __syncthreads();
    for (int s = 128; s > 0; s >>= 1) { if (t < s) red[t] += red[t + s]; __syncthreads(); }
    const float invZ = 1.f / red[0];

    const size_t base4 = (size_t)b * 16384 + (size_t)chunk * 1024;   // float4 units
    #pragma unroll
    for (int k = 0; k < 4; ++k) {
        const size_t e4 = base4 + k * 256 + t;
        const int i = (int)((e4 >> 5) & 511);
        const float a0 = sc[0 * NOPc + i] * invZ;
        const float a1 = sc[1 * NOPc + i] * invZ;
        const float a2 = sc[2 * NOPc + i] * invZ;
        const float a3 = sc[3 * NOPc + i] * invZ;
        const float4 vp = ((const float4*)pre_f1)[e4];
        const float4 vs = ((const float4*)sub_f1)[e4];
        const float4 ve = ((const float4*)self_f1)[e4];
        const float4 vm = ((const float4*)ma_f2)[e4];
        float4 o;
        o.x = 1.f / (1.f + expf(-(a0 * vp.x + a1 * vs.x + a2 * ve.x + a3 * vm.x)));
        o.y = 1.f / (1.f + expf(-(a0 * vp.y + a1 * vs.y + a2 * ve.y + a3 * vm.y)));
        o.z = 1.f / (1.f + expf(-(a0 * vp.z + a1 * vs.z + a2 * ve.z + a3 * vm.z)));
        o.w = 1.f / (1.f + expf(-(a0 * vp.w + a1 * vs.w + a2 * ve.w + a3 * vm.w)));
        ((float4*)out)[e4] = o;
    }
}

extern "C" void kernel_launch(void* const* d_in, const int* in_sizes, int n_in,
                              void* d_out, int out_size, void* d_ws, size_t ws_size,
                              hipStream_t stream) {
    const float* op      = (const float*)d_in[0];
    const float* ma      = (const float*)d_in[1];
    const float* eg      = (const float*)d_in[2];
    const int*   ma_adj  = (const int*)d_in[3];
    const int*   pre_adj = (const int*)d_in[4];
    const int*   sub_adj = (const int*)d_in[5];
    const int*   bidx    = (const int*)d_in[6];
    const float* attn    = (const float*)d_in[7];
    float* out = (float*)d_out;
    const float* Wraw[5][6];
    for (int m = 0; m < 5; ++m)
        for (int j = 0; j < 6; ++j)
            Wraw[m][j] = (const float*)d_in[8 + 6 * m + j];

    // ---- workspace layout ----
    float* wsf = (float*)d_ws;
    float* pre_agg = wsf;  wsf += (size_t)NROW * 16;
    float* sub_agg = wsf;  wsf += (size_t)NROW * 16;
    float* pre_f1  = wsf;  wsf += (size_t)NROW * OUTc;
    float* sub_f1  = wsf;  wsf += (size_t)NROW * OUTc;
    float* self_f1 = wsf;  wsf += (size_t)NROW * OUTc;
    float* ma_f2   = wsf;  wsf += (size_t)NROW * OUTc;
    float* uts     = wsf;  wsf += (size_t)4 * NROW;
    float* f1z     = wsf;  wsf += 128;
    float* sumG    = wsf;  wsf += (size_t)NROW * 128;
    float* cntG    = wsf;  wsf += (size_t)NROW * 128;
    int*   counts  = (int*)wsf;   wsf += NROW;
    int*   bases   = (int*)wsf;   wsf += NROW;
    int*   natot   = (int*)wsf;   wsf += 16;
    ush*   rowseg  = (ush*)wsf;   wsf += NEMAX / 2;
    ush*   Xq      = (ush*)wsf;   wsf += (size_t)NEMAX * 8;   // NEMAX rows * 16 ush
    ush*   packp   = (ush*)wsf;

    PrepArgs pa;
    MlpPack pk[5];
    for (int m = 0; m < 5; ++m) {
        const int kre[3] = { (m == 4 ? 128 : 16), 256, 256 };
        const int kbn[3] = { (m == 4 ? 4 : 1), 8, 8 };
        const int nbn[3] = { 16, 16, 8 };
        const ush* dh[3]; const ush* dl[3];
        for (int j = 0; j < 3; ++j) {
            const int id = m * 3 + j;
            pa.d[id].src = Wraw[m][2 * j];
            pa.d[id].kreal = kre[j];
            pa.d[id].kbn = kbn[j];
            pa.d[id].nbn = nbn[j];
            const int cnt = kbn[j] * nbn[j] * 512;
            pa.d[id].dh = packp; dh[j] = packp; packp += cnt;
            pa.d[id].dl = packp; dl[j] = packp; packp += cnt;
        }
        pk[m].w1h = dh[0]; pk[m].w1l = dl[0];
        pk[m].w2h = dh[1]; pk[m].w2l = dl[1];
        pk[m].w3h = dh[2]; pk[m].w3l = dl[2];
        pk[m].b1 = Wraw[m][1]; pk[m].b2 = Wraw[m][3]; pk[m].b3 = Wraw[m][5];
    }
    pa.op = op; pa.pre_adj = pre_adj; pa.sub_adj = sub_adj; pa.ma_adj = ma_adj;
    pa.bidx = bidx;
    pa.pre_agg = pre_agg; pa.sub_agg = sub_agg; pa.counts = counts;
    pa.z_b1 = Wraw[0][1]; pa.z_w2 = Wraw[0][2]; pa.z_b2 = Wraw[0][3];
    pa.z_w3 = Wraw[0][4]; pa.z_b3 = Wraw[0][5];
    pa.f1z = f1z;

    EF1Args ea;
    ea.Xq = Xq; ea.rowseg = rowseg; ea.natot = natot; ea.P0 = pk[0];
    ea.sumG = sumG; ea.cntG = cntG;
    ea.X[0] = pre_agg; ea.X[1] = sub_agg; ea.X[2] = op;
    ea.P[0] = pk[1];   ea.P[1] = pk[2];   ea.P[2] = pk[3];
    ea.f1[0] = pre_f1; ea.f1[1] = sub_f1; ea.f1[2] = self_f1;
    ea.ut[0] = uts + 0 * NROW;
    ea.ut[1] = uts + 1 * NROW;
    ea.ut[2] = uts + 2 * NROW;

    prep_kernel<<<dim3(960 + NROW + 1), 256, 0, stream>>>(pa);
    scan_kernel<<<1, 1024, 0, stream>>>(counts, bases, natot, Xq, rowseg);
    scatter_kernel<<<dim3(NROW / 4), 256, 0, stream>>>(ma, eg, ma_adj, bidx, bases,
                                                       Xq, rowseg, sumG, cntG);
    edge_f1_kernel<<<dim3(8192 + 768), 256, 0, stream>>>(ea, attn);
    p3_kernel<<<dim3(256), 256, 0, stream>>>(pk[4], attn, sumG, cntG, counts, f1z,
                                             ma_f2, uts + 3 * NROW);
    combine2_kernel<<<dim3(NBb * 16), 256, 0, stream>>>(uts, pre_f1, sub_f1, self_f1, ma_f2, out);
}